// Round 2
// baseline (984.408 us; speedup 1.0000x reference)
//
#include <hip/hip_runtime.h>

#define EPSF 1e-7f
#define MAXNORM (1.0f - 1e-5f)

__device__ __forceinline__ float rsum64(float v) {
#pragma unroll
  for (int m = 32; m; m >>= 1) v += __shfl_xor(v, m, 64);
  return v;
}

__device__ __forceinline__ float rsum16(float v) {
#pragma unroll
  for (int m = 8; m; m >>= 1) v += __shfl_xor(v, m, 64);
  return v;
}

// count occurrences: cnt[idx[i]] += 1
__global__ void k_count(const int* __restrict__ idx, float* __restrict__ cnt, int n) {
  int i = blockIdx.x * blockDim.x + threadIdx.x;
  if (i < n) atomicAdd(&cnt[idx[i]], 1.0f);
}

// h = proj(expmap0(x)), wave per node
__global__ void __launch_bounds__(256) k_init(const float* __restrict__ x,
                                              float* __restrict__ h, int N) {
  int node = blockIdx.x * 4 + (threadIdx.x >> 6);
  if (node >= N) return;
  int lane = threadIdx.x & 63;
  float u = x[(size_t)node * 64 + lane];
  float n = fmaxf(sqrtf(rsum64(u * u)), EPSF);
  float e = tanhf(n) * u / n;
  float ne = fmaxf(sqrtf(rsum64(e * e)), EPSF);
  if (ne > MAXNORM) e *= MAXNORM / ne;
  h[(size_t)node * 64 + lane] = e;
}

// xt = logmap0(proj(mobius_add(proj(expmap0(logmap0(h) @ W^T)), proj(expmap0(b)))))
// i.e. hyp_linear fused, emitting the tangent-space vector the aggregation needs.
__global__ void __launch_bounds__(256) k_linear(const float* __restrict__ h,
                                                const float* __restrict__ W,
                                                const float* __restrict__ b,
                                                float* __restrict__ xt, int N) {
  __shared__ float Wl[64 * 65];
  int tid = threadIdx.x;
  int lane = tid & 63;
  for (int i = tid; i < 64 * 64; i += 256)
    Wl[(i >> 6) * 65 + (i & 63)] = W[i];
  __syncthreads();

  int node = blockIdx.x * 4 + (tid >> 6);
  if (node >= N) return;

  // logmap0 of input point
  float xv = h[(size_t)node * 64 + lane];
  float n = fmaxf(sqrtf(rsum64(xv * xv)), EPSF);
  float t = atanhf(fminf(n, MAXNORM)) * xv / n;

  // y = t @ W^T  -> y[lane] = sum_k t[k] * W[lane][k]
  float acc = 0.f;
#pragma unroll
  for (int k = 0; k < 64; ++k) {
    float tk = __shfl(t, k, 64);
    acc = fmaf(Wl[lane * 65 + k], tk, acc);
  }

  // proj(expmap0(y))
  float ny = fmaxf(sqrtf(rsum64(acc * acc)), EPSF);
  float hy = tanhf(ny) * acc / ny;
  float nh = fmaxf(sqrtf(rsum64(hy * hy)), EPSF);
  if (nh > MAXNORM) hy *= MAXNORM / nh;

  // hb = proj(expmap0(b))
  float bb = b[lane];
  float nb = fmaxf(sqrtf(rsum64(bb * bb)), EPSF);
  float hb = tanhf(nb) * bb / nb;
  float nhb = fmaxf(sqrtf(rsum64(hb * hb)), EPSF);
  if (nhb > MAXNORM) hb *= MAXNORM / nhb;

  // mobius_add(hy, hb)
  float x2 = rsum64(hy * hy);
  float y2 = rsum64(hb * hb);
  float xy = rsum64(hy * hb);
  float num = (1.f + 2.f * xy + y2) * hy + (1.f - x2) * hb;
  float den = fmaxf(1.f + 2.f * xy + x2 * y2, EPSF);
  float r = num / den;
  float nr = fmaxf(sqrtf(rsum64(r * r)), EPSF);
  if (nr > MAXNORM) r *= MAXNORM / nr;

  // logmap0 for aggregation
  float nr2 = fmaxf(sqrtf(rsum64(r * r)), EPSF);
  float tout = atanhf(fminf(nr2, MAXNORM)) * r / nr2;
  xt[(size_t)node * 64 + lane] = tout;
}

// agg[dst[e]][d] += xt[src[e]][d]; one wave per edge (64 dims)
__global__ void k_scatter(const int* __restrict__ src, const int* __restrict__ dst,
                          const float* __restrict__ xt, float* __restrict__ agg,
                          int total) {
  int idx = blockIdx.x * blockDim.x + threadIdx.x;
  if (idx >= total) return;
  int e = idx >> 6;
  int d = idx & 63;
  int s = src[e];
  int tnode = dst[e];
  atomicAdd(&agg[(size_t)tnode * 64 + d], xt[(size_t)s * 64 + d]);
}

// per node: u = agg/max(cnt,1); h = proj(expmap0(u));
// if do_act: h = proj(expmap0(leaky(logmap0(h))))  -> store
// if do_pool: t = logmap0(h) -> atomic pool into pooled[batch[node]]
__global__ void __launch_bounds__(256) k_aggpost(
    const float* __restrict__ agg, const float* __restrict__ cnt,
    float* __restrict__ hout, int N, int do_act, int do_pool,
    const int* __restrict__ batch, float* __restrict__ pooled) {
  int node = blockIdx.x * 4 + (threadIdx.x >> 6);
  if (node >= N) return;
  int lane = threadIdx.x & 63;

  float u = agg[(size_t)node * 64 + lane] / fmaxf(cnt[node], 1.0f);
  float n = fmaxf(sqrtf(rsum64(u * u)), EPSF);
  float e = tanhf(n) * u / n;
  float ne = fmaxf(sqrtf(rsum64(e * e)), EPSF);
  if (ne > MAXNORM) e *= MAXNORM / ne;

  if (do_act) {
    float nn = fmaxf(sqrtf(rsum64(e * e)), EPSF);
    float t = atanhf(fminf(nn, MAXNORM)) * e / nn;
    t = (t >= 0.f) ? t : 0.2f * t;
    float nt = fmaxf(sqrtf(rsum64(t * t)), EPSF);
    e = tanhf(nt) * t / nt;
    float ne2 = fmaxf(sqrtf(rsum64(e * e)), EPSF);
    if (ne2 > MAXNORM) e *= MAXNORM / ne2;
    hout[(size_t)node * 64 + lane] = e;
  } else if (do_pool) {
    float nn = fmaxf(sqrtf(rsum64(e * e)), EPSF);
    float t = atanhf(fminf(nn, MAXNORM)) * e / nn;
    int g = batch[node];
    atomicAdd(&pooled[(size_t)g * 64 + lane], t);
    // NOTE: graph-size counts come solely from k_count(batch,...) — counting
    // here as well double-counts and halves the pooled mean (R1 bug).
  } else {
    hout[(size_t)node * 64 + lane] = e;
  }
}

// head: per graph, 1 wave. pooled mean -> proj(expmap0) -> hyp_linear(W4[16,64], b4)
__global__ void __launch_bounds__(64) k_final(const float* __restrict__ pooled,
                                              const float* __restrict__ cntg,
                                              const float* __restrict__ W4,
                                              const float* __restrict__ b4,
                                              float* __restrict__ out, int G) {
  int g = blockIdx.x;
  int lane = threadIdx.x;
  float u = pooled[(size_t)g * 64 + lane] / fmaxf(cntg[g], 1.0f);
  float n = fmaxf(sqrtf(rsum64(u * u)), EPSF);
  float e = tanhf(n) * u / n;
  float ne = fmaxf(sqrtf(rsum64(e * e)), EPSF);
  if (ne > MAXNORM) e *= MAXNORM / ne;
  float nn = fmaxf(sqrtf(rsum64(e * e)), EPSF);
  float t = atanhf(fminf(nn, MAXNORM)) * e / nn;

  int row = lane & 15;  // duplicate each output row across 4 lane-groups
  float acc = 0.f;
#pragma unroll
  for (int k = 0; k < 64; ++k) {
    float tk = __shfl(t, k, 64);
    acc = fmaf(W4[row * 64 + k], tk, acc);
  }
  // expmap0 (16-dim) + proj
  float ny = fmaxf(sqrtf(rsum16(acc * acc)), EPSF);
  float hy = tanhf(ny) * acc / ny;
  float nh = fmaxf(sqrtf(rsum16(hy * hy)), EPSF);
  if (nh > MAXNORM) hy *= MAXNORM / nh;
  // hb = proj(expmap0(b4))
  float bb = b4[row];
  float nb = fmaxf(sqrtf(rsum16(bb * bb)), EPSF);
  float hb = tanhf(nb) * bb / nb;
  float nhb = fmaxf(sqrtf(rsum16(hb * hb)), EPSF);
  if (nhb > MAXNORM) hb *= MAXNORM / nhb;
  // mobius_add
  float x2 = rsum16(hy * hy);
  float y2 = rsum16(hb * hb);
  float xy = rsum16(hy * hb);
  float num = (1.f + 2.f * xy + y2) * hy + (1.f - x2) * hb;
  float den = fmaxf(1.f + 2.f * xy + x2 * y2, EPSF);
  float r = num / den;
  float nr = fmaxf(sqrtf(rsum16(r * r)), EPSF);
  if (nr > MAXNORM) r *= MAXNORM / nr;
  if (lane < 16) out[(size_t)g * 16 + lane] = r;
}

extern "C" void kernel_launch(void* const* d_in, const int* in_sizes, int n_in,
                              void* d_out, int out_size, void* d_ws, size_t ws_size,
                              hipStream_t stream) {
  const float* x  = (const float*)d_in[0];
  const float* W1 = (const float*)d_in[1];
  const float* b1 = (const float*)d_in[2];
  const float* W2 = (const float*)d_in[3];
  const float* b2 = (const float*)d_in[4];
  const float* W3 = (const float*)d_in[5];
  const float* b3 = (const float*)d_in[6];
  const float* W4 = (const float*)d_in[7];
  const float* b4 = (const float*)d_in[8];
  const int* ei   = (const int*)d_in[9];
  const int* batch = (const int*)d_in[10];

  int N = in_sizes[0] / 64;
  int E = in_sizes[9] / 2;
  int G = out_size / 16;
  const int* src = ei;
  const int* dst = ei + E;

  float* ws = (float*)d_ws;
  float* hA     = ws;
  float* xt     = hA + (size_t)N * 64;
  float* agg    = xt + (size_t)N * 64;
  float* cnt    = agg + (size_t)N * 64;
  float* pooled = cnt + N;
  float* cntg   = pooled + (size_t)G * 64;
  float* out = (float*)d_out;

  hipMemsetAsync(cnt, 0, (size_t)N * sizeof(float), stream);
  hipMemsetAsync(pooled, 0, ((size_t)G * 64 + G) * sizeof(float), stream);

  int nbE = (E + 255) / 256;
  k_count<<<nbE, 256, 0, stream>>>(dst, cnt, E);
  int nbN = (N + 255) / 256;
  k_count<<<nbN, 256, 0, stream>>>(batch, cntg, N);

  int nb4 = (N + 3) / 4;
  k_init<<<nb4, 256, 0, stream>>>(x, hA, N);

  const float* Ws[3] = {W1, W2, W3};
  const float* bs[3] = {b1, b2, b3};
  for (int l = 0; l < 3; ++l) {
    k_linear<<<nb4, 256, 0, stream>>>(hA, Ws[l], bs[l], xt, N);
    hipMemsetAsync(agg, 0, (size_t)N * 64 * sizeof(float), stream);
    int total = E * 64;
    int nbS = (total + 255) / 256;
    k_scatter<<<nbS, 256, 0, stream>>>(src, dst, xt, agg, total);
    k_aggpost<<<nb4, 256, 0, stream>>>(agg, cnt, hA, N, (l < 2) ? 1 : 0,
                                       (l == 2) ? 1 : 0, batch, pooled);
  }
  k_final<<<G, 64, 0, stream>>>(pooled, cntg, W4, b4, out, G);
}

// Round 3
// 559.955 us; speedup vs baseline: 1.7580x; 1.7580x over previous
//
#include <hip/hip_runtime.h>

#define EPSF 1e-7f
#define MAXNORM (1.0f - 1e-5f)

__device__ __forceinline__ float rsum64(float v) {
#pragma unroll
  for (int m = 32; m; m >>= 1) v += __shfl_xor(v, m, 64);
  return v;
}

__device__ __forceinline__ float rsum16(float v) {
#pragma unroll
  for (int m = 8; m; m >>= 1) v += __shfl_xor(v, m, 64);
  return v;
}

// ---------------- CSR build (by dst) ----------------
__global__ void k_hist(const int* __restrict__ dst, int* __restrict__ deg, int E) {
  int e = blockIdx.x * blockDim.x + threadIdx.x;
  if (e < E) atomicAdd(&deg[dst[e]], 1);
}

// block-level inclusive scan -> exclusive local scan + block totals
__global__ void __launch_bounds__(256) k_scanA(const int* __restrict__ deg,
                                               int* __restrict__ locscan,
                                               int* __restrict__ partial, int N) {
  __shared__ int buf[256];
  int i = blockIdx.x * 256 + threadIdx.x;
  int v = (i < N) ? deg[i] : 0;
  buf[threadIdx.x] = v;
  __syncthreads();
#pragma unroll
  for (int off = 1; off < 256; off <<= 1) {
    int t = (threadIdx.x >= off) ? buf[threadIdx.x - off] : 0;
    __syncthreads();
    buf[threadIdx.x] += t;
    __syncthreads();
  }
  if (i < N) locscan[i] = buf[threadIdx.x] - v;
  if (threadIdx.x == 255) partial[blockIdx.x] = buf[255];
}

// single-block exclusive scan of block totals (nb <= 256)
__global__ void __launch_bounds__(256) k_scanB(int* __restrict__ partial, int nb) {
  __shared__ int buf[256];
  int v = (threadIdx.x < nb) ? partial[threadIdx.x] : 0;
  buf[threadIdx.x] = v;
  __syncthreads();
#pragma unroll
  for (int off = 1; off < 256; off <<= 1) {
    int t = (threadIdx.x >= off) ? buf[threadIdx.x - off] : 0;
    __syncthreads();
    buf[threadIdx.x] += t;
    __syncthreads();
  }
  if (threadIdx.x < nb) partial[threadIdx.x] = buf[threadIdx.x] - v;
}

__global__ void __launch_bounds__(256) k_scanC(const int* __restrict__ locscan,
                                               const int* __restrict__ partial,
                                               int* __restrict__ rowptr, int N, int E) {
  int i = blockIdx.x * 256 + threadIdx.x;
  if (i < N) rowptr[i] = locscan[i] + partial[blockIdx.x];
  if (i == 0) rowptr[N] = E;
}

// fill CSR: consume deg as a countdown cursor (row order arbitrary)
__global__ void k_fill(const int* __restrict__ src, const int* __restrict__ dst,
                       const int* __restrict__ rowptr, int* __restrict__ deg,
                       int* __restrict__ csr, int E) {
  int e = blockIdx.x * blockDim.x + threadIdx.x;
  if (e >= E) return;
  int d = dst[e];
  int p = atomicSub(&deg[d], 1) - 1;
  csr[rowptr[d] + p] = src[e];
}

// count occurrences: cnt[idx[i]] += 1  (graph sizes)
__global__ void k_count(const int* __restrict__ idx, float* __restrict__ cnt, int n) {
  int i = blockIdx.x * blockDim.x + threadIdx.x;
  if (i < n) atomicAdd(&cnt[idx[i]], 1.0f);
}

// h = proj(expmap0(x)), wave per node
__global__ void __launch_bounds__(256) k_init(const float* __restrict__ x,
                                              float* __restrict__ h, int N) {
  int node = blockIdx.x * 4 + (threadIdx.x >> 6);
  if (node >= N) return;
  int lane = threadIdx.x & 63;
  float u = x[(size_t)node * 64 + lane];
  float n = fmaxf(sqrtf(rsum64(u * u)), EPSF);
  float e = tanhf(n) * u / n;
  float ne = fmaxf(sqrtf(rsum64(e * e)), EPSF);
  if (ne > MAXNORM) e *= MAXNORM / ne;
  h[(size_t)node * 64 + lane] = e;
}

// hyp_linear fused, emitting the tangent-space vector the aggregation needs.
__global__ void __launch_bounds__(256) k_linear(const float* __restrict__ h,
                                                const float* __restrict__ W,
                                                const float* __restrict__ b,
                                                float* __restrict__ xt, int N) {
  __shared__ float Wl[64 * 65];
  int tid = threadIdx.x;
  int lane = tid & 63;
  for (int i = tid; i < 64 * 64; i += 256)
    Wl[(i >> 6) * 65 + (i & 63)] = W[i];
  __syncthreads();

  int node = blockIdx.x * 4 + (tid >> 6);
  if (node >= N) return;

  float xv = h[(size_t)node * 64 + lane];
  float n = fmaxf(sqrtf(rsum64(xv * xv)), EPSF);
  float t = atanhf(fminf(n, MAXNORM)) * xv / n;

  float acc = 0.f;
#pragma unroll
  for (int k = 0; k < 64; ++k) {
    float tk = __shfl(t, k, 64);
    acc = fmaf(Wl[lane * 65 + k], tk, acc);
  }

  float ny = fmaxf(sqrtf(rsum64(acc * acc)), EPSF);
  float hy = tanhf(ny) * acc / ny;
  float nh = fmaxf(sqrtf(rsum64(hy * hy)), EPSF);
  if (nh > MAXNORM) hy *= MAXNORM / nh;

  float bb = b[lane];
  float nb = fmaxf(sqrtf(rsum64(bb * bb)), EPSF);
  float hb = tanhf(nb) * bb / nb;
  float nhb = fmaxf(sqrtf(rsum64(hb * hb)), EPSF);
  if (nhb > MAXNORM) hb *= MAXNORM / nhb;

  float x2 = rsum64(hy * hy);
  float y2 = rsum64(hb * hb);
  float xy = rsum64(hy * hb);
  float num = (1.f + 2.f * xy + y2) * hy + (1.f - x2) * hb;
  float den = fmaxf(1.f + 2.f * xy + x2 * y2, EPSF);
  float r = num / den;
  float nr = fmaxf(sqrtf(rsum64(r * r)), EPSF);
  if (nr > MAXNORM) r *= MAXNORM / nr;

  float nr2 = fmaxf(sqrtf(rsum64(r * r)), EPSF);
  float tout = atanhf(fminf(nr2, MAXNORM)) * r / nr2;
  xt[(size_t)node * 64 + lane] = tout;
}

// fused: CSR gather-mean -> proj(expmap0) -> [act | pool | plain] ; wave per node
__global__ void __launch_bounds__(256) k_gatheragg(
    const int* __restrict__ rowptr, const int* __restrict__ csr,
    const float* __restrict__ xt, float* __restrict__ hout, int N,
    int do_act, int do_pool, const int* __restrict__ batch,
    float* __restrict__ pooled) {
  int node = blockIdx.x * 4 + (threadIdx.x >> 6);
  if (node >= N) return;
  int lane = threadIdx.x & 63;

  int r0 = rowptr[node], r1 = rowptr[node + 1];
  float acc = 0.f;
  int j = r0;
  for (; j + 3 < r1; j += 4) {
    int s0 = csr[j], s1 = csr[j + 1], s2 = csr[j + 2], s3 = csr[j + 3];
    float v0 = xt[(size_t)s0 * 64 + lane];
    float v1 = xt[(size_t)s1 * 64 + lane];
    float v2 = xt[(size_t)s2 * 64 + lane];
    float v3 = xt[(size_t)s3 * 64 + lane];
    acc += v0 + v1 + v2 + v3;
  }
  for (; j < r1; ++j) acc += xt[(size_t)csr[j] * 64 + lane];

  float dcnt = (float)(r1 - r0);
  float u = acc / fmaxf(dcnt, 1.0f);
  float n = fmaxf(sqrtf(rsum64(u * u)), EPSF);
  float e = tanhf(n) * u / n;
  float ne = fmaxf(sqrtf(rsum64(e * e)), EPSF);
  if (ne > MAXNORM) e *= MAXNORM / ne;

  if (do_act) {
    float nn = fmaxf(sqrtf(rsum64(e * e)), EPSF);
    float t = atanhf(fminf(nn, MAXNORM)) * e / nn;
    t = (t >= 0.f) ? t : 0.2f * t;
    float nt = fmaxf(sqrtf(rsum64(t * t)), EPSF);
    e = tanhf(nt) * t / nt;
    float ne2 = fmaxf(sqrtf(rsum64(e * e)), EPSF);
    if (ne2 > MAXNORM) e *= MAXNORM / ne2;
    hout[(size_t)node * 64 + lane] = e;
  } else if (do_pool) {
    float nn = fmaxf(sqrtf(rsum64(e * e)), EPSF);
    float t = atanhf(fminf(nn, MAXNORM)) * e / nn;
    int g = batch[node];
    atomicAdd(&pooled[(size_t)g * 64 + lane], t);
  } else {
    hout[(size_t)node * 64 + lane] = e;
  }
}

// head: per graph, 1 wave
__global__ void __launch_bounds__(64) k_final(const float* __restrict__ pooled,
                                              const float* __restrict__ cntg,
                                              const float* __restrict__ W4,
                                              const float* __restrict__ b4,
                                              float* __restrict__ out, int G) {
  int g = blockIdx.x;
  int lane = threadIdx.x;
  float u = pooled[(size_t)g * 64 + lane] / fmaxf(cntg[g], 1.0f);
  float n = fmaxf(sqrtf(rsum64(u * u)), EPSF);
  float e = tanhf(n) * u / n;
  float ne = fmaxf(sqrtf(rsum64(e * e)), EPSF);
  if (ne > MAXNORM) e *= MAXNORM / ne;
  float nn = fmaxf(sqrtf(rsum64(e * e)), EPSF);
  float t = atanhf(fminf(nn, MAXNORM)) * e / nn;

  int row = lane & 15;
  float acc = 0.f;
#pragma unroll
  for (int k = 0; k < 64; ++k) {
    float tk = __shfl(t, k, 64);
    acc = fmaf(W4[row * 64 + k], tk, acc);
  }
  float ny = fmaxf(sqrtf(rsum16(acc * acc)), EPSF);
  float hy = tanhf(ny) * acc / ny;
  float nh = fmaxf(sqrtf(rsum16(hy * hy)), EPSF);
  if (nh > MAXNORM) hy *= MAXNORM / nh;
  float bb = b4[row];
  float nb = fmaxf(sqrtf(rsum16(bb * bb)), EPSF);
  float hb = tanhf(nb) * bb / nb;
  float nhb = fmaxf(sqrtf(rsum16(hb * hb)), EPSF);
  if (nhb > MAXNORM) hb *= MAXNORM / nhb;
  float x2 = rsum16(hy * hy);
  float y2 = rsum16(hb * hb);
  float xy = rsum16(hy * hb);
  float num = (1.f + 2.f * xy + y2) * hy + (1.f - x2) * hb;
  float den = fmaxf(1.f + 2.f * xy + x2 * y2, EPSF);
  float r = num / den;
  float nr = fmaxf(sqrtf(rsum16(r * r)), EPSF);
  if (nr > MAXNORM) r *= MAXNORM / nr;
  if (lane < 16) out[(size_t)g * 16 + lane] = r;
}

extern "C" void kernel_launch(void* const* d_in, const int* in_sizes, int n_in,
                              void* d_out, int out_size, void* d_ws, size_t ws_size,
                              hipStream_t stream) {
  const float* x  = (const float*)d_in[0];
  const float* W1 = (const float*)d_in[1];
  const float* b1 = (const float*)d_in[2];
  const float* W2 = (const float*)d_in[3];
  const float* b2 = (const float*)d_in[4];
  const float* W3 = (const float*)d_in[5];
  const float* b3 = (const float*)d_in[6];
  const float* W4 = (const float*)d_in[7];
  const float* b4 = (const float*)d_in[8];
  const int* ei   = (const int*)d_in[9];
  const int* batch = (const int*)d_in[10];

  int N = in_sizes[0] / 64;
  int E = in_sizes[9] / 2;
  int G = out_size / 16;
  const int* src = ei;
  const int* dst = ei + E;

  float* ws = (float*)d_ws;
  float* hA     = ws;                          // N*64
  float* xt     = hA + (size_t)N * 64;         // N*64
  float* pooled = xt + (size_t)N * 64;         // G*64
  float* cntg   = pooled + (size_t)G * 64;     // G
  int* ip       = (int*)(cntg + G);
  int* deg      = ip;                          // N (doubles as fill cursor)
  int* locscan  = deg + N;                     // N
  int* rowptr   = locscan + N;                 // N+1
  int* partial  = rowptr + N + 1;              // 256
  int* csr      = partial + 256;               // E
  float* out = (float*)d_out;

  int nbN = (N + 255) / 256;
  int nbE = (E + 255) / 256;
  int nb4 = (N + 3) / 4;

  // ---- CSR build (per call; edges are static inputs) ----
  hipMemsetAsync(deg, 0, (size_t)N * sizeof(int), stream);
  hipMemsetAsync(pooled, 0, ((size_t)G * 64 + G) * sizeof(float), stream);
  k_hist<<<nbE, 256, 0, stream>>>(dst, deg, E);
  k_scanA<<<nbN, 256, 0, stream>>>(deg, locscan, partial, N);
  k_scanB<<<1, 256, 0, stream>>>(partial, nbN);
  k_scanC<<<nbN, 256, 0, stream>>>(locscan, partial, rowptr, N, E);
  k_fill<<<nbE, 256, 0, stream>>>(src, dst, rowptr, deg, csr, E);

  k_count<<<nbN, 256, 0, stream>>>(batch, cntg, N);
  k_init<<<nb4, 256, 0, stream>>>(x, hA, N);

  const float* Ws[3] = {W1, W2, W3};
  const float* bs[3] = {b1, b2, b3};
  for (int l = 0; l < 3; ++l) {
    k_linear<<<nb4, 256, 0, stream>>>(hA, Ws[l], bs[l], xt, N);
    k_gatheragg<<<nb4, 256, 0, stream>>>(rowptr, csr, xt, hA, N,
                                         (l < 2) ? 1 : 0, (l == 2) ? 1 : 0,
                                         batch, pooled);
  }
  k_final<<<G, 64, 0, stream>>>(pooled, cntg, W4, b4, out, G);
}

// Round 4
// 394.287 us; speedup vs baseline: 2.4967x; 1.4202x over previous
//
#include <hip/hip_runtime.h>

#define EPSF 1e-7f
#define MAXNORM (1.0f - 1e-5f)

__device__ __forceinline__ float rsum64(float v) {
#pragma unroll
  for (int m = 32; m; m >>= 1) v += __shfl_xor(v, m, 64);
  return v;
}
__device__ __forceinline__ float rsum16(float v) {
#pragma unroll
  for (int m = 8; m; m >>= 1) v += __shfl_xor(v, m, 64);
  return v;
}

__device__ __forceinline__ float frcp(float x) { return __builtin_amdgcn_rcpf(x); }
__device__ __forceinline__ float fsqrt_(float x) { return __builtin_amdgcn_sqrtf(x); }
__device__ __forceinline__ float tanh_fast(float x) {
  x = fminf(x, 20.f);
  float e = __builtin_amdgcn_exp2f(x * 2.88539008178f);  // e^{2x}
  return (e - 1.f) * frcp(e + 1.f);
}
__device__ __forceinline__ float atanh_fast(float x) {
  // 0.5*ln((1+x)/(1-x)) = 0.5*ln2*log2((1+x)/(1-x))
  return 0.34657359028f * __builtin_amdgcn_logf((1.f + x) * frcp(1.f - x));
}
// logmap0(proj(expmap0(u))) == f(nu) * u, nu = max(||u||, EPS).
// Handles proj-clip (tanh>MAXNORM) and tiny-norm cases like the reference.
__device__ __forceinline__ float lp_exp_log_scale(float nu) {
  float te = tanh_fast(nu);
  float tec = fminf(fmaxf(te, EPSF), MAXNORM);
  return atanh_fast(tec) * frcp(fmaxf(te, EPSF)) * te * frcp(nu);
}

// ---------------- CSR build (by dst) ----------------
__global__ void k_hist(const int* __restrict__ dst, int* __restrict__ deg, int E) {
  int e = blockIdx.x * blockDim.x + threadIdx.x;
  if (e < E) atomicAdd(&deg[dst[e]], 1);
}

__global__ void __launch_bounds__(256) k_scanA(const int* __restrict__ deg,
                                               int* __restrict__ locscan,
                                               int* __restrict__ partial, int N) {
  __shared__ int buf[256];
  int i = blockIdx.x * 256 + threadIdx.x;
  int v = (i < N) ? deg[i] : 0;
  buf[threadIdx.x] = v;
  __syncthreads();
#pragma unroll
  for (int off = 1; off < 256; off <<= 1) {
    int t = (threadIdx.x >= off) ? buf[threadIdx.x - off] : 0;
    __syncthreads();
    buf[threadIdx.x] += t;
    __syncthreads();
  }
  if (i < N) locscan[i] = buf[threadIdx.x] - v;
  if (threadIdx.x == 255) partial[blockIdx.x] = buf[255];
}

__global__ void __launch_bounds__(256) k_scanB(int* __restrict__ partial, int nb) {
  __shared__ int buf[256];
  int v = (threadIdx.x < nb) ? partial[threadIdx.x] : 0;
  buf[threadIdx.x] = v;
  __syncthreads();
#pragma unroll
  for (int off = 1; off < 256; off <<= 1) {
    int t = (threadIdx.x >= off) ? buf[threadIdx.x - off] : 0;
    __syncthreads();
    buf[threadIdx.x] += t;
    __syncthreads();
  }
  if (threadIdx.x < nb) partial[threadIdx.x] = buf[threadIdx.x] - v;
}

__global__ void __launch_bounds__(256) k_scanC(const int* __restrict__ locscan,
                                               const int* __restrict__ partial,
                                               int* __restrict__ rowptr, int N, int E) {
  int i = blockIdx.x * 256 + threadIdx.x;
  if (i < N) rowptr[i] = locscan[i] + partial[blockIdx.x];
  if (i == 0) rowptr[N] = E;
}

__global__ void k_fill(const int* __restrict__ src, const int* __restrict__ dst,
                       const int* __restrict__ rowptr, int* __restrict__ deg,
                       int* __restrict__ csr, int E) {
  int e = blockIdx.x * blockDim.x + threadIdx.x;
  if (e >= E) return;
  int d = dst[e];
  int p = atomicSub(&deg[d], 1) - 1;
  csr[rowptr[d] + p] = src[e];
}

__global__ void k_count(const int* __restrict__ idx, float* __restrict__ cnt, int n) {
  int i = blockIdx.x * blockDim.x + threadIdx.x;
  if (i < n) atomicAdd(&cnt[idx[i]], 1.0f);
}

// hb = proj(expmap0(b)) per layer (3 waves, one per layer); hb2 = ||hb||^2
__global__ void __launch_bounds__(192) k_prepb(const float* __restrict__ b1,
                                               const float* __restrict__ b2,
                                               const float* __restrict__ b3,
                                               float* __restrict__ hb_all,
                                               float* __restrict__ hb2_all) {
  int w = threadIdx.x >> 6, lane = threadIdx.x & 63;
  const float* b = (w == 0) ? b1 : (w == 1) ? b2 : b3;
  float bb = b[lane];
  float nb = fmaxf(fsqrt_(rsum64(bb * bb)), EPSF);
  float tb = tanh_fast(nb);
  float cb = fminf(tb, MAXNORM);           // norm of proj(expmap0(b))
  float hb = cb * frcp(nb) * bb;
  hb_all[w * 64 + lane] = hb;
  if (lane == 0) hb2_all[w] = cb * cb;
}

// shared matvec+hyperbolic tail: y=matvec(t2); mobius bias; emit tangent xt.
__device__ __forceinline__ void linear_tail(float t2, const float* Wl, float* ts,
                                            int wid, int lane, float hbv, float hb2,
                                            float* __restrict__ xt, int node) {
  ts[wid * 64 + lane] = t2;
  const float4* Wrow = reinterpret_cast<const float4*>(&Wl[lane * 68]);
  const float4* tv4 = reinterpret_cast<const float4*>(&ts[wid * 64]);
  float acc = 0.f;
#pragma unroll
  for (int q = 0; q < 16; ++q) {
    float4 w = Wrow[q];
    float4 tq = tv4[q];
    acc = fmaf(w.x, tq.x, acc);
    acc = fmaf(w.y, tq.y, acc);
    acc = fmaf(w.z, tq.z, acc);
    acc = fmaf(w.w, tq.w, acc);
  }
  // proj(expmap0(y)) via analytic norm
  float ny = fmaxf(fsqrt_(rsum64(acc * acc)), EPSF);
  float ty = tanh_fast(ny);
  float cy = fminf(ty, MAXNORM);
  float hyv = cy * frcp(ny) * acc;       // ||hy|| = cy
  float x2 = cy * cy;
  // mobius_add(hy, hb)
  float xy = rsum64(hyv * hbv);
  float a = 1.f + 2.f * xy + hb2;
  float c = 1.f - x2;
  float den = fmaxf(1.f + 2.f * xy + x2 * hb2, EPSF);
  float rv = (a * hyv + c * hbv) * frcp(den);
  // proj + logmap0 composite
  float nr = fmaxf(fsqrt_(rsum64(rv * rv)), EPSF);
  float s = atanh_fast(fminf(nr, MAXNORM)) * frcp(nr);
  xt[(size_t)node * 64 + lane] = s * rv;
}

// layer1: x -> xt1 = logmap0(hyp_linear(proj(expmap0(x)), W1, b1))
__global__ void __launch_bounds__(512) k_lin1(const float* __restrict__ x,
                                              const float* __restrict__ W,
                                              const float* __restrict__ hb,
                                              const float* __restrict__ hb2p,
                                              float* __restrict__ xt, int N) {
  __shared__ __align__(16) float Wl[64 * 68];
  __shared__ __align__(16) float ts[8 * 64];
  int tid = threadIdx.x, wid = tid >> 6, lane = tid & 63;
  for (int i = tid; i < 4096; i += 512) Wl[(i >> 6) * 68 + (i & 63)] = W[i];
  __syncthreads();
  float hbv = hb[lane];
  float hb2 = hb2p[0];
  for (int node = blockIdx.x * 8 + wid; node < N; node += gridDim.x * 8) {
    float xv = x[(size_t)node * 64 + lane];
    float nx = fmaxf(fsqrt_(rsum64(xv * xv)), EPSF);
    float t2 = lp_exp_log_scale(nx) * xv;     // logmap0(proj(expmap0(x)))
    linear_tail(t2, Wl, ts, wid, lane, hbv, hb2, xt, node);
  }
}

// layer boundary: gather-mean(xt_prev) -> hyp_agg finish -> act -> hyp_linear -> xt_next
__global__ void __launch_bounds__(512) k_gatherlin(
    const int* __restrict__ rowptr, const int* __restrict__ csr,
    const float* __restrict__ xtp, const float* __restrict__ W,
    const float* __restrict__ hb, const float* __restrict__ hb2p,
    float* __restrict__ xt, int N) {
  __shared__ __align__(16) float Wl[64 * 68];
  __shared__ __align__(16) float ts[8 * 64];
  int tid = threadIdx.x, wid = tid >> 6, lane = tid & 63;
  for (int i = tid; i < 4096; i += 512) Wl[(i >> 6) * 68 + (i & 63)] = W[i];
  __syncthreads();
  float hbv = hb[lane];
  float hb2 = hb2p[0];
  for (int node = blockIdx.x * 8 + wid; node < N; node += gridDim.x * 8) {
    int r0 = rowptr[node], r1 = rowptr[node + 1];
    float acc = 0.f;
    int j = r0;
    for (; j + 3 < r1; j += 4) {
      int s0 = csr[j], s1 = csr[j + 1], s2 = csr[j + 2], s3 = csr[j + 3];
      acc += xtp[(size_t)s0 * 64 + lane] + xtp[(size_t)s1 * 64 + lane] +
             xtp[(size_t)s2 * 64 + lane] + xtp[(size_t)s3 * 64 + lane];
    }
    for (; j < r1; ++j) acc += xtp[(size_t)csr[j] * 64 + lane];
    float u = acc * frcp(fmaxf((float)(r1 - r0), 1.f));
    // hyp_agg finish + act's logmap composite
    float nu = fmaxf(fsqrt_(rsum64(u * u)), EPSF);
    float t = lp_exp_log_scale(nu) * u;       // logmap0(proj(expmap0(u)))
    t = (t >= 0.f) ? t : 0.2f * t;            // leaky_relu 0.2
    float nt = fmaxf(fsqrt_(rsum64(t * t)), EPSF);
    float t2 = lp_exp_log_scale(nt) * t;      // exp/proj then next-linear's logmap
    linear_tail(t2, Wl, ts, wid, lane, hbv, hb2, xt, node);
  }
}

// layer3 end: gather-mean -> hyp_agg finish -> logmap -> pool atomics
__global__ void __launch_bounds__(256) k_gpool(const int* __restrict__ rowptr,
                                               const int* __restrict__ csr,
                                               const float* __restrict__ xtp,
                                               const int* __restrict__ batch,
                                               float* __restrict__ pooled, int N) {
  int node = blockIdx.x * 4 + (threadIdx.x >> 6);
  if (node >= N) return;
  int lane = threadIdx.x & 63;
  int r0 = rowptr[node], r1 = rowptr[node + 1];
  float acc = 0.f;
  int j = r0;
  for (; j + 3 < r1; j += 4) {
    int s0 = csr[j], s1 = csr[j + 1], s2 = csr[j + 2], s3 = csr[j + 3];
    acc += xtp[(size_t)s0 * 64 + lane] + xtp[(size_t)s1 * 64 + lane] +
           xtp[(size_t)s2 * 64 + lane] + xtp[(size_t)s3 * 64 + lane];
  }
  for (; j < r1; ++j) acc += xtp[(size_t)csr[j] * 64 + lane];
  float u = acc * frcp(fmaxf((float)(r1 - r0), 1.f));
  float nu = fmaxf(fsqrt_(rsum64(u * u)), EPSF);
  float t = lp_exp_log_scale(nu) * u;
  atomicAdd(&pooled[(size_t)batch[node] * 64 + lane], t);
}

// head: per graph, 1 wave (kept precise; ~512 waves total, negligible cost)
__global__ void __launch_bounds__(64) k_final(const float* __restrict__ pooled,
                                              const float* __restrict__ cntg,
                                              const float* __restrict__ W4,
                                              const float* __restrict__ b4,
                                              float* __restrict__ out, int G) {
  int g = blockIdx.x;
  int lane = threadIdx.x;
  float u = pooled[(size_t)g * 64 + lane] / fmaxf(cntg[g], 1.0f);
  float n = fmaxf(sqrtf(rsum64(u * u)), EPSF);
  float e = tanhf(n) * u / n;
  float ne = fmaxf(sqrtf(rsum64(e * e)), EPSF);
  if (ne > MAXNORM) e *= MAXNORM / ne;
  float nn = fmaxf(sqrtf(rsum64(e * e)), EPSF);
  float t = atanhf(fminf(nn, MAXNORM)) * e / nn;

  int row = lane & 15;
  float acc = 0.f;
#pragma unroll
  for (int k = 0; k < 64; ++k) {
    float tk = __shfl(t, k, 64);
    acc = fmaf(W4[row * 64 + k], tk, acc);
  }
  float ny = fmaxf(sqrtf(rsum16(acc * acc)), EPSF);
  float hy = tanhf(ny) * acc / ny;
  float nh = fmaxf(sqrtf(rsum16(hy * hy)), EPSF);
  if (nh > MAXNORM) hy *= MAXNORM / nh;
  float bb = b4[row];
  float nb = fmaxf(sqrtf(rsum16(bb * bb)), EPSF);
  float hb = tanhf(nb) * bb / nb;
  float nhb = fmaxf(sqrtf(rsum16(hb * hb)), EPSF);
  if (nhb > MAXNORM) hb *= MAXNORM / nhb;
  float x2 = rsum16(hy * hy);
  float y2 = rsum16(hb * hb);
  float xy = rsum16(hy * hb);
  float num = (1.f + 2.f * xy + y2) * hy + (1.f - x2) * hb;
  float den = fmaxf(1.f + 2.f * xy + x2 * y2, EPSF);
  float r = num / den;
  float nr = fmaxf(sqrtf(rsum16(r * r)), EPSF);
  if (nr > MAXNORM) r *= MAXNORM / nr;
  if (lane < 16) out[(size_t)g * 16 + lane] = r;
}

extern "C" void kernel_launch(void* const* d_in, const int* in_sizes, int n_in,
                              void* d_out, int out_size, void* d_ws, size_t ws_size,
                              hipStream_t stream) {
  const float* x  = (const float*)d_in[0];
  const float* W1 = (const float*)d_in[1];
  const float* b1 = (const float*)d_in[2];
  const float* W2 = (const float*)d_in[3];
  const float* b2 = (const float*)d_in[4];
  const float* W3 = (const float*)d_in[5];
  const float* b3 = (const float*)d_in[6];
  const float* W4 = (const float*)d_in[7];
  const float* b4 = (const float*)d_in[8];
  const int* ei   = (const int*)d_in[9];
  const int* batch = (const int*)d_in[10];

  int N = in_sizes[0] / 64;
  int E = in_sizes[9] / 2;
  int G = out_size / 16;
  const int* src = ei;
  const int* dst = ei + E;

  float* ws = (float*)d_ws;
  float* xtA    = ws;                          // N*64
  float* xtB    = xtA + (size_t)N * 64;        // N*64
  float* pooled = xtB + (size_t)N * 64;        // G*64
  float* cntg   = pooled + (size_t)G * 64;     // G
  float* hb_all = cntg + G;                    // 192
  float* hb2_all = hb_all + 192;               // 4 (pad)
  int* ip       = (int*)(hb2_all + 4);
  int* deg      = ip;                          // N
  int* locscan  = deg + N;                     // N
  int* rowptr   = locscan + N;                 // N+1
  int* partial  = rowptr + N + 1;              // 256
  int* csr      = partial + 256;               // E
  float* out = (float*)d_out;

  int nbN = (N + 255) / 256;
  int nbE = (E + 255) / 256;
  int nb4 = (N + 3) / 4;

  hipMemsetAsync(deg, 0, (size_t)N * sizeof(int), stream);
  hipMemsetAsync(pooled, 0, ((size_t)G * 64 + G) * sizeof(float), stream);

  k_hist<<<nbE, 256, 0, stream>>>(dst, deg, E);
  k_scanA<<<nbN, 256, 0, stream>>>(deg, locscan, partial, N);
  k_scanB<<<1, 256, 0, stream>>>(partial, nbN);
  k_scanC<<<nbN, 256, 0, stream>>>(locscan, partial, rowptr, N, E);
  k_fill<<<nbE, 256, 0, stream>>>(src, dst, rowptr, deg, csr, E);

  k_count<<<nbN, 256, 0, stream>>>(batch, cntg, N);
  k_prepb<<<1, 192, 0, stream>>>(b1, b2, b3, hb_all, hb2_all);

  k_lin1<<<2048, 512, 0, stream>>>(x, W1, hb_all, hb2_all, xtA, N);
  k_gatherlin<<<2048, 512, 0, stream>>>(rowptr, csr, xtA, W2, hb_all + 64,
                                        hb2_all + 1, xtB, N);
  k_gatherlin<<<2048, 512, 0, stream>>>(rowptr, csr, xtB, W3, hb_all + 128,
                                        hb2_all + 2, xtA, N);
  k_gpool<<<nb4, 256, 0, stream>>>(rowptr, csr, xtA, batch, pooled, N);
  k_final<<<G, 64, 0, stream>>>(pooled, cntg, W4, b4, out, G);
}

// Round 5
// 372.860 us; speedup vs baseline: 2.6402x; 1.0575x over previous
//
#include <hip/hip_runtime.h>

#define EPSF 1e-7f
#define MAXNORM (1.0f - 1e-5f)

__device__ __forceinline__ float rsum64(float v) {
#pragma unroll
  for (int m = 32; m; m >>= 1) v += __shfl_xor(v, m, 64);
  return v;
}
__device__ __forceinline__ float rsum16(float v) {
#pragma unroll
  for (int m = 8; m; m >>= 1) v += __shfl_xor(v, m, 64);
  return v;
}

__device__ __forceinline__ float frcp(float x) { return __builtin_amdgcn_rcpf(x); }
__device__ __forceinline__ float fsqrt_(float x) { return __builtin_amdgcn_sqrtf(x); }
__device__ __forceinline__ float tanh_fast(float x) {
  x = fminf(x, 20.f);
  float e = __builtin_amdgcn_exp2f(x * 2.88539008178f);  // e^{2x}
  return (e - 1.f) * frcp(e + 1.f);
}
__device__ __forceinline__ float atanh_fast(float x) {
  return 0.34657359028f * __builtin_amdgcn_logf((1.f + x) * frcp(1.f - x));
}
// logmap0(proj(expmap0(u))) == f(nu) * u, nu = max(||u||, EPS).
__device__ __forceinline__ float lp_exp_log_scale(float nu) {
  float te = tanh_fast(nu);
  float tec = fminf(fmaxf(te, EPSF), MAXNORM);
  return atanh_fast(tec) * frcp(fmaxf(te, EPSF)) * te * frcp(nu);
}

// gather-mean over CSR row [r0,r1) of 64-dim f32 rows; returns per-lane dim value.
// float4-per-lane: one wave instruction gathers 4 rows (1KB); 2 accs for MLP.
__device__ __forceinline__ float gather_mean(const int* __restrict__ csr,
                                             const float* __restrict__ xtp,
                                             int r0, int r1, int lane) {
  int grp = lane >> 4;          // which of 4 rows this lane helps load
  int sub = lane & 15;          // 16 lanes * float4 = 64 floats
  float4 a0 = {0.f, 0.f, 0.f, 0.f}, a1 = {0.f, 0.f, 0.f, 0.f};
  int j = r0;
  for (; j + 8 <= r1; j += 8) {
    int i0 = csr[j + grp];
    int i1 = csr[j + 4 + grp];
    float4 v0 = *reinterpret_cast<const float4*>(&xtp[(size_t)i0 * 64 + sub * 4]);
    float4 v1 = *reinterpret_cast<const float4*>(&xtp[(size_t)i1 * 64 + sub * 4]);
    a0.x += v0.x; a0.y += v0.y; a0.z += v0.z; a0.w += v0.w;
    a1.x += v1.x; a1.y += v1.y; a1.z += v1.z; a1.w += v1.w;
  }
  if (j + 4 <= r1) {
    int i0 = csr[j + grp];
    float4 v0 = *reinterpret_cast<const float4*>(&xtp[(size_t)i0 * 64 + sub * 4]);
    a0.x += v0.x; a0.y += v0.y; a0.z += v0.z; a0.w += v0.w;
    j += 4;
  }
  float accS = 0.f;
  for (; j < r1; ++j) accS += xtp[(size_t)csr[j] * 64 + lane];
  a0.x += a1.x; a0.y += a1.y; a0.z += a1.z; a0.w += a1.w;
  // sum the 4 lane-groups (each holds partial sums for dims of (lane&15))
#pragma unroll
  for (int m = 16; m <= 32; m <<= 1) {
    a0.x += __shfl_xor(a0.x, m, 64);
    a0.y += __shfl_xor(a0.y, m, 64);
    a0.z += __shfl_xor(a0.z, m, 64);
    a0.w += __shfl_xor(a0.w, m, 64);
  }
  // redistribute: lane d wants component (d&3) of lane (d>>2)
  int srcl = lane >> 2;
  float c0 = __shfl(a0.x, srcl, 64);
  float c1 = __shfl(a0.y, srcl, 64);
  float c2 = __shfl(a0.z, srcl, 64);
  float c3 = __shfl(a0.w, srcl, 64);
  int sel = lane & 3;
  float g = (sel == 0) ? c0 : (sel == 1) ? c1 : (sel == 2) ? c2 : c3;
  return g + accS;
}

// ---------------- CSR build (by dst) ----------------
__global__ void k_hist(const int* __restrict__ dst, int* __restrict__ deg, int E) {
  int e = blockIdx.x * blockDim.x + threadIdx.x;
  if (e < E) atomicAdd(&deg[dst[e]], 1);
}

__global__ void __launch_bounds__(256) k_scanA(const int* __restrict__ deg,
                                               int* __restrict__ locscan,
                                               int* __restrict__ partial, int N) {
  __shared__ int buf[256];
  int i = blockIdx.x * 256 + threadIdx.x;
  int v = (i < N) ? deg[i] : 0;
  buf[threadIdx.x] = v;
  __syncthreads();
#pragma unroll
  for (int off = 1; off < 256; off <<= 1) {
    int t = (threadIdx.x >= off) ? buf[threadIdx.x - off] : 0;
    __syncthreads();
    buf[threadIdx.x] += t;
    __syncthreads();
  }
  if (i < N) locscan[i] = buf[threadIdx.x] - v;
  if (threadIdx.x == 255) partial[blockIdx.x] = buf[255];
}

__global__ void __launch_bounds__(256) k_scanB(int* __restrict__ partial, int nb) {
  __shared__ int buf[256];
  int v = (threadIdx.x < nb) ? partial[threadIdx.x] : 0;
  buf[threadIdx.x] = v;
  __syncthreads();
#pragma unroll
  for (int off = 1; off < 256; off <<= 1) {
    int t = (threadIdx.x >= off) ? buf[threadIdx.x - off] : 0;
    __syncthreads();
    buf[threadIdx.x] += t;
    __syncthreads();
  }
  if (threadIdx.x < nb) partial[threadIdx.x] = buf[threadIdx.x] - v;
}

__global__ void __launch_bounds__(256) k_scanC(const int* __restrict__ locscan,
                                               const int* __restrict__ partial,
                                               int* __restrict__ rowptr, int N, int E) {
  int i = blockIdx.x * 256 + threadIdx.x;
  if (i < N) rowptr[i] = locscan[i] + partial[blockIdx.x];
  if (i == 0) rowptr[N] = E;
}

__global__ void k_fill(const int* __restrict__ src, const int* __restrict__ dst,
                       const int* __restrict__ rowptr, int* __restrict__ deg,
                       int* __restrict__ csr, int E) {
  int e = blockIdx.x * blockDim.x + threadIdx.x;
  if (e >= E) return;
  int d = dst[e];
  int p = atomicSub(&deg[d], 1) - 1;
  csr[rowptr[d] + p] = src[e];
}

__global__ void k_count(const int* __restrict__ idx, float* __restrict__ cnt, int n) {
  int i = blockIdx.x * blockDim.x + threadIdx.x;
  if (i < n) atomicAdd(&cnt[idx[i]], 1.0f);
}

// hb = proj(expmap0(b)) per layer; hb2 = ||hb||^2
__global__ void __launch_bounds__(192) k_prepb(const float* __restrict__ b1,
                                               const float* __restrict__ b2,
                                               const float* __restrict__ b3,
                                               float* __restrict__ hb_all,
                                               float* __restrict__ hb2_all) {
  int w = threadIdx.x >> 6, lane = threadIdx.x & 63;
  const float* b = (w == 0) ? b1 : (w == 1) ? b2 : b3;
  float bb = b[lane];
  float nb = fmaxf(fsqrt_(rsum64(bb * bb)), EPSF);
  float tb = tanh_fast(nb);
  float cb = fminf(tb, MAXNORM);
  float hb = cb * frcp(nb) * bb;
  hb_all[w * 64 + lane] = hb;
  if (lane == 0) hb2_all[w] = cb * cb;
}

// shared matvec+hyperbolic tail: y=matvec(t2); mobius bias; emit tangent xt.
__device__ __forceinline__ void linear_tail(float t2, const float* Wl, float* ts,
                                            int wid, int lane, float hbv, float hb2,
                                            float* __restrict__ xt, int node) {
  ts[wid * 64 + lane] = t2;
  const float4* Wrow = reinterpret_cast<const float4*>(&Wl[lane * 68]);
  const float4* tv4 = reinterpret_cast<const float4*>(&ts[wid * 64]);
  float acc = 0.f;
#pragma unroll
  for (int q = 0; q < 16; ++q) {
    float4 w = Wrow[q];
    float4 tq = tv4[q];
    acc = fmaf(w.x, tq.x, acc);
    acc = fmaf(w.y, tq.y, acc);
    acc = fmaf(w.z, tq.z, acc);
    acc = fmaf(w.w, tq.w, acc);
  }
  float ny = fmaxf(fsqrt_(rsum64(acc * acc)), EPSF);
  float ty = tanh_fast(ny);
  float cy = fminf(ty, MAXNORM);
  float hyv = cy * frcp(ny) * acc;
  float x2 = cy * cy;
  float xy = rsum64(hyv * hbv);
  float a = 1.f + 2.f * xy + hb2;
  float c = 1.f - x2;
  float den = fmaxf(1.f + 2.f * xy + x2 * hb2, EPSF);
  float rv = (a * hyv + c * hbv) * frcp(den);
  float nr = fmaxf(fsqrt_(rsum64(rv * rv)), EPSF);
  float s = atanh_fast(fminf(nr, MAXNORM)) * frcp(nr);
  xt[(size_t)node * 64 + lane] = s * rv;
}

// layer1: x -> xt1 = logmap0(hyp_linear(proj(expmap0(x)), W1, b1))
__global__ void __launch_bounds__(512) k_lin1(const float* __restrict__ x,
                                              const float* __restrict__ W,
                                              const float* __restrict__ hb,
                                              const float* __restrict__ hb2p,
                                              float* __restrict__ xt, int N) {
  __shared__ __align__(16) float Wl[64 * 68];
  __shared__ __align__(16) float ts[8 * 64];
  int tid = threadIdx.x, wid = tid >> 6, lane = tid & 63;
  for (int i = tid; i < 4096; i += 512) Wl[(i >> 6) * 68 + (i & 63)] = W[i];
  __syncthreads();
  float hbv = hb[lane];
  float hb2 = hb2p[0];
  for (int node = blockIdx.x * 8 + wid; node < N; node += gridDim.x * 8) {
    float xv = x[(size_t)node * 64 + lane];
    float nx = fmaxf(fsqrt_(rsum64(xv * xv)), EPSF);
    float t2 = lp_exp_log_scale(nx) * xv;
    linear_tail(t2, Wl, ts, wid, lane, hbv, hb2, xt, node);
  }
}

// layer boundary: gather-mean(xt_prev) -> hyp_agg -> act -> hyp_linear -> xt_next
__global__ void __launch_bounds__(512) k_gatherlin(
    const int* __restrict__ rowptr, const int* __restrict__ csr,
    const float* __restrict__ xtp, const float* __restrict__ W,
    const float* __restrict__ hb, const float* __restrict__ hb2p,
    float* __restrict__ xt, int N) {
  __shared__ __align__(16) float Wl[64 * 68];
  __shared__ __align__(16) float ts[8 * 64];
  int tid = threadIdx.x, wid = tid >> 6, lane = tid & 63;
  for (int i = tid; i < 4096; i += 512) Wl[(i >> 6) * 68 + (i & 63)] = W[i];
  __syncthreads();
  float hbv = hb[lane];
  float hb2 = hb2p[0];
  for (int node = blockIdx.x * 8 + wid; node < N; node += gridDim.x * 8) {
    int r0 = rowptr[node], r1 = rowptr[node + 1];
    float acc = gather_mean(csr, xtp, r0, r1, lane);
    float u = acc * frcp(fmaxf((float)(r1 - r0), 1.f));
    float nu = fmaxf(fsqrt_(rsum64(u * u)), EPSF);
    float t = lp_exp_log_scale(nu) * u;
    t = (t >= 0.f) ? t : 0.2f * t;
    float nt = fmaxf(fsqrt_(rsum64(t * t)), EPSF);
    float t2 = lp_exp_log_scale(nt) * t;
    linear_tail(t2, Wl, ts, wid, lane, hbv, hb2, xt, node);
  }
}

// layer3 end: gather-mean -> hyp_agg finish -> logmap -> pool atomics
__global__ void __launch_bounds__(256) k_gpool(const int* __restrict__ rowptr,
                                               const int* __restrict__ csr,
                                               const float* __restrict__ xtp,
                                               const int* __restrict__ batch,
                                               float* __restrict__ pooled, int N) {
  int node = blockIdx.x * 4 + (threadIdx.x >> 6);
  if (node >= N) return;
  int lane = threadIdx.x & 63;
  int r0 = rowptr[node], r1 = rowptr[node + 1];
  float acc = gather_mean(csr, xtp, r0, r1, lane);
  float u = acc * frcp(fmaxf((float)(r1 - r0), 1.f));
  float nu = fmaxf(fsqrt_(rsum64(u * u)), EPSF);
  float t = lp_exp_log_scale(nu) * u;
  atomicAdd(&pooled[(size_t)batch[node] * 64 + lane], t);
}

// head: per graph, 1 wave (precise; negligible cost)
__global__ void __launch_bounds__(64) k_final(const float* __restrict__ pooled,
                                              const float* __restrict__ cntg,
                                              const float* __restrict__ W4,
                                              const float* __restrict__ b4,
                                              float* __restrict__ out, int G) {
  int g = blockIdx.x;
  int lane = threadIdx.x;
  float u = pooled[(size_t)g * 64 + lane] / fmaxf(cntg[g], 1.0f);
  float n = fmaxf(sqrtf(rsum64(u * u)), EPSF);
  float e = tanhf(n) * u / n;
  float ne = fmaxf(sqrtf(rsum64(e * e)), EPSF);
  if (ne > MAXNORM) e *= MAXNORM / ne;
  float nn = fmaxf(sqrtf(rsum64(e * e)), EPSF);
  float t = atanhf(fminf(nn, MAXNORM)) * e / nn;

  int row = lane & 15;
  float acc = 0.f;
#pragma unroll
  for (int k = 0; k < 64; ++k) {
    float tk = __shfl(t, k, 64);
    acc = fmaf(W4[row * 64 + k], tk, acc);
  }
  float ny = fmaxf(sqrtf(rsum16(acc * acc)), EPSF);
  float hy = tanhf(ny) * acc / ny;
  float nh = fmaxf(sqrtf(rsum16(hy * hy)), EPSF);
  if (nh > MAXNORM) hy *= MAXNORM / nh;
  float bb = b4[row];
  float nb = fmaxf(sqrtf(rsum16(bb * bb)), EPSF);
  float hb = tanhf(nb) * bb / nb;
  float nhb = fmaxf(sqrtf(rsum16(hb * hb)), EPSF);
  if (nhb > MAXNORM) hb *= MAXNORM / nhb;
  float x2 = rsum16(hy * hy);
  float y2 = rsum16(hb * hb);
  float xy = rsum16(hy * hb);
  float num = (1.f + 2.f * xy + y2) * hy + (1.f - x2) * hb;
  float den = fmaxf(1.f + 2.f * xy + x2 * y2, EPSF);
  float r = num / den;
  float nr = fmaxf(sqrtf(rsum16(r * r)), EPSF);
  if (nr > MAXNORM) r *= MAXNORM / nr;
  if (lane < 16) out[(size_t)g * 16 + lane] = r;
}

extern "C" void kernel_launch(void* const* d_in, const int* in_sizes, int n_in,
                              void* d_out, int out_size, void* d_ws, size_t ws_size,
                              hipStream_t stream) {
  const float* x  = (const float*)d_in[0];
  const float* W1 = (const float*)d_in[1];
  const float* b1 = (const float*)d_in[2];
  const float* W2 = (const float*)d_in[3];
  const float* b2 = (const float*)d_in[4];
  const float* W3 = (const float*)d_in[5];
  const float* b3 = (const float*)d_in[6];
  const float* W4 = (const float*)d_in[7];
  const float* b4 = (const float*)d_in[8];
  const int* ei   = (const int*)d_in[9];
  const int* batch = (const int*)d_in[10];

  int N = in_sizes[0] / 64;
  int E = in_sizes[9] / 2;
  int G = out_size / 16;
  const int* src = ei;
  const int* dst = ei + E;

  float* ws = (float*)d_ws;
  float* xtA    = ws;                          // N*64
  float* xtB    = xtA + (size_t)N * 64;        // N*64
  float* pooled = xtB + (size_t)N * 64;        // G*64
  float* cntg   = pooled + (size_t)G * 64;     // G
  float* hb_all = cntg + G;                    // 192
  float* hb2_all = hb_all + 192;               // 4 (pad)
  int* ip       = (int*)(hb2_all + 4);
  int* deg      = ip;                          // N
  int* locscan  = deg + N;                     // N
  int* rowptr   = locscan + N;                 // N+1
  int* partial  = rowptr + N + 1;              // 256
  int* csr      = partial + 256;               // E
  float* out = (float*)d_out;

  int nbN = (N + 255) / 256;
  int nbE = (E + 255) / 256;
  int nb4 = (N + 3) / 4;

  hipMemsetAsync(deg, 0, (size_t)N * sizeof(int), stream);
  hipMemsetAsync(pooled, 0, ((size_t)G * 64 + G) * sizeof(float), stream);

  k_hist<<<nbE, 256, 0, stream>>>(dst, deg, E);
  k_scanA<<<nbN, 256, 0, stream>>>(deg, locscan, partial, N);
  k_scanB<<<1, 256, 0, stream>>>(partial, nbN);
  k_scanC<<<nbN, 256, 0, stream>>>(locscan, partial, rowptr, N, E);
  k_fill<<<nbE, 256, 0, stream>>>(src, dst, rowptr, deg, csr, E);

  k_count<<<nbN, 256, 0, stream>>>(batch, cntg, N);
  k_prepb<<<1, 192, 0, stream>>>(b1, b2, b3, hb_all, hb2_all);

  k_lin1<<<2048, 512, 0, stream>>>(x, W1, hb_all, hb2_all, xtA, N);
  k_gatherlin<<<2048, 512, 0, stream>>>(rowptr, csr, xtA, W2, hb_all + 64,
                                        hb2_all + 1, xtB, N);
  k_gatherlin<<<2048, 512, 0, stream>>>(rowptr, csr, xtB, W3, hb_all + 128,
                                        hb2_all + 2, xtA, N);
  k_gpool<<<nb4, 256, 0, stream>>>(rowptr, csr, xtA, batch, pooled, N);
  k_final<<<G, 64, 0, stream>>>(pooled, cntg, W4, b4, out, G);
}

// Round 6
// 329.676 us; speedup vs baseline: 2.9860x; 1.1310x over previous
//
#include <hip/hip_runtime.h>

#define EPSF 1e-7f
#define MAXNORM (1.0f - 1e-5f)

__device__ __forceinline__ float rsum64(float v) {
#pragma unroll
  for (int m = 32; m; m >>= 1) v += __shfl_xor(v, m, 64);
  return v;
}
__device__ __forceinline__ float rsum16(float v) {
#pragma unroll
  for (int m = 8; m; m >>= 1) v += __shfl_xor(v, m, 64);
  return v;
}

__device__ __forceinline__ float frcp(float x) { return __builtin_amdgcn_rcpf(x); }
__device__ __forceinline__ float fsqrt_(float x) { return __builtin_amdgcn_sqrtf(x); }
__device__ __forceinline__ float tanh_fast(float x) {
  x = fminf(x, 20.f);
  float e = __builtin_amdgcn_exp2f(x * 2.88539008178f);  // e^{2x}
  return (e - 1.f) * frcp(e + 1.f);
}
__device__ __forceinline__ float atanh_fast(float x) {
  return 0.34657359028f * __builtin_amdgcn_logf((1.f + x) * frcp(1.f - x));
}
// logmap0(proj(expmap0(u))) == f(nu) * u, nu = max(||u||, EPS).
__device__ __forceinline__ float lp_exp_log_scale(float nu) {
  float te = tanh_fast(nu);
  float tec = fminf(fmaxf(te, EPSF), MAXNORM);
  return atanh_fast(tec) * frcp(fmaxf(te, EPSF)) * te * frcp(nu);
}

// gather-sum over CSR row [r0,r1): indices hoisted to registers (one coalesced
// load per 64 edges), then all row-gathers are independent (shfl-derived idx).
__device__ __forceinline__ float gather_sum(const int* __restrict__ csr,
                                            const float* __restrict__ xtp,
                                            int r0, int r1, int lane) {
  int grp = lane >> 4;   // which of 4 rows this lane helps load
  int sub = lane & 15;   // 16 lanes * float4 = 64 floats
  float4 a0 = {0.f, 0.f, 0.f, 0.f}, a1 = {0.f, 0.f, 0.f, 0.f};
  float accS = 0.f;
  int deg = r1 - r0;
  int base = 0;
  while (base < deg) {
    int chunk = min(64, deg - base);
    int eidx = (lane < chunk) ? csr[r0 + base + lane] : 0;
    int c = 0;
    for (; c + 8 <= chunk; c += 8) {
      int i0 = __shfl(eidx, c + grp, 64);
      int i1 = __shfl(eidx, c + 4 + grp, 64);
      float4 v0 = *reinterpret_cast<const float4*>(&xtp[(size_t)i0 * 64 + sub * 4]);
      float4 v1 = *reinterpret_cast<const float4*>(&xtp[(size_t)i1 * 64 + sub * 4]);
      a0.x += v0.x; a0.y += v0.y; a0.z += v0.z; a0.w += v0.w;
      a1.x += v1.x; a1.y += v1.y; a1.z += v1.z; a1.w += v1.w;
    }
    if (c + 4 <= chunk) {
      int i0 = __shfl(eidx, c + grp, 64);
      float4 v0 = *reinterpret_cast<const float4*>(&xtp[(size_t)i0 * 64 + sub * 4]);
      a0.x += v0.x; a0.y += v0.y; a0.z += v0.z; a0.w += v0.w;
      c += 4;
    }
    for (; c < chunk; ++c) {
      int i = __shfl(eidx, c, 64);
      accS += xtp[(size_t)i * 64 + lane];
    }
    base += chunk;
  }
  a0.x += a1.x; a0.y += a1.y; a0.z += a1.z; a0.w += a1.w;
#pragma unroll
  for (int m = 16; m <= 32; m <<= 1) {
    a0.x += __shfl_xor(a0.x, m, 64);
    a0.y += __shfl_xor(a0.y, m, 64);
    a0.z += __shfl_xor(a0.z, m, 64);
    a0.w += __shfl_xor(a0.w, m, 64);
  }
  int srcl = lane >> 2;
  float c0 = __shfl(a0.x, srcl, 64);
  float c1 = __shfl(a0.y, srcl, 64);
  float c2 = __shfl(a0.z, srcl, 64);
  float c3 = __shfl(a0.w, srcl, 64);
  int sel = lane & 3;
  float g = (sel == 0) ? c0 : (sel == 1) ? c1 : (sel == 2) ? c2 : c3;
  return g + accS;
}

// ---------------- CSR build (by dst) ----------------
__global__ void k_hist(const int* __restrict__ dst, int* __restrict__ deg, int E) {
  int e = blockIdx.x * blockDim.x + threadIdx.x;
  if (e < E) atomicAdd(&deg[dst[e]], 1);
}

__global__ void __launch_bounds__(256) k_scanA(const int* __restrict__ deg,
                                               int* __restrict__ locscan,
                                               int* __restrict__ partial, int N) {
  __shared__ int buf[256];
  int i = blockIdx.x * 256 + threadIdx.x;
  int v = (i < N) ? deg[i] : 0;
  buf[threadIdx.x] = v;
  __syncthreads();
#pragma unroll
  for (int off = 1; off < 256; off <<= 1) {
    int t = (threadIdx.x >= off) ? buf[threadIdx.x - off] : 0;
    __syncthreads();
    buf[threadIdx.x] += t;
    __syncthreads();
  }
  if (i < N) locscan[i] = buf[threadIdx.x] - v;
  if (threadIdx.x == 255) partial[blockIdx.x] = buf[255];
}

__global__ void __launch_bounds__(256) k_scanB(int* __restrict__ partial, int nb) {
  __shared__ int buf[256];
  int v = (threadIdx.x < nb) ? partial[threadIdx.x] : 0;
  buf[threadIdx.x] = v;
  __syncthreads();
#pragma unroll
  for (int off = 1; off < 256; off <<= 1) {
    int t = (threadIdx.x >= off) ? buf[threadIdx.x - off] : 0;
    __syncthreads();
    buf[threadIdx.x] += t;
    __syncthreads();
  }
  if (threadIdx.x < nb) partial[threadIdx.x] = buf[threadIdx.x] - v;
}

__global__ void __launch_bounds__(256) k_scanC(const int* __restrict__ locscan,
                                               const int* __restrict__ partial,
                                               int* __restrict__ rowptr, int N, int E) {
  int i = blockIdx.x * 256 + threadIdx.x;
  if (i < N) rowptr[i] = locscan[i] + partial[blockIdx.x];
  if (i == 0) rowptr[N] = E;
}

__global__ void k_fill(const int* __restrict__ src, const int* __restrict__ dst,
                       const int* __restrict__ rowptr, int* __restrict__ deg,
                       int* __restrict__ csr, int E) {
  int e = blockIdx.x * blockDim.x + threadIdx.x;
  if (e >= E) return;
  int d = dst[e];
  int p = atomicSub(&deg[d], 1) - 1;
  csr[rowptr[d] + p] = src[e];
}

__global__ void k_count(const int* __restrict__ idx, float* __restrict__ cnt, int n) {
  int i = blockIdx.x * blockDim.x + threadIdx.x;
  if (i < n) atomicAdd(&cnt[idx[i]], 1.0f);
}

// hb = proj(expmap0(b)) per layer; hb2 = ||hb||^2
__global__ void __launch_bounds__(192) k_prepb(const float* __restrict__ b1,
                                               const float* __restrict__ b2,
                                               const float* __restrict__ b3,
                                               float* __restrict__ hb_all,
                                               float* __restrict__ hb2_all) {
  int w = threadIdx.x >> 6, lane = threadIdx.x & 63;
  const float* b = (w == 0) ? b1 : (w == 1) ? b2 : b3;
  float bb = b[lane];
  float nb = fmaxf(fsqrt_(rsum64(bb * bb)), EPSF);
  float tb = tanh_fast(nb);
  float cb = fminf(tb, MAXNORM);
  float hb = cb * frcp(nb) * bb;
  hb_all[w * 64 + lane] = hb;
  if (lane == 0) hb2_all[w] = cb * cb;
}

// mobius bias + proj + logmap0 tail for one matvec result
__device__ __forceinline__ float mobius_out(float acc, float hbv, float hb2) {
  float ny = fmaxf(fsqrt_(rsum64(acc * acc)), EPSF);
  float ty = tanh_fast(ny);
  float cy = fminf(ty, MAXNORM);
  float hyv = cy * frcp(ny) * acc;
  float x2 = cy * cy;
  float xy = rsum64(hyv * hbv);
  float a = 1.f + 2.f * xy + hb2;
  float c = 1.f - x2;
  float den = fmaxf(1.f + 2.f * xy + x2 * hb2, EPSF);
  float rv = (a * hyv + c * hbv) * frcp(den);
  float nr = fmaxf(fsqrt_(rsum64(rv * rv)), EPSF);
  float s = atanh_fast(fminf(nr, MAXNORM)) * frcp(nr);
  return s * rv;
}

// matvec for a node pair; W-row float4 reads shared by both nodes.
__device__ __forceinline__ void matvec_pair(const float* Wl, float* ts, int wid,
                                            int lane, float t2a, float t2b,
                                            float& acca, float& accb) {
  float* tsw = ts + wid * 128;
  tsw[lane] = t2a;
  tsw[64 + lane] = t2b;
  const float4* Wrow = reinterpret_cast<const float4*>(&Wl[lane * 68]);
  const float4* ta4 = reinterpret_cast<const float4*>(tsw);
  const float4* tb4 = reinterpret_cast<const float4*>(tsw + 64);
  float a = 0.f, b = 0.f;
#pragma unroll
  for (int q = 0; q < 16; ++q) {
    float4 w = Wrow[q];
    float4 ta = ta4[q];
    float4 tb = tb4[q];
    a = fmaf(w.x, ta.x, a); a = fmaf(w.y, ta.y, a);
    a = fmaf(w.z, ta.z, a); a = fmaf(w.w, ta.w, a);
    b = fmaf(w.x, tb.x, b); b = fmaf(w.y, tb.y, b);
    b = fmaf(w.z, tb.z, b); b = fmaf(w.w, tb.w, b);
  }
  acca = a; accb = b;
}

// layer1 (node-pair): x -> xt1
__global__ void __launch_bounds__(512) k_lin1(const float* __restrict__ x,
                                              const float* __restrict__ W,
                                              const float* __restrict__ hb,
                                              const float* __restrict__ hb2p,
                                              float* __restrict__ xt, int N) {
  __shared__ __align__(16) float Wl[64 * 68];
  __shared__ __align__(16) float ts[8 * 128];
  int tid = threadIdx.x, wid = tid >> 6, lane = tid & 63;
  for (int i = tid; i < 4096; i += 512) Wl[(i >> 6) * 68 + (i & 63)] = W[i];
  __syncthreads();
  float hbv = hb[lane];
  float hb2 = hb2p[0];
  int pairs = (N + 1) >> 1;
  for (int p = blockIdx.x * 8 + wid; p < pairs; p += gridDim.x * 8) {
    int n0 = 2 * p, n1 = n0 + 1;
    bool v1 = n1 < N;
    float xa = x[(size_t)n0 * 64 + lane];
    float xb = v1 ? x[(size_t)n1 * 64 + lane] : 0.f;
    float na = fmaxf(fsqrt_(rsum64(xa * xa)), EPSF);
    float nb = fmaxf(fsqrt_(rsum64(xb * xb)), EPSF);
    float t2a = lp_exp_log_scale(na) * xa;
    float t2b = lp_exp_log_scale(nb) * xb;
    float acca, accb;
    matvec_pair(Wl, ts, wid, lane, t2a, t2b, acca, accb);
    float oa = mobius_out(acca, hbv, hb2);
    float ob = mobius_out(accb, hbv, hb2);
    xt[(size_t)n0 * 64 + lane] = oa;
    if (v1) xt[(size_t)n1 * 64 + lane] = ob;
  }
}

// layer boundary (node-pair): gather-mean -> hyp_agg -> act -> hyp_linear -> xt
__global__ void __launch_bounds__(512) k_gatherlin(
    const int* __restrict__ rowptr, const int* __restrict__ csr,
    const float* __restrict__ xtp, const float* __restrict__ W,
    const float* __restrict__ hb, const float* __restrict__ hb2p,
    float* __restrict__ xt, int N) {
  __shared__ __align__(16) float Wl[64 * 68];
  __shared__ __align__(16) float ts[8 * 128];
  int tid = threadIdx.x, wid = tid >> 6, lane = tid & 63;
  for (int i = tid; i < 4096; i += 512) Wl[(i >> 6) * 68 + (i & 63)] = W[i];
  __syncthreads();
  float hbv = hb[lane];
  float hb2 = hb2p[0];
  int pairs = (N + 1) >> 1;
  for (int p = blockIdx.x * 8 + wid; p < pairs; p += gridDim.x * 8) {
    int n0 = 2 * p, n1 = n0 + 1;
    bool v1 = n1 < N;
    int r0a = rowptr[n0], r1a = rowptr[n0 + 1];
    int r0b = r1a, r1b = v1 ? rowptr[n1 + 1] : r1a;
    float sa = gather_sum(csr, xtp, r0a, r1a, lane);
    float sb = gather_sum(csr, xtp, r0b, r1b, lane);
    float ua = sa * frcp(fmaxf((float)(r1a - r0a), 1.f));
    float ub = sb * frcp(fmaxf((float)(r1b - r0b), 1.f));
    float nua = fmaxf(fsqrt_(rsum64(ua * ua)), EPSF);
    float nub = fmaxf(fsqrt_(rsum64(ub * ub)), EPSF);
    float ta = lp_exp_log_scale(nua) * ua;
    float tb = lp_exp_log_scale(nub) * ub;
    ta = (ta >= 0.f) ? ta : 0.2f * ta;
    tb = (tb >= 0.f) ? tb : 0.2f * tb;
    float nta = fmaxf(fsqrt_(rsum64(ta * ta)), EPSF);
    float ntb = fmaxf(fsqrt_(rsum64(tb * tb)), EPSF);
    float t2a = lp_exp_log_scale(nta) * ta;
    float t2b = lp_exp_log_scale(ntb) * tb;
    float acca, accb;
    matvec_pair(Wl, ts, wid, lane, t2a, t2b, acca, accb);
    float oa = mobius_out(acca, hbv, hb2);
    float ob = mobius_out(accb, hbv, hb2);
    xt[(size_t)n0 * 64 + lane] = oa;
    if (v1) xt[(size_t)n1 * 64 + lane] = ob;
  }
}

// layer3 end (node-pair): gather-mean -> hyp_agg -> logmap -> pool atomics
__global__ void __launch_bounds__(256) k_gpool(const int* __restrict__ rowptr,
                                               const int* __restrict__ csr,
                                               const float* __restrict__ xtp,
                                               const int* __restrict__ batch,
                                               float* __restrict__ pooled, int N) {
  int p = blockIdx.x * 4 + (threadIdx.x >> 6);
  int pairs = (N + 1) >> 1;
  if (p >= pairs) return;
  int lane = threadIdx.x & 63;
  int n0 = 2 * p, n1 = n0 + 1;
  bool v1 = n1 < N;
  int r0a = rowptr[n0], r1a = rowptr[n0 + 1];
  int r0b = r1a, r1b = v1 ? rowptr[n1 + 1] : r1a;
  float sa = gather_sum(csr, xtp, r0a, r1a, lane);
  float sb = gather_sum(csr, xtp, r0b, r1b, lane);
  float ua = sa * frcp(fmaxf((float)(r1a - r0a), 1.f));
  float ub = sb * frcp(fmaxf((float)(r1b - r0b), 1.f));
  float nua = fmaxf(fsqrt_(rsum64(ua * ua)), EPSF);
  float nub = fmaxf(fsqrt_(rsum64(ub * ub)), EPSF);
  float ta = lp_exp_log_scale(nua) * ua;
  float tb = lp_exp_log_scale(nub) * ub;
  atomicAdd(&pooled[(size_t)batch[n0] * 64 + lane], ta);
  if (v1) atomicAdd(&pooled[(size_t)batch[n1] * 64 + lane], tb);
}

// head: per graph, 1 wave (precise; negligible cost)
__global__ void __launch_bounds__(64) k_final(const float* __restrict__ pooled,
                                              const float* __restrict__ cntg,
                                              const float* __restrict__ W4,
                                              const float* __restrict__ b4,
                                              float* __restrict__ out, int G) {
  int g = blockIdx.x;
  int lane = threadIdx.x;
  float u = pooled[(size_t)g * 64 + lane] / fmaxf(cntg[g], 1.0f);
  float n = fmaxf(sqrtf(rsum64(u * u)), EPSF);
  float e = tanhf(n) * u / n;
  float ne = fmaxf(sqrtf(rsum64(e * e)), EPSF);
  if (ne > MAXNORM) e *= MAXNORM / ne;
  float nn = fmaxf(sqrtf(rsum64(e * e)), EPSF);
  float t = atanhf(fminf(nn, MAXNORM)) * e / nn;

  int row = lane & 15;
  float acc = 0.f;
#pragma unroll
  for (int k = 0; k < 64; ++k) {
    float tk = __shfl(t, k, 64);
    acc = fmaf(W4[row * 64 + k], tk, acc);
  }
  float ny = fmaxf(sqrtf(rsum16(acc * acc)), EPSF);
  float hy = tanhf(ny) * acc / ny;
  float nh = fmaxf(sqrtf(rsum16(hy * hy)), EPSF);
  if (nh > MAXNORM) hy *= MAXNORM / nh;
  float bb = b4[row];
  float nb = fmaxf(sqrtf(rsum16(bb * bb)), EPSF);
  float hb = tanhf(nb) * bb / nb;
  float nhb = fmaxf(sqrtf(rsum16(hb * hb)), EPSF);
  if (nhb > MAXNORM) hb *= MAXNORM / nhb;
  float x2 = rsum16(hy * hy);
  float y2 = rsum16(hb * hb);
  float xy = rsum16(hy * hb);
  float num = (1.f + 2.f * xy + y2) * hy + (1.f - x2) * hb;
  float den = fmaxf(1.f + 2.f * xy + x2 * y2, EPSF);
  float r = num / den;
  float nr = fmaxf(sqrtf(rsum16(r * r)), EPSF);
  if (nr > MAXNORM) r *= MAXNORM / nr;
  if (lane < 16) out[(size_t)g * 16 + lane] = r;
}

extern "C" void kernel_launch(void* const* d_in, const int* in_sizes, int n_in,
                              void* d_out, int out_size, void* d_ws, size_t ws_size,
                              hipStream_t stream) {
  const float* x  = (const float*)d_in[0];
  const float* W1 = (const float*)d_in[1];
  const float* b1 = (const float*)d_in[2];
  const float* W2 = (const float*)d_in[3];
  const float* b2 = (const float*)d_in[4];
  const float* W3 = (const float*)d_in[5];
  const float* b3 = (const float*)d_in[6];
  const float* W4 = (const float*)d_in[7];
  const float* b4 = (const float*)d_in[8];
  const int* ei   = (const int*)d_in[9];
  const int* batch = (const int*)d_in[10];

  int N = in_sizes[0] / 64;
  int E = in_sizes[9] / 2;
  int G = out_size / 16;
  const int* src = ei;
  const int* dst = ei + E;

  float* ws = (float*)d_ws;
  float* xtA    = ws;                          // N*64
  float* xtB    = xtA + (size_t)N * 64;        // N*64
  float* pooled = xtB + (size_t)N * 64;        // G*64
  float* cntg   = pooled + (size_t)G * 64;     // G
  float* hb_all = cntg + G;                    // 192
  float* hb2_all = hb_all + 192;               // 4 (pad)
  int* ip       = (int*)(hb2_all + 4);
  int* deg      = ip;                          // N
  int* locscan  = deg + N;                     // N
  int* rowptr   = locscan + N;                 // N+1
  int* partial  = rowptr + N + 1;              // 256
  int* csr      = partial + 256;               // E
  float* out = (float*)d_out;

  int nbN = (N + 255) / 256;
  int nbE = (E + 255) / 256;
  int pairs = (N + 1) / 2;
  int nbP = (pairs + 3) / 4;

  hipMemsetAsync(deg, 0, (size_t)N * sizeof(int), stream);
  hipMemsetAsync(pooled, 0, ((size_t)G * 64 + G) * sizeof(float), stream);

  k_hist<<<nbE, 256, 0, stream>>>(dst, deg, E);
  k_scanA<<<nbN, 256, 0, stream>>>(deg, locscan, partial, N);
  k_scanB<<<1, 256, 0, stream>>>(partial, nbN);
  k_scanC<<<nbN, 256, 0, stream>>>(locscan, partial, rowptr, N, E);
  k_fill<<<nbE, 256, 0, stream>>>(src, dst, rowptr, deg, csr, E);

  k_count<<<nbN, 256, 0, stream>>>(batch, cntg, N);
  k_prepb<<<1, 192, 0, stream>>>(b1, b2, b3, hb_all, hb2_all);

  k_lin1<<<2048, 512, 0, stream>>>(x, W1, hb_all, hb2_all, xtA, N);
  k_gatherlin<<<2048, 512, 0, stream>>>(rowptr, csr, xtA, W2, hb_all + 64,
                                        hb2_all + 1, xtB, N);
  k_gatherlin<<<2048, 512, 0, stream>>>(rowptr, csr, xtB, W3, hb_all + 128,
                                        hb2_all + 2, xtA, N);
  k_gpool<<<nbP, 256, 0, stream>>>(rowptr, csr, xtA, batch, pooled, N);
  k_final<<<G, 64, 0, stream>>>(pooled, cntg, W4, b4, out, G);
}

// Round 7
// 308.003 us; speedup vs baseline: 3.1961x; 1.0704x over previous
//
#include <hip/hip_runtime.h>

#define EPSF 1e-7f
#define MAXNORM (1.0f - 1e-5f)

__device__ __forceinline__ float rsum64(float v) {
#pragma unroll
  for (int m = 32; m; m >>= 1) v += __shfl_xor(v, m, 64);
  return v;
}
__device__ __forceinline__ float rsum16(float v) {
#pragma unroll
  for (int m = 8; m; m >>= 1) v += __shfl_xor(v, m, 64);
  return v;
}

__device__ __forceinline__ float frcp(float x) { return __builtin_amdgcn_rcpf(x); }
__device__ __forceinline__ float fsqrt_(float x) { return __builtin_amdgcn_sqrtf(x); }
__device__ __forceinline__ float tanh_fast(float x) {
  x = fminf(x, 20.f);
  float e = __builtin_amdgcn_exp2f(x * 2.88539008178f);  // e^{2x}
  return (e - 1.f) * frcp(e + 1.f);
}
__device__ __forceinline__ float atanh_fast(float x) {
  return 0.34657359028f * __builtin_amdgcn_logf((1.f + x) * frcp(1.f - x));
}
// logmap0(proj(expmap0(u))) == f(nu) * u, nu = max(||u||, EPS).
__device__ __forceinline__ float lp_exp_log_scale(float nu) {
  float te = tanh_fast(nu);
  float tec = fminf(fmaxf(te, EPSF), MAXNORM);
  return atanh_fast(tec) * frcp(fmaxf(te, EPSF)) * te * frcp(nu);
}

__device__ __forceinline__ float4 ld4(const float* p) {
  return *reinterpret_cast<const float4*>(p);
}

// Fused dual-node gather: both nodes' row loads issue in the same basic block
// (independent vmcnt chains overlap). Masked-fmaf handles remainders without
// divergent loads (clamped shfl index duplicates a valid row; mask zeroes it).
// Returns per-node float4 partial sums, group-summed across the 4 row-groups:
// lane (g*16+sub) holds dims [sub*4, sub*4+4) of the FULL sum (all g identical).
__device__ __forceinline__ void gather_pair(const int* __restrict__ csr,
                                            const float* __restrict__ xtp,
                                            int r0a, int r1a, int r0b, int r1b,
                                            int lane, float4& SA, float4& SB) {
  int grp = lane >> 4, sub = lane & 15;
  float4 P0 = {0, 0, 0, 0}, P1 = {0, 0, 0, 0};
  float4 Q0 = {0, 0, 0, 0}, Q1 = {0, 0, 0, 0};
  int dega = r1a - r0a, degb = r1b - r0b;
  int basea = 0, baseb = 0;
  while (basea < dega || baseb < degb) {
    int ca = dega - basea; ca = (ca > 64) ? 64 : ((ca < 0) ? 0 : ca);
    int cb = degb - baseb; cb = (cb > 64) ? 64 : ((cb < 0) ? 0 : cb);
    int ea = (lane < ca) ? csr[r0a + basea + lane] : 0;
    int eb = (lane < cb) ? csr[r0b + baseb + lane] : 0;
    int cmax = (ca > cb) ? ca : cb;
    for (int c = 0; c < cmax; c += 8) {
      if (c < ca) {  // wave-uniform branch
        int l0 = c + grp, l1 = c + 4 + grp;
        float m0 = (l0 < ca) ? 1.f : 0.f;
        float m1 = (l1 < ca) ? 1.f : 0.f;
        int i0 = __shfl(ea, (l0 < ca) ? l0 : (ca - 1), 64);
        int i1 = __shfl(ea, (l1 < ca) ? l1 : (ca - 1), 64);
        float4 v0 = ld4(&xtp[(size_t)i0 * 64 + sub * 4]);
        float4 v1 = ld4(&xtp[(size_t)i1 * 64 + sub * 4]);
        P0.x = fmaf(m0, v0.x, P0.x); P0.y = fmaf(m0, v0.y, P0.y);
        P0.z = fmaf(m0, v0.z, P0.z); P0.w = fmaf(m0, v0.w, P0.w);
        P1.x = fmaf(m1, v1.x, P1.x); P1.y = fmaf(m1, v1.y, P1.y);
        P1.z = fmaf(m1, v1.z, P1.z); P1.w = fmaf(m1, v1.w, P1.w);
      }
      if (c < cb) {
        int l0 = c + grp, l1 = c + 4 + grp;
        float m0 = (l0 < cb) ? 1.f : 0.f;
        float m1 = (l1 < cb) ? 1.f : 0.f;
        int i0 = __shfl(eb, (l0 < cb) ? l0 : (cb - 1), 64);
        int i1 = __shfl(eb, (l1 < cb) ? l1 : (cb - 1), 64);
        float4 v0 = ld4(&xtp[(size_t)i0 * 64 + sub * 4]);
        float4 v1 = ld4(&xtp[(size_t)i1 * 64 + sub * 4]);
        Q0.x = fmaf(m0, v0.x, Q0.x); Q0.y = fmaf(m0, v0.y, Q0.y);
        Q0.z = fmaf(m0, v0.z, Q0.z); Q0.w = fmaf(m0, v0.w, Q0.w);
        Q1.x = fmaf(m1, v1.x, Q1.x); Q1.y = fmaf(m1, v1.y, Q1.y);
        Q1.z = fmaf(m1, v1.z, Q1.z); Q1.w = fmaf(m1, v1.w, Q1.w);
      }
    }
    basea += ca; baseb += cb;
  }
  SA.x = P0.x + P1.x; SA.y = P0.y + P1.y; SA.z = P0.z + P1.z; SA.w = P0.w + P1.w;
  SB.x = Q0.x + Q1.x; SB.y = Q0.y + Q1.y; SB.z = Q0.z + Q1.z; SB.w = Q0.w + Q1.w;
#pragma unroll
  for (int m = 16; m <= 32; m <<= 1) {
    SA.x += __shfl_xor(SA.x, m, 64); SA.y += __shfl_xor(SA.y, m, 64);
    SA.z += __shfl_xor(SA.z, m, 64); SA.w += __shfl_xor(SA.w, m, 64);
    SB.x += __shfl_xor(SB.x, m, 64); SB.y += __shfl_xor(SB.y, m, 64);
    SB.z += __shfl_xor(SB.z, m, 64); SB.w += __shfl_xor(SB.w, m, 64);
  }
}

// redistribute float4-per-16-lane layout to scalar-per-lane (dim = lane)
__device__ __forceinline__ float redist(float4 S, int lane) {
  int srcl = lane >> 2, sel = lane & 3;
  float c0 = __shfl(S.x, srcl, 64);
  float c1 = __shfl(S.y, srcl, 64);
  float c2 = __shfl(S.z, srcl, 64);
  float c3 = __shfl(S.w, srcl, 64);
  return (sel == 0) ? c0 : (sel == 1) ? c1 : (sel == 2) ? c2 : c3;
}

// ---------------- CSR build (by dst) + graph-size count ----------------
__global__ void k_histcnt(const int* __restrict__ dst, int* __restrict__ deg, int E,
                          const int* __restrict__ batch, float* __restrict__ cntg,
                          int N) {
  int i = blockIdx.x * blockDim.x + threadIdx.x;
  if (i < E) atomicAdd(&deg[dst[i]], 1);
  else if (i < E + N) atomicAdd(&cntg[batch[i - E]], 1.0f);
}

__global__ void __launch_bounds__(256) k_scanA(const int* __restrict__ deg,
                                               int* __restrict__ locscan,
                                               int* __restrict__ partial, int N) {
  __shared__ int buf[256];
  int i = blockIdx.x * 256 + threadIdx.x;
  int v = (i < N) ? deg[i] : 0;
  buf[threadIdx.x] = v;
  __syncthreads();
#pragma unroll
  for (int off = 1; off < 256; off <<= 1) {
    int t = (threadIdx.x >= off) ? buf[threadIdx.x - off] : 0;
    __syncthreads();
    buf[threadIdx.x] += t;
    __syncthreads();
  }
  if (i < N) locscan[i] = buf[threadIdx.x] - v;
  if (threadIdx.x == 255) partial[blockIdx.x] = buf[255];
}

__global__ void __launch_bounds__(256) k_scanB(int* __restrict__ partial, int nb) {
  __shared__ int buf[256];
  int v = (threadIdx.x < nb) ? partial[threadIdx.x] : 0;
  buf[threadIdx.x] = v;
  __syncthreads();
#pragma unroll
  for (int off = 1; off < 256; off <<= 1) {
    int t = (threadIdx.x >= off) ? buf[threadIdx.x - off] : 0;
    __syncthreads();
    buf[threadIdx.x] += t;
    __syncthreads();
  }
  if (threadIdx.x < nb) partial[threadIdx.x] = buf[threadIdx.x] - v;
}

__global__ void __launch_bounds__(256) k_scanC(const int* __restrict__ locscan,
                                               const int* __restrict__ partial,
                                               int* __restrict__ rowptr, int N, int E) {
  int i = blockIdx.x * 256 + threadIdx.x;
  if (i < N) rowptr[i] = locscan[i] + partial[blockIdx.x];
  if (i == 0) rowptr[N] = E;
}

__global__ void k_fill(const int* __restrict__ src, const int* __restrict__ dst,
                       const int* __restrict__ rowptr, int* __restrict__ deg,
                       int* __restrict__ csr, int E) {
  int e = blockIdx.x * blockDim.x + threadIdx.x;
  if (e >= E) return;
  int d = dst[e];
  int p = atomicSub(&deg[d], 1) - 1;
  csr[rowptr[d] + p] = src[e];
}

// hb = proj(expmap0(b)) per layer; hb2 = ||hb||^2
__global__ void __launch_bounds__(192) k_prepb(const float* __restrict__ b1,
                                               const float* __restrict__ b2,
                                               const float* __restrict__ b3,
                                               float* __restrict__ hb_all,
                                               float* __restrict__ hb2_all) {
  int w = threadIdx.x >> 6, lane = threadIdx.x & 63;
  const float* b = (w == 0) ? b1 : (w == 1) ? b2 : b3;
  float bb = b[lane];
  float nb = fmaxf(fsqrt_(rsum64(bb * bb)), EPSF);
  float tb = tanh_fast(nb);
  float cb = fminf(tb, MAXNORM);
  float hb = cb * frcp(nb) * bb;
  hb_all[w * 64 + lane] = hb;
  if (lane == 0) hb2_all[w] = cb * cb;
}

// matvec for a node pair; W-row float4 reads shared by both nodes.
__device__ __forceinline__ void matvec_pair(const float* Wl, float* ts, int wid,
                                            int lane, float t2a, float t2b,
                                            float& acca, float& accb) {
  float* tsw = ts + wid * 128;
  tsw[lane] = t2a;
  tsw[64 + lane] = t2b;
  const float4* Wrow = reinterpret_cast<const float4*>(&Wl[lane * 68]);
  const float4* ta4 = reinterpret_cast<const float4*>(tsw);
  const float4* tb4 = reinterpret_cast<const float4*>(tsw + 64);
  float a = 0.f, b = 0.f;
#pragma unroll
  for (int q = 0; q < 16; ++q) {
    float4 w = Wrow[q];
    float4 ta = ta4[q];
    float4 tb = tb4[q];
    a = fmaf(w.x, ta.x, a); a = fmaf(w.y, ta.y, a);
    a = fmaf(w.z, ta.z, a); a = fmaf(w.w, ta.w, a);
    b = fmaf(w.x, tb.x, b); b = fmaf(w.y, tb.y, b);
    b = fmaf(w.z, tb.z, b); b = fmaf(w.w, tb.w, b);
  }
  acca = a; accb = b;
}

// mobius-bias + proj + logmap0 tail, dual-node, analytic result norm.
// One fused dual-dual reduction: {||acc||^2, <acc,hb>} for both nodes at once.
__device__ __forceinline__ void mobius_pair(float acca, float accb, float hbv,
                                            float hb2, float& oa, float& ob) {
  float p1a = acca * acca, p2a = acca * hbv;
  float p1b = accb * accb, p2b = accb * hbv;
#pragma unroll
  for (int m = 1; m <= 32; m <<= 1) {
    p1a += __shfl_xor(p1a, m, 64); p2a += __shfl_xor(p2a, m, 64);
    p1b += __shfl_xor(p1b, m, 64); p2b += __shfl_xor(p2b, m, 64);
  }
  float nya = fmaxf(fsqrt_(p1a), EPSF);
  float nyb = fmaxf(fsqrt_(p1b), EPSF);
  float cya = fminf(tanh_fast(nya), MAXNORM);
  float cyb = fminf(tanh_fast(nyb), MAXNORM);
  float ka = cya * frcp(nya);
  float kb = cyb * frcp(nyb);
  float xya = ka * p2a, xyb = kb * p2b;
  float x2a = cya * cya, x2b = cyb * cyb;
  float aa = 1.f + 2.f * xya + hb2, ab = 1.f + 2.f * xyb + hb2;
  float ca = 1.f - x2a, cb = 1.f - x2b;
  float dena = fmaxf(1.f + 2.f * xya + x2a * hb2, EPSF);
  float denb = fmaxf(1.f + 2.f * xyb + x2b * hb2, EPSF);
  float rda = frcp(dena), rdb = frcp(denb);
  float nr2a = (aa * aa * x2a + 2.f * aa * ca * xya + ca * ca * hb2) * rda * rda;
  float nr2b = (ab * ab * x2b + 2.f * ab * cb * xyb + cb * cb * hb2) * rdb * rdb;
  float nra = fmaxf(fsqrt_(nr2a), EPSF);
  float nrb = fmaxf(fsqrt_(nr2b), EPSF);
  float sa = atanh_fast(fminf(nra, MAXNORM)) * frcp(nra);
  float sb = atanh_fast(fminf(nrb, MAXNORM)) * frcp(nrb);
  oa = sa * rda * (aa * ka * acca + ca * hbv);
  ob = sb * rdb * (ab * kb * accb + cb * hbv);
}

// layer1 (node-pair): x -> xt1
__global__ void __launch_bounds__(512) k_lin1(const float* __restrict__ x,
                                              const float* __restrict__ W,
                                              const float* __restrict__ hb,
                                              const float* __restrict__ hb2p,
                                              float* __restrict__ xt, int N) {
  __shared__ __align__(16) float Wl[64 * 68];
  __shared__ __align__(16) float ts[8 * 128];
  int tid = threadIdx.x, wid = tid >> 6, lane = tid & 63;
  for (int i = tid; i < 4096; i += 512) Wl[(i >> 6) * 68 + (i & 63)] = W[i];
  __syncthreads();
  float hbv = hb[lane];
  float hb2 = hb2p[0];
  int pairs = (N + 1) >> 1;
  for (int p = blockIdx.x * 8 + wid; p < pairs; p += gridDim.x * 8) {
    int n0 = 2 * p, n1 = n0 + 1;
    bool v1 = n1 < N;
    float xa = x[(size_t)n0 * 64 + lane];
    float xb = v1 ? x[(size_t)n1 * 64 + lane] : 0.f;
    float pa = xa * xa, pb = xb * xb;
#pragma unroll
    for (int m = 1; m <= 32; m <<= 1) {
      pa += __shfl_xor(pa, m, 64); pb += __shfl_xor(pb, m, 64);
    }
    float na = fmaxf(fsqrt_(pa), EPSF);
    float nb = fmaxf(fsqrt_(pb), EPSF);
    float t2a = lp_exp_log_scale(na) * xa;
    float t2b = lp_exp_log_scale(nb) * xb;
    float acca, accb;
    matvec_pair(Wl, ts, wid, lane, t2a, t2b, acca, accb);
    float oa, ob;
    mobius_pair(acca, accb, hbv, hb2, oa, ob);
    xt[(size_t)n0 * 64 + lane] = oa;
    if (v1) xt[(size_t)n1 * 64 + lane] = ob;
  }
}

// layer boundary (node-pair): gather-mean -> hyp_agg -> act -> hyp_linear -> xt
__global__ void __launch_bounds__(512) k_gatherlin(
    const int* __restrict__ rowptr, const int* __restrict__ csr,
    const float* __restrict__ xtp, const float* __restrict__ W,
    const float* __restrict__ hb, const float* __restrict__ hb2p,
    float* __restrict__ xt, int N) {
  __shared__ __align__(16) float Wl[64 * 68];
  __shared__ __align__(16) float ts[8 * 128];
  int tid = threadIdx.x, wid = tid >> 6, lane = tid & 63;
  for (int i = tid; i < 4096; i += 512) Wl[(i >> 6) * 68 + (i & 63)] = W[i];
  __syncthreads();
  float hbv = hb[lane];
  float hb2 = hb2p[0];
  int pairs = (N + 1) >> 1;
  for (int p = blockIdx.x * 8 + wid; p < pairs; p += gridDim.x * 8) {
    int n0 = 2 * p, n1 = n0 + 1;
    bool v1 = n1 < N;
    int r0a = rowptr[n0], r1a = rowptr[n0 + 1];
    int r0b = r1a, r1b = v1 ? rowptr[n1 + 1] : r1a;
    float4 SA, SB;
    gather_pair(csr, xtp, r0a, r1a, r0b, r1b, lane, SA, SB);
    float dia = frcp(fmaxf((float)(r1a - r0a), 1.f));
    float dib = frcp(fmaxf((float)(r1b - r0b), 1.f));
    float4 Ua = {SA.x * dia, SA.y * dia, SA.z * dia, SA.w * dia};
    float4 Ub = {SB.x * dib, SB.y * dib, SB.z * dib, SB.w * dib};
    // fused norms from float4 partials: p = sum u^2, q = sum (u*w)^2 (leaky)
    float pa = Ua.x * Ua.x + Ua.y * Ua.y + Ua.z * Ua.z + Ua.w * Ua.w;
    float qa = (Ua.x < 0.f ? 0.04f : 1.f) * Ua.x * Ua.x +
               (Ua.y < 0.f ? 0.04f : 1.f) * Ua.y * Ua.y +
               (Ua.z < 0.f ? 0.04f : 1.f) * Ua.z * Ua.z +
               (Ua.w < 0.f ? 0.04f : 1.f) * Ua.w * Ua.w;
    float pb = Ub.x * Ub.x + Ub.y * Ub.y + Ub.z * Ub.z + Ub.w * Ub.w;
    float qb = (Ub.x < 0.f ? 0.04f : 1.f) * Ub.x * Ub.x +
               (Ub.y < 0.f ? 0.04f : 1.f) * Ub.y * Ub.y +
               (Ub.z < 0.f ? 0.04f : 1.f) * Ub.z * Ub.z +
               (Ub.w < 0.f ? 0.04f : 1.f) * Ub.w * Ub.w;
#pragma unroll
    for (int m = 1; m <= 8; m <<= 1) {
      pa += __shfl_xor(pa, m, 64); qa += __shfl_xor(qa, m, 64);
      pb += __shfl_xor(pb, m, 64); qb += __shfl_xor(qb, m, 64);
    }
    float ua = redist(Ua, lane);
    float ub = redist(Ub, lane);
    float nua = fmaxf(fsqrt_(pa), EPSF);
    float nub = fmaxf(fsqrt_(pb), EPSF);
    float s1a = lp_exp_log_scale(nua);
    float s1b = lp_exp_log_scale(nub);
    float nta = fmaxf(s1a * fsqrt_(qa), EPSF);
    float ntb = fmaxf(s1b * fsqrt_(qb), EPSF);
    float fa = lp_exp_log_scale(nta) * s1a;
    float fb = lp_exp_log_scale(ntb) * s1b;
    float t2a = fa * ua * ((ua < 0.f) ? 0.2f : 1.f);
    float t2b = fb * ub * ((ub < 0.f) ? 0.2f : 1.f);
    float acca, accb;
    matvec_pair(Wl, ts, wid, lane, t2a, t2b, acca, accb);
    float oa, ob;
    mobius_pair(acca, accb, hbv, hb2, oa, ob);
    xt[(size_t)n0 * 64 + lane] = oa;
    if (v1) xt[(size_t)n1 * 64 + lane] = ob;
  }
}

// layer3 end (node-pair): gather-mean -> hyp_agg -> logmap -> pool atomics
__global__ void __launch_bounds__(256) k_gpool(const int* __restrict__ rowptr,
                                               const int* __restrict__ csr,
                                               const float* __restrict__ xtp,
                                               const int* __restrict__ batch,
                                               float* __restrict__ pooled, int N) {
  int p = blockIdx.x * 4 + (threadIdx.x >> 6);
  int pairs = (N + 1) >> 1;
  if (p >= pairs) return;
  int lane = threadIdx.x & 63;
  int n0 = 2 * p, n1 = n0 + 1;
  bool v1 = n1 < N;
  int r0a = rowptr[n0], r1a = rowptr[n0 + 1];
  int r0b = r1a, r1b = v1 ? rowptr[n1 + 1] : r1a;
  float4 SA, SB;
  gather_pair(csr, xtp, r0a, r1a, r0b, r1b, lane, SA, SB);
  float dia = frcp(fmaxf((float)(r1a - r0a), 1.f));
  float dib = frcp(fmaxf((float)(r1b - r0b), 1.f));
  float4 Ua = {SA.x * dia, SA.y * dia, SA.z * dia, SA.w * dia};
  float4 Ub = {SB.x * dib, SB.y * dib, SB.z * dib, SB.w * dib};
  float pa = Ua.x * Ua.x + Ua.y * Ua.y + Ua.z * Ua.z + Ua.w * Ua.w;
  float pb = Ub.x * Ub.x + Ub.y * Ub.y + Ub.z * Ub.z + Ub.w * Ub.w;
#pragma unroll
  for (int m = 1; m <= 8; m <<= 1) {
    pa += __shfl_xor(pa, m, 64); pb += __shfl_xor(pb, m, 64);
  }
  float ua = redist(Ua, lane);
  float ub = redist(Ub, lane);
  float nua = fmaxf(fsqrt_(pa), EPSF);
  float nub = fmaxf(fsqrt_(pb), EPSF);
  float ta = lp_exp_log_scale(nua) * ua;
  float tb = lp_exp_log_scale(nub) * ub;
  atomicAdd(&pooled[(size_t)batch[n0] * 64 + lane], ta);
  if (v1) atomicAdd(&pooled[(size_t)batch[n1] * 64 + lane], tb);
}

// head: per graph, 1 wave (precise; negligible cost)
__global__ void __launch_bounds__(64) k_final(const float* __restrict__ pooled,
                                              const float* __restrict__ cntg,
                                              const float* __restrict__ W4,
                                              const float* __restrict__ b4,
                                              float* __restrict__ out, int G) {
  int g = blockIdx.x;
  int lane = threadIdx.x;
  float u = pooled[(size_t)g * 64 + lane] / fmaxf(cntg[g], 1.0f);
  float n = fmaxf(sqrtf(rsum64(u * u)), EPSF);
  float e = tanhf(n) * u / n;
  float ne = fmaxf(sqrtf(rsum64(e * e)), EPSF);
  if (ne > MAXNORM) e *= MAXNORM / ne;
  float nn = fmaxf(sqrtf(rsum64(e * e)), EPSF);
  float t = atanhf(fminf(nn, MAXNORM)) * e / nn;

  int row = lane & 15;
  float acc = 0.f;
#pragma unroll
  for (int k = 0; k < 64; ++k) {
    float tk = __shfl(t, k, 64);
    acc = fmaf(W4[row * 64 + k], tk, acc);
  }
  float ny = fmaxf(sqrtf(rsum16(acc * acc)), EPSF);
  float hy = tanhf(ny) * acc / ny;
  float nh = fmaxf(sqrtf(rsum16(hy * hy)), EPSF);
  if (nh > MAXNORM) hy *= MAXNORM / nh;
  float bb = b4[row];
  float nb = fmaxf(sqrtf(rsum16(bb * bb)), EPSF);
  float hb = tanhf(nb) * bb / nb;
  float nhb = fmaxf(sqrtf(rsum16(hb * hb)), EPSF);
  if (nhb > MAXNORM) hb *= MAXNORM / nhb;
  float x2 = rsum16(hy * hy);
  float y2 = rsum16(hb * hb);
  float xy = rsum16(hy * hb);
  float num = (1.f + 2.f * xy + y2) * hy + (1.f - x2) * hb;
  float den = fmaxf(1.f + 2.f * xy + x2 * y2, EPSF);
  float r = num / den;
  float nr = fmaxf(sqrtf(rsum16(r * r)), EPSF);
  if (nr > MAXNORM) r *= MAXNORM / nr;
  if (lane < 16) out[(size_t)g * 16 + lane] = r;
}

extern "C" void kernel_launch(void* const* d_in, const int* in_sizes, int n_in,
                              void* d_out, int out_size, void* d_ws, size_t ws_size,
                              hipStream_t stream) {
  const float* x  = (const float*)d_in[0];
  const float* W1 = (const float*)d_in[1];
  const float* b1 = (const float*)d_in[2];
  const float* W2 = (const float*)d_in[3];
  const float* b2 = (const float*)d_in[4];
  const float* W3 = (const float*)d_in[5];
  const float* b3 = (const float*)d_in[6];
  const float* W4 = (const float*)d_in[7];
  const float* b4 = (const float*)d_in[8];
  const int* ei   = (const int*)d_in[9];
  const int* batch = (const int*)d_in[10];

  int N = in_sizes[0] / 64;
  int E = in_sizes[9] / 2;
  int G = out_size / 16;
  const int* src = ei;
  const int* dst = ei + E;

  float* ws = (float*)d_ws;
  float* xtA    = ws;                          // N*64
  float* xtB    = xtA + (size_t)N * 64;        // N*64
  float* pooled = xtB + (size_t)N * 64;        // G*64
  float* cntg   = pooled + (size_t)G * 64;     // G
  float* hb_all = cntg + G;                    // 192
  float* hb2_all = hb_all + 192;               // 4 (pad)
  int* ip       = (int*)(hb2_all + 4);
  int* deg      = ip;                          // N
  int* locscan  = deg + N;                     // N
  int* rowptr   = locscan + N;                 // N+1
  int* partial  = rowptr + N + 1;              // 256
  int* csr      = partial + 256;               // E
  float* out = (float*)d_out;

  int nbN = (N + 255) / 256;
  int nbE = (E + 255) / 256;
  int nbEN = (E + N + 255) / 256;
  int pairs = (N + 1) / 2;
  int nbP = (pairs + 3) / 4;

  hipMemsetAsync(deg, 0, (size_t)N * sizeof(int), stream);
  hipMemsetAsync(pooled, 0, ((size_t)G * 64 + G) * sizeof(float), stream);

  k_histcnt<<<nbEN, 256, 0, stream>>>(dst, deg, E, batch, cntg, N);
  k_scanA<<<nbN, 256, 0, stream>>>(deg, locscan, partial, N);
  k_scanB<<<1, 256, 0, stream>>>(partial, nbN);
  k_scanC<<<nbN, 256, 0, stream>>>(locscan, partial, rowptr, N, E);
  k_fill<<<nbE, 256, 0, stream>>>(src, dst, rowptr, deg, csr, E);

  k_prepb<<<1, 192, 0, stream>>>(b1, b2, b3, hb_all, hb2_all);

  k_lin1<<<2048, 512, 0, stream>>>(x, W1, hb_all, hb2_all, xtA, N);
  k_gatherlin<<<2048, 512, 0, stream>>>(rowptr, csr, xtA, W2, hb_all + 64,
                                        hb2_all + 1, xtB, N);
  k_gatherlin<<<2048, 512, 0, stream>>>(rowptr, csr, xtB, W3, hb_all + 128,
                                        hb2_all + 2, xtA, N);
  k_gpool<<<nbP, 256, 0, stream>>>(rowptr, csr, xtA, batch, pooled, N);
  k_final<<<G, 64, 0, stream>>>(pooled, cntg, W4, b4, out, G);
}

// Round 8
// 271.530 us; speedup vs baseline: 3.6254x; 1.1343x over previous
//
#include <hip/hip_runtime.h>

#define EPSF 1e-7f
#define MAXNORM (1.0f - 1e-5f)

__device__ __forceinline__ float rsum64(float v) {
#pragma unroll
  for (int m = 32; m; m >>= 1) v += __shfl_xor(v, m, 64);
  return v;
}
__device__ __forceinline__ float rsum16(float v) {
#pragma unroll
  for (int m = 8; m; m >>= 1) v += __shfl_xor(v, m, 64);
  return v;
}

__device__ __forceinline__ float frcp(float x) { return __builtin_amdgcn_rcpf(x); }
__device__ __forceinline__ float fsqrt_(float x) { return __builtin_amdgcn_sqrtf(x); }
__device__ __forceinline__ float tanh_fast(float x) {
  x = fminf(x, 20.f);
  float e = __builtin_amdgcn_exp2f(x * 2.88539008178f);  // e^{2x}
  return (e - 1.f) * frcp(e + 1.f);
}
__device__ __forceinline__ float atanh_fast(float x) {
  return 0.34657359028f * __builtin_amdgcn_logf((1.f + x) * frcp(1.f - x));
}
// logmap0(proj(expmap0(u))) == f(nu) * u, nu = max(||u||, EPS).
__device__ __forceinline__ float lp_exp_log_scale(float nu) {
  float te = tanh_fast(nu);
  float tec = fminf(fmaxf(te, EPSF), MAXNORM);
  return atanh_fast(tec) * frcp(fmaxf(te, EPSF)) * te * frcp(nu);
}

__device__ __forceinline__ float4 ld4(const float* p) {
  return *reinterpret_cast<const float4*>(p);
}

// Fused dual-node gather (see R7 notes): both nodes' loads issue in one block.
__device__ __forceinline__ void gather_pair(const int* __restrict__ csr,
                                            const float* __restrict__ xtp,
                                            int r0a, int r1a, int r0b, int r1b,
                                            int lane, float4& SA, float4& SB) {
  int grp = lane >> 4, sub = lane & 15;
  float4 P0 = {0, 0, 0, 0}, P1 = {0, 0, 0, 0};
  float4 Q0 = {0, 0, 0, 0}, Q1 = {0, 0, 0, 0};
  int dega = r1a - r0a, degb = r1b - r0b;
  int basea = 0, baseb = 0;
  while (basea < dega || baseb < degb) {
    int ca = dega - basea; ca = (ca > 64) ? 64 : ((ca < 0) ? 0 : ca);
    int cb = degb - baseb; cb = (cb > 64) ? 64 : ((cb < 0) ? 0 : cb);
    int ea = (lane < ca) ? csr[r0a + basea + lane] : 0;
    int eb = (lane < cb) ? csr[r0b + baseb + lane] : 0;
    int cmax = (ca > cb) ? ca : cb;
    for (int c = 0; c < cmax; c += 8) {
      if (c < ca) {  // wave-uniform branch
        int l0 = c + grp, l1 = c + 4 + grp;
        float m0 = (l0 < ca) ? 1.f : 0.f;
        float m1 = (l1 < ca) ? 1.f : 0.f;
        int i0 = __shfl(ea, (l0 < ca) ? l0 : (ca - 1), 64);
        int i1 = __shfl(ea, (l1 < ca) ? l1 : (ca - 1), 64);
        float4 v0 = ld4(&xtp[(size_t)i0 * 64 + sub * 4]);
        float4 v1 = ld4(&xtp[(size_t)i1 * 64 + sub * 4]);
        P0.x = fmaf(m0, v0.x, P0.x); P0.y = fmaf(m0, v0.y, P0.y);
        P0.z = fmaf(m0, v0.z, P0.z); P0.w = fmaf(m0, v0.w, P0.w);
        P1.x = fmaf(m1, v1.x, P1.x); P1.y = fmaf(m1, v1.y, P1.y);
        P1.z = fmaf(m1, v1.z, P1.z); P1.w = fmaf(m1, v1.w, P1.w);
      }
      if (c < cb) {
        int l0 = c + grp, l1 = c + 4 + grp;
        float m0 = (l0 < cb) ? 1.f : 0.f;
        float m1 = (l1 < cb) ? 1.f : 0.f;
        int i0 = __shfl(eb, (l0 < cb) ? l0 : (cb - 1), 64);
        int i1 = __shfl(eb, (l1 < cb) ? l1 : (cb - 1), 64);
        float4 v0 = ld4(&xtp[(size_t)i0 * 64 + sub * 4]);
        float4 v1 = ld4(&xtp[(size_t)i1 * 64 + sub * 4]);
        Q0.x = fmaf(m0, v0.x, Q0.x); Q0.y = fmaf(m0, v0.y, Q0.y);
        Q0.z = fmaf(m0, v0.z, Q0.z); Q0.w = fmaf(m0, v0.w, Q0.w);
        Q1.x = fmaf(m1, v1.x, Q1.x); Q1.y = fmaf(m1, v1.y, Q1.y);
        Q1.z = fmaf(m1, v1.z, Q1.z); Q1.w = fmaf(m1, v1.w, Q1.w);
      }
    }
    basea += ca; baseb += cb;
  }
  SA.x = P0.x + P1.x; SA.y = P0.y + P1.y; SA.z = P0.z + P1.z; SA.w = P0.w + P1.w;
  SB.x = Q0.x + Q1.x; SB.y = Q0.y + Q1.y; SB.z = Q0.z + Q1.z; SB.w = Q0.w + Q1.w;
#pragma unroll
  for (int m = 16; m <= 32; m <<= 1) {
    SA.x += __shfl_xor(SA.x, m, 64); SA.y += __shfl_xor(SA.y, m, 64);
    SA.z += __shfl_xor(SA.z, m, 64); SA.w += __shfl_xor(SA.w, m, 64);
    SB.x += __shfl_xor(SB.x, m, 64); SB.y += __shfl_xor(SB.y, m, 64);
    SB.z += __shfl_xor(SB.z, m, 64); SB.w += __shfl_xor(SB.w, m, 64);
  }
}

// redistribute float4-per-16-lane layout to scalar-per-lane (dim = lane)
__device__ __forceinline__ float redist(float4 S, int lane) {
  int srcl = lane >> 2, sel = lane & 3;
  float c0 = __shfl(S.x, srcl, 64);
  float c1 = __shfl(S.y, srcl, 64);
  float c2 = __shfl(S.z, srcl, 64);
  float c3 = __shfl(S.w, srcl, 64);
  return (sel == 0) ? c0 : (sel == 1) ? c1 : (sel == 2) ? c2 : c3;
}

// ---------------- CSR build: XCD-privatized histogram ----------------
// 8 deg copies; copy = blockIdx&7 (round-robin XCD heuristic) keeps each
// copy's atomic lines XCD-local (R7: shared-copy atomics ping-ponged 26MB
// of counter lines through HBM).
__global__ void k_hist8(const int* __restrict__ dst, int* __restrict__ deg8,
                        int E, int N) {
  int e = blockIdx.x * blockDim.x + threadIdx.x;
  if (e >= E) return;
  int c = blockIdx.x & 7;
  atomicAdd(&deg8[(size_t)c * N + dst[e]], 1);
}

// per-node: total degree + per-copy exclusive offsets (for deterministic fill)
__global__ void __launch_bounds__(256) k_red8(int* __restrict__ deg8,
                                              int* __restrict__ offs8,
                                              int* __restrict__ deg, int N) {
  int d = blockIdx.x * blockDim.x + threadIdx.x;
  if (d >= N) return;
  int s = 0;
#pragma unroll
  for (int k = 0; k < 8; ++k) {
    int v = deg8[(size_t)k * N + d];
    offs8[(size_t)k * N + d] = s;
    s += v;
  }
  deg[d] = s;
}

__global__ void __launch_bounds__(256) k_scanA(const int* __restrict__ deg,
                                               int* __restrict__ locscan,
                                               int* __restrict__ partial, int N) {
  __shared__ int buf[256];
  int i = blockIdx.x * 256 + threadIdx.x;
  int v = (i < N) ? deg[i] : 0;
  buf[threadIdx.x] = v;
  __syncthreads();
#pragma unroll
  for (int off = 1; off < 256; off <<= 1) {
    int t = (threadIdx.x >= off) ? buf[threadIdx.x - off] : 0;
    __syncthreads();
    buf[threadIdx.x] += t;
    __syncthreads();
  }
  if (i < N) locscan[i] = buf[threadIdx.x] - v;
  if (threadIdx.x == 255) partial[blockIdx.x] = buf[255];
}

__global__ void __launch_bounds__(256) k_scanB(int* __restrict__ partial, int nb) {
  __shared__ int buf[256];
  int v = (threadIdx.x < nb) ? partial[threadIdx.x] : 0;
  buf[threadIdx.x] = v;
  __syncthreads();
#pragma unroll
  for (int off = 1; off < 256; off <<= 1) {
    int t = (threadIdx.x >= off) ? buf[threadIdx.x - off] : 0;
    __syncthreads();
    buf[threadIdx.x] += t;
    __syncthreads();
  }
  if (threadIdx.x < nb) partial[threadIdx.x] = buf[threadIdx.x] - v;
}

__global__ void __launch_bounds__(256) k_scanC(const int* __restrict__ locscan,
                                               const int* __restrict__ partial,
                                               int* __restrict__ rowptr, int N, int E) {
  int i = blockIdx.x * 256 + threadIdx.x;
  if (i < N) rowptr[i] = locscan[i] + partial[blockIdx.x];
  if (i == 0) rowptr[N] = E;
}

// fill using per-copy cursor (deg8 counts down, XCD-local atomics)
__global__ void k_fill8(const int* __restrict__ src, const int* __restrict__ dst,
                        const int* __restrict__ rowptr,
                        const int* __restrict__ offs8, int* __restrict__ deg8,
                        int* __restrict__ csr, int E, int N) {
  int e = blockIdx.x * blockDim.x + threadIdx.x;
  if (e >= E) return;
  int c = blockIdx.x & 7;
  int d = dst[e];
  int p = atomicSub(&deg8[(size_t)c * N + d], 1) - 1;
  csr[rowptr[d] + offs8[(size_t)c * N + d] + p] = src[e];
}

// graph sizes from SORTED batch via binary search — zero atomics.
__global__ void k_gsize(const int* __restrict__ batch, float* __restrict__ cntg,
                        int N, int G) {
  int g = blockIdx.x * blockDim.x + threadIdx.x;
  if (g >= G) return;
  int lo = 0, hi = N;
  while (lo < hi) { int mid = (lo + hi) >> 1; if (batch[mid] < g) lo = mid + 1; else hi = mid; }
  int lb = lo;
  lo = 0; hi = N; int g1 = g + 1;
  while (lo < hi) { int mid = (lo + hi) >> 1; if (batch[mid] < g1) lo = mid + 1; else hi = mid; }
  cntg[g] = (float)(lo - lb);
}

// hb = proj(expmap0(b)) per layer; hb2 = ||hb||^2
__global__ void __launch_bounds__(192) k_prepb(const float* __restrict__ b1,
                                               const float* __restrict__ b2,
                                               const float* __restrict__ b3,
                                               float* __restrict__ hb_all,
                                               float* __restrict__ hb2_all) {
  int w = threadIdx.x >> 6, lane = threadIdx.x & 63;
  const float* b = (w == 0) ? b1 : (w == 1) ? b2 : b3;
  float bb = b[lane];
  float nb = fmaxf(fsqrt_(rsum64(bb * bb)), EPSF);
  float tb = tanh_fast(nb);
  float cb = fminf(tb, MAXNORM);
  float hb = cb * frcp(nb) * bb;
  hb_all[w * 64 + lane] = hb;
  if (lane == 0) hb2_all[w] = cb * cb;
}

// matvec for a node pair; W-row float4 reads shared by both nodes.
__device__ __forceinline__ void matvec_pair(const float* Wl, float* ts, int wid,
                                            int lane, float t2a, float t2b,
                                            float& acca, float& accb) {
  float* tsw = ts + wid * 128;
  tsw[lane] = t2a;
  tsw[64 + lane] = t2b;
  const float4* Wrow = reinterpret_cast<const float4*>(&Wl[lane * 68]);
  const float4* ta4 = reinterpret_cast<const float4*>(tsw);
  const float4* tb4 = reinterpret_cast<const float4*>(tsw + 64);
  float a = 0.f, b = 0.f;
#pragma unroll
  for (int q = 0; q < 16; ++q) {
    float4 w = Wrow[q];
    float4 ta = ta4[q];
    float4 tb = tb4[q];
    a = fmaf(w.x, ta.x, a); a = fmaf(w.y, ta.y, a);
    a = fmaf(w.z, ta.z, a); a = fmaf(w.w, ta.w, a);
    b = fmaf(w.x, tb.x, b); b = fmaf(w.y, tb.y, b);
    b = fmaf(w.z, tb.z, b); b = fmaf(w.w, tb.w, b);
  }
  acca = a; accb = b;
}

// mobius-bias + proj + logmap0 tail, dual-node, analytic result norm.
__device__ __forceinline__ void mobius_pair(float acca, float accb, float hbv,
                                            float hb2, float& oa, float& ob) {
  float p1a = acca * acca, p2a = acca * hbv;
  float p1b = accb * accb, p2b = accb * hbv;
#pragma unroll
  for (int m = 1; m <= 32; m <<= 1) {
    p1a += __shfl_xor(p1a, m, 64); p2a += __shfl_xor(p2a, m, 64);
    p1b += __shfl_xor(p1b, m, 64); p2b += __shfl_xor(p2b, m, 64);
  }
  float nya = fmaxf(fsqrt_(p1a), EPSF);
  float nyb = fmaxf(fsqrt_(p1b), EPSF);
  float cya = fminf(tanh_fast(nya), MAXNORM);
  float cyb = fminf(tanh_fast(nyb), MAXNORM);
  float ka = cya * frcp(nya);
  float kb = cyb * frcp(nyb);
  float xya = ka * p2a, xyb = kb * p2b;
  float x2a = cya * cya, x2b = cyb * cyb;
  float aa = 1.f + 2.f * xya + hb2, ab = 1.f + 2.f * xyb + hb2;
  float ca = 1.f - x2a, cb = 1.f - x2b;
  float dena = fmaxf(1.f + 2.f * xya + x2a * hb2, EPSF);
  float denb = fmaxf(1.f + 2.f * xyb + x2b * hb2, EPSF);
  float rda = frcp(dena), rdb = frcp(denb);
  float nr2a = (aa * aa * x2a + 2.f * aa * ca * xya + ca * ca * hb2) * rda * rda;
  float nr2b = (ab * ab * x2b + 2.f * ab * cb * xyb + cb * cb * hb2) * rdb * rdb;
  float nra = fmaxf(fsqrt_(nr2a), EPSF);
  float nrb = fmaxf(fsqrt_(nr2b), EPSF);
  float sa = atanh_fast(fminf(nra, MAXNORM)) * frcp(nra);
  float sb = atanh_fast(fminf(nrb, MAXNORM)) * frcp(nrb);
  oa = sa * rda * (aa * ka * acca + ca * hbv);
  ob = sb * rdb * (ab * kb * accb + cb * hbv);
}

// layer1 (node-pair): x -> xt1
__global__ void __launch_bounds__(512) k_lin1(const float* __restrict__ x,
                                              const float* __restrict__ W,
                                              const float* __restrict__ hb,
                                              const float* __restrict__ hb2p,
                                              float* __restrict__ xt, int N) {
  __shared__ __align__(16) float Wl[64 * 68];
  __shared__ __align__(16) float ts[8 * 128];
  int tid = threadIdx.x, wid = tid >> 6, lane = tid & 63;
  for (int i = tid; i < 4096; i += 512) Wl[(i >> 6) * 68 + (i & 63)] = W[i];
  __syncthreads();
  float hbv = hb[lane];
  float hb2 = hb2p[0];
  int pairs = (N + 1) >> 1;
  for (int p = blockIdx.x * 8 + wid; p < pairs; p += gridDim.x * 8) {
    int n0 = 2 * p, n1 = n0 + 1;
    bool v1 = n1 < N;
    float xa = x[(size_t)n0 * 64 + lane];
    float xb = v1 ? x[(size_t)n1 * 64 + lane] : 0.f;
    float pa = xa * xa, pb = xb * xb;
#pragma unroll
    for (int m = 1; m <= 32; m <<= 1) {
      pa += __shfl_xor(pa, m, 64); pb += __shfl_xor(pb, m, 64);
    }
    float na = fmaxf(fsqrt_(pa), EPSF);
    float nb = fmaxf(fsqrt_(pb), EPSF);
    float t2a = lp_exp_log_scale(na) * xa;
    float t2b = lp_exp_log_scale(nb) * xb;
    float acca, accb;
    matvec_pair(Wl, ts, wid, lane, t2a, t2b, acca, accb);
    float oa, ob;
    mobius_pair(acca, accb, hbv, hb2, oa, ob);
    xt[(size_t)n0 * 64 + lane] = oa;
    if (v1) xt[(size_t)n1 * 64 + lane] = ob;
  }
}

// layer boundary (node-pair): gather-mean -> hyp_agg -> act -> hyp_linear -> xt
__global__ void __launch_bounds__(512) k_gatherlin(
    const int* __restrict__ rowptr, const int* __restrict__ csr,
    const float* __restrict__ xtp, const float* __restrict__ W,
    const float* __restrict__ hb, const float* __restrict__ hb2p,
    float* __restrict__ xt, int N) {
  __shared__ __align__(16) float Wl[64 * 68];
  __shared__ __align__(16) float ts[8 * 128];
  int tid = threadIdx.x, wid = tid >> 6, lane = tid & 63;
  for (int i = tid; i < 4096; i += 512) Wl[(i >> 6) * 68 + (i & 63)] = W[i];
  __syncthreads();
  float hbv = hb[lane];
  float hb2 = hb2p[0];
  int pairs = (N + 1) >> 1;
  for (int p = blockIdx.x * 8 + wid; p < pairs; p += gridDim.x * 8) {
    int n0 = 2 * p, n1 = n0 + 1;
    bool v1 = n1 < N;
    int r0a = rowptr[n0], r1a = rowptr[n0 + 1];
    int r0b = r1a, r1b = v1 ? rowptr[n1 + 1] : r1a;
    float4 SA, SB;
    gather_pair(csr, xtp, r0a, r1a, r0b, r1b, lane, SA, SB);
    float dia = frcp(fmaxf((float)(r1a - r0a), 1.f));
    float dib = frcp(fmaxf((float)(r1b - r0b), 1.f));
    float4 Ua = {SA.x * dia, SA.y * dia, SA.z * dia, SA.w * dia};
    float4 Ub = {SB.x * dib, SB.y * dib, SB.z * dib, SB.w * dib};
    float pa = Ua.x * Ua.x + Ua.y * Ua.y + Ua.z * Ua.z + Ua.w * Ua.w;
    float qa = (Ua.x < 0.f ? 0.04f : 1.f) * Ua.x * Ua.x +
               (Ua.y < 0.f ? 0.04f : 1.f) * Ua.y * Ua.y +
               (Ua.z < 0.f ? 0.04f : 1.f) * Ua.z * Ua.z +
               (Ua.w < 0.f ? 0.04f : 1.f) * Ua.w * Ua.w;
    float pb = Ub.x * Ub.x + Ub.y * Ub.y + Ub.z * Ub.z + Ub.w * Ub.w;
    float qb = (Ub.x < 0.f ? 0.04f : 1.f) * Ub.x * Ub.x +
               (Ub.y < 0.f ? 0.04f : 1.f) * Ub.y * Ub.y +
               (Ub.z < 0.f ? 0.04f : 1.f) * Ub.z * Ub.z +
               (Ub.w < 0.f ? 0.04f : 1.f) * Ub.w * Ub.w;
#pragma unroll
    for (int m = 1; m <= 8; m <<= 1) {
      pa += __shfl_xor(pa, m, 64); qa += __shfl_xor(qa, m, 64);
      pb += __shfl_xor(pb, m, 64); qb += __shfl_xor(qb, m, 64);
    }
    float ua = redist(Ua, lane);
    float ub = redist(Ub, lane);
    float nua = fmaxf(fsqrt_(pa), EPSF);
    float nub = fmaxf(fsqrt_(pb), EPSF);
    float s1a = lp_exp_log_scale(nua);
    float s1b = lp_exp_log_scale(nub);
    float nta = fmaxf(s1a * fsqrt_(qa), EPSF);
    float ntb = fmaxf(s1b * fsqrt_(qb), EPSF);
    float fa = lp_exp_log_scale(nta) * s1a;
    float fb = lp_exp_log_scale(ntb) * s1b;
    float t2a = fa * ua * ((ua < 0.f) ? 0.2f : 1.f);
    float t2b = fb * ub * ((ub < 0.f) ? 0.2f : 1.f);
    float acca, accb;
    matvec_pair(Wl, ts, wid, lane, t2a, t2b, acca, accb);
    float oa, ob;
    mobius_pair(acca, accb, hbv, hb2, oa, ob);
    xt[(size_t)n0 * 64 + lane] = oa;
    if (v1) xt[(size_t)n1 * 64 + lane] = ob;
  }
}

// layer3 end (node-pair): gather-mean -> hyp_agg -> logmap -> pool atomics
__global__ void __launch_bounds__(256) k_gpool(const int* __restrict__ rowptr,
                                               const int* __restrict__ csr,
                                               const float* __restrict__ xtp,
                                               const int* __restrict__ batch,
                                               float* __restrict__ pooled, int N) {
  int p = blockIdx.x * 4 + (threadIdx.x >> 6);
  int pairs = (N + 1) >> 1;
  if (p >= pairs) return;
  int lane = threadIdx.x & 63;
  int n0 = 2 * p, n1 = n0 + 1;
  bool v1 = n1 < N;
  int r0a = rowptr[n0], r1a = rowptr[n0 + 1];
  int r0b = r1a, r1b = v1 ? rowptr[n1 + 1] : r1a;
  float4 SA, SB;
  gather_pair(csr, xtp, r0a, r1a, r0b, r1b, lane, SA, SB);
  float dia = frcp(fmaxf((float)(r1a - r0a), 1.f));
  float dib = frcp(fmaxf((float)(r1b - r0b), 1.f));
  float4 Ua = {SA.x * dia, SA.y * dia, SA.z * dia, SA.w * dia};
  float4 Ub = {SB.x * dib, SB.y * dib, SB.z * dib, SB.w * dib};
  float pa = Ua.x * Ua.x + Ua.y * Ua.y + Ua.z * Ua.z + Ua.w * Ua.w;
  float pb = Ub.x * Ub.x + Ub.y * Ub.y + Ub.z * Ub.z + Ub.w * Ub.w;
#pragma unroll
  for (int m = 1; m <= 8; m <<= 1) {
    pa += __shfl_xor(pa, m, 64); pb += __shfl_xor(pb, m, 64);
  }
  float ua = redist(Ua, lane);
  float ub = redist(Ub, lane);
  float nua = fmaxf(fsqrt_(pa), EPSF);
  float nub = fmaxf(fsqrt_(pb), EPSF);
  float ta = lp_exp_log_scale(nua) * ua;
  float tb = lp_exp_log_scale(nub) * ub;
  atomicAdd(&pooled[(size_t)batch[n0] * 64 + lane], ta);
  if (v1) atomicAdd(&pooled[(size_t)batch[n1] * 64 + lane], tb);
}

// head: per graph, 1 wave (precise; negligible cost)
__global__ void __launch_bounds__(64) k_final(const float* __restrict__ pooled,
                                              const float* __restrict__ cntg,
                                              const float* __restrict__ W4,
                                              const float* __restrict__ b4,
                                              float* __restrict__ out, int G) {
  int g = blockIdx.x;
  int lane = threadIdx.x;
  float u = pooled[(size_t)g * 64 + lane] / fmaxf(cntg[g], 1.0f);
  float n = fmaxf(sqrtf(rsum64(u * u)), EPSF);
  float e = tanhf(n) * u / n;
  float ne = fmaxf(sqrtf(rsum64(e * e)), EPSF);
  if (ne > MAXNORM) e *= MAXNORM / ne;
  float nn = fmaxf(sqrtf(rsum64(e * e)), EPSF);
  float t = atanhf(fminf(nn, MAXNORM)) * e / nn;

  int row = lane & 15;
  float acc = 0.f;
#pragma unroll
  for (int k = 0; k < 64; ++k) {
    float tk = __shfl(t, k, 64);
    acc = fmaf(W4[row * 64 + k], tk, acc);
  }
  float ny = fmaxf(sqrtf(rsum16(acc * acc)), EPSF);
  float hy = tanhf(ny) * acc / ny;
  float nh = fmaxf(sqrtf(rsum16(hy * hy)), EPSF);
  if (nh > MAXNORM) hy *= MAXNORM / nh;
  float bb = b4[row];
  float nb = fmaxf(sqrtf(rsum16(bb * bb)), EPSF);
  float hb = tanhf(nb) * bb / nb;
  float nhb = fmaxf(sqrtf(rsum16(hb * hb)), EPSF);
  if (nhb > MAXNORM) hb *= MAXNORM / nhb;
  float x2 = rsum16(hy * hy);
  float y2 = rsum16(hb * hb);
  float xy = rsum16(hy * hb);
  float num = (1.f + 2.f * xy + y2) * hy + (1.f - x2) * hb;
  float den = fmaxf(1.f + 2.f * xy + x2 * y2, EPSF);
  float r = num / den;
  float nr = fmaxf(sqrtf(rsum16(r * r)), EPSF);
  if (nr > MAXNORM) r *= MAXNORM / nr;
  if (lane < 16) out[(size_t)g * 16 + lane] = r;
}

extern "C" void kernel_launch(void* const* d_in, const int* in_sizes, int n_in,
                              void* d_out, int out_size, void* d_ws, size_t ws_size,
                              hipStream_t stream) {
  const float* x  = (const float*)d_in[0];
  const float* W1 = (const float*)d_in[1];
  const float* b1 = (const float*)d_in[2];
  const float* W2 = (const float*)d_in[3];
  const float* b2 = (const float*)d_in[4];
  const float* W3 = (const float*)d_in[5];
  const float* b3 = (const float*)d_in[6];
  const float* W4 = (const float*)d_in[7];
  const float* b4 = (const float*)d_in[8];
  const int* ei   = (const int*)d_in[9];
  const int* batch = (const int*)d_in[10];

  int N = in_sizes[0] / 64;
  int E = in_sizes[9] / 2;
  int G = out_size / 16;
  const int* src = ei;
  const int* dst = ei + E;

  float* ws = (float*)d_ws;
  float* xtA    = ws;                          // N*64
  float* xtB    = xtA + (size_t)N * 64;        // N*64
  float* pooled = xtB + (size_t)N * 64;        // G*64
  float* cntg   = pooled + (size_t)G * 64;     // G
  float* hb_all = cntg + G;                    // 192
  float* hb2_all = hb_all + 192;               // 4 (pad)
  int* ip       = (int*)(hb2_all + 4);
  int* deg      = ip;                          // N
  int* locscan  = deg + N;                     // N
  int* rowptr   = locscan + N;                 // N+1
  int* partial  = rowptr + N + 1;              // 256 (pad to 8-align)
  int* deg8     = partial + 256;               // 8N
  int* offs8    = deg8 + (size_t)8 * N;        // 8N
  int* csr      = offs8 + (size_t)8 * N;       // E
  float* out = (float*)d_out;

  int nbN = (N + 255) / 256;
  int nbE = (E + 255) / 256;
  int pairs = (N + 1) / 2;
  int nbP = (pairs + 3) / 4;

  hipMemsetAsync(deg8, 0, (size_t)8 * N * sizeof(int), stream);
  hipMemsetAsync(pooled, 0, (size_t)G * 64 * sizeof(float), stream);

  k_hist8<<<nbE, 256, 0, stream>>>(dst, deg8, E, N);
  k_gsize<<<(G + 255) / 256, 256, 0, stream>>>(batch, cntg, N, G);
  k_red8<<<nbN, 256, 0, stream>>>(deg8, offs8, deg, N);
  k_scanA<<<nbN, 256, 0, stream>>>(deg, locscan, partial, N);
  k_scanB<<<1, 256, 0, stream>>>(partial, nbN);
  k_scanC<<<nbN, 256, 0, stream>>>(locscan, partial, rowptr, N, E);
  k_fill8<<<nbE, 256, 0, stream>>>(src, dst, rowptr, offs8, deg8, csr, E, N);

  k_prepb<<<1, 192, 0, stream>>>(b1, b2, b3, hb_all, hb2_all);

  k_lin1<<<2048, 512, 0, stream>>>(x, W1, hb_all, hb2_all, xtA, N);
  k_gatherlin<<<2048, 512, 0, stream>>>(rowptr, csr, xtA, W2, hb_all + 64,
                                        hb2_all + 1, xtB, N);
  k_gatherlin<<<2048, 512, 0, stream>>>(rowptr, csr, xtB, W3, hb_all + 128,
                                        hb2_all + 2, xtA, N);
  k_gpool<<<nbP, 256, 0, stream>>>(rowptr, csr, xtA, batch, pooled, N);
  k_final<<<G, 64, 0, stream>>>(pooled, cntg, W4, b4, out, G);
}

// Round 9
// 268.751 us; speedup vs baseline: 3.6629x; 1.0103x over previous
//
#include <hip/hip_runtime.h>
#include <hip/hip_fp16.h>

#define EPSF 1e-7f
#define MAXNORM (1.0f - 1e-5f)

__device__ __forceinline__ float rsum64(float v) {
#pragma unroll
  for (int m = 32; m; m >>= 1) v += __shfl_xor(v, m, 64);
  return v;
}
__device__ __forceinline__ float rsum16(float v) {
#pragma unroll
  for (int m = 8; m; m >>= 1) v += __shfl_xor(v, m, 64);
  return v;
}

__device__ __forceinline__ float frcp(float x) { return __builtin_amdgcn_rcpf(x); }
__device__ __forceinline__ float fsqrt_(float x) { return __builtin_amdgcn_sqrtf(x); }
__device__ __forceinline__ float tanh_fast(float x) {
  x = fminf(x, 20.f);
  float e = __builtin_amdgcn_exp2f(x * 2.88539008178f);  // e^{2x}
  return (e - 1.f) * frcp(e + 1.f);
}
__device__ __forceinline__ float atanh_fast(float x) {
  return 0.34657359028f * __builtin_amdgcn_logf((1.f + x) * frcp(1.f - x));
}
// logmap0(proj(expmap0(u))) == f(nu) * u, nu = max(||u||, EPS).
__device__ __forceinline__ float lp_exp_log_scale(float nu) {
  float te = tanh_fast(nu);
  float tec = fminf(fmaxf(te, EPSF), MAXNORM);
  return atanh_fast(tec) * frcp(fmaxf(te, EPSF)) * te * frcp(nu);
}

// ---- fp16 row gather helpers: 8 rows per wave-instruction (128B rows) ----
__device__ __forceinline__ void gstep(const uint4* __restrict__ xt4, int idx,
                                      int sub, float4& A, float4& B) {
  uint4 raw = xt4[(size_t)idx * 8 + sub];
  union { uint4 u; __half2 h[4]; } U; U.u = raw;
  float2 f0 = __half22float2(U.h[0]);
  float2 f1 = __half22float2(U.h[1]);
  float2 f2 = __half22float2(U.h[2]);
  float2 f3 = __half22float2(U.h[3]);
  A.x += f0.x; A.y += f0.y; A.z += f1.x; A.w += f1.y;
  B.x += f2.x; B.y += f2.y; B.z += f3.x; B.w += f3.y;
}
__device__ __forceinline__ void gstep_m(const uint4* __restrict__ xt4, int idx,
                                        int sub, float m, float4& A, float4& B) {
  uint4 raw = xt4[(size_t)idx * 8 + sub];
  union { uint4 u; __half2 h[4]; } U; U.u = raw;
  float2 f0 = __half22float2(U.h[0]);
  float2 f1 = __half22float2(U.h[1]);
  float2 f2 = __half22float2(U.h[2]);
  float2 f3 = __half22float2(U.h[3]);
  A.x = fmaf(m, f0.x, A.x); A.y = fmaf(m, f0.y, A.y);
  A.z = fmaf(m, f1.x, A.z); A.w = fmaf(m, f1.y, A.w);
  B.x = fmaf(m, f2.x, B.x); B.y = fmaf(m, f2.y, B.y);
  B.z = fmaf(m, f3.x, B.z); B.w = fmaf(m, f3.y, B.w);
}

// Fused dual-node gather over fp16 rows. grp=lane>>3 picks one of 8 rows per
// load; sub=lane&7 picks the 16B segment (dims sub*8..sub*8+7 in A,B).
// Full 8-row steps are unmasked; single masked tail step per chunk.
__device__ __forceinline__ void gather_pair(const int* __restrict__ csr,
                                            const __half* __restrict__ xtp,
                                            int r0a, int r1a, int r0b, int r1b,
                                            int lane, float4& Aa, float4& Ba,
                                            float4& Ab, float4& Bb) {
  const uint4* xt4 = reinterpret_cast<const uint4*>(xtp);
  int grp = lane >> 3, sub = lane & 7;
  Aa = {0, 0, 0, 0}; Ba = {0, 0, 0, 0}; Ab = {0, 0, 0, 0}; Bb = {0, 0, 0, 0};
  int dega = r1a - r0a, degb = r1b - r0b;
  int basea = 0, baseb = 0;
  while (basea < dega || baseb < degb) {
    int ca = dega - basea; ca = (ca > 64) ? 64 : ((ca < 0) ? 0 : ca);
    int cb = degb - baseb; cb = (cb > 64) ? 64 : ((cb < 0) ? 0 : cb);
    int ea = (lane < ca) ? csr[r0a + basea + lane] : 0;
    int eb = (lane < cb) ? csr[r0b + baseb + lane] : 0;
    int cmax = (ca > cb) ? ca : cb;
    for (int c = 0; c < cmax; c += 8) {
      if (c + 8 <= ca) {            // wave-uniform
        int i = __shfl(ea, c + grp, 64);
        gstep(xt4, i, sub, Aa, Ba);
      } else if (c < ca) {
        int l = c + grp;
        float m = (l < ca) ? 1.f : 0.f;
        int i = __shfl(ea, (l < ca) ? l : (ca - 1), 64);
        gstep_m(xt4, i, sub, m, Aa, Ba);
      }
      if (c + 8 <= cb) {
        int i = __shfl(eb, c + grp, 64);
        gstep(xt4, i, sub, Ab, Bb);
      } else if (c < cb) {
        int l = c + grp;
        float m = (l < cb) ? 1.f : 0.f;
        int i = __shfl(eb, (l < cb) ? l : (cb - 1), 64);
        gstep_m(xt4, i, sub, m, Ab, Bb);
      }
    }
    basea += ca; baseb += cb;
  }
  // sum the 8 row-groups (grp axis): lanes differing in bits 3..5
#pragma unroll
  for (int m = 8; m <= 32; m <<= 1) {
    Aa.x += __shfl_xor(Aa.x, m, 64); Aa.y += __shfl_xor(Aa.y, m, 64);
    Aa.z += __shfl_xor(Aa.z, m, 64); Aa.w += __shfl_xor(Aa.w, m, 64);
    Ba.x += __shfl_xor(Ba.x, m, 64); Ba.y += __shfl_xor(Ba.y, m, 64);
    Ba.z += __shfl_xor(Ba.z, m, 64); Ba.w += __shfl_xor(Ba.w, m, 64);
    Ab.x += __shfl_xor(Ab.x, m, 64); Ab.y += __shfl_xor(Ab.y, m, 64);
    Ab.z += __shfl_xor(Ab.z, m, 64); Ab.w += __shfl_xor(Ab.w, m, 64);
    Bb.x += __shfl_xor(Bb.x, m, 64); Bb.y += __shfl_xor(Bb.y, m, 64);
    Bb.z += __shfl_xor(Bb.z, m, 64); Bb.w += __shfl_xor(Bb.w, m, 64);
  }
}

// redistribute 8-dims-per-lane layout to scalar-per-lane (dim = lane)
__device__ __forceinline__ float redist8(float4 A, float4 B, int lane) {
  int srcl = lane >> 3, sel = lane & 7;
  float s0 = __shfl(A.x, srcl, 64), s1 = __shfl(A.y, srcl, 64);
  float s2 = __shfl(A.z, srcl, 64), s3 = __shfl(A.w, srcl, 64);
  float s4 = __shfl(B.x, srcl, 64), s5 = __shfl(B.y, srcl, 64);
  float s6 = __shfl(B.z, srcl, 64), s7 = __shfl(B.w, srcl, 64);
  float lo = (sel & 2) ? ((sel & 1) ? s3 : s2) : ((sel & 1) ? s1 : s0);
  float hi = (sel & 2) ? ((sel & 1) ? s7 : s6) : ((sel & 1) ? s5 : s4);
  return (sel & 4) ? hi : lo;
}

// ---------------- CSR build: XCD-privatized histogram (R8) ----------------
__global__ void k_hist8(const int* __restrict__ dst, int* __restrict__ deg8,
                        int E, int N) {
  int e = blockIdx.x * blockDim.x + threadIdx.x;
  if (e >= E) return;
  int c = blockIdx.x & 7;
  atomicAdd(&deg8[(size_t)c * N + dst[e]], 1);
}

__global__ void __launch_bounds__(256) k_red8(int* __restrict__ deg8,
                                              int* __restrict__ offs8,
                                              int* __restrict__ deg, int N) {
  int d = blockIdx.x * blockDim.x + threadIdx.x;
  if (d >= N) return;
  int s = 0;
#pragma unroll
  for (int k = 0; k < 8; ++k) {
    int v = deg8[(size_t)k * N + d];
    offs8[(size_t)k * N + d] = s;
    s += v;
  }
  deg[d] = s;
}

__global__ void __launch_bounds__(256) k_scanA(const int* __restrict__ deg,
                                               int* __restrict__ locscan,
                                               int* __restrict__ partial, int N) {
  __shared__ int buf[256];
  int i = blockIdx.x * 256 + threadIdx.x;
  int v = (i < N) ? deg[i] : 0;
  buf[threadIdx.x] = v;
  __syncthreads();
#pragma unroll
  for (int off = 1; off < 256; off <<= 1) {
    int t = (threadIdx.x >= off) ? buf[threadIdx.x - off] : 0;
    __syncthreads();
    buf[threadIdx.x] += t;
    __syncthreads();
  }
  if (i < N) locscan[i] = buf[threadIdx.x] - v;
  if (threadIdx.x == 255) partial[blockIdx.x] = buf[255];
}

__global__ void __launch_bounds__(256) k_scanB(int* __restrict__ partial, int nb) {
  __shared__ int buf[256];
  int v = (threadIdx.x < nb) ? partial[threadIdx.x] : 0;
  buf[threadIdx.x] = v;
  __syncthreads();
#pragma unroll
  for (int off = 1; off < 256; off <<= 1) {
    int t = (threadIdx.x >= off) ? buf[threadIdx.x - off] : 0;
    __syncthreads();
    buf[threadIdx.x] += t;
    __syncthreads();
  }
  if (threadIdx.x < nb) partial[threadIdx.x] = buf[threadIdx.x] - v;
}

__global__ void __launch_bounds__(256) k_scanC(const int* __restrict__ locscan,
                                               const int* __restrict__ partial,
                                               int* __restrict__ rowptr, int N, int E) {
  int i = blockIdx.x * 256 + threadIdx.x;
  if (i < N) rowptr[i] = locscan[i] + partial[blockIdx.x];
  if (i == 0) rowptr[N] = E;
}

__global__ void k_fill8(const int* __restrict__ src, const int* __restrict__ dst,
                        const int* __restrict__ rowptr,
                        const int* __restrict__ offs8, int* __restrict__ deg8,
                        int* __restrict__ csr, int E, int N) {
  int e = blockIdx.x * blockDim.x + threadIdx.x;
  if (e >= E) return;
  int c = blockIdx.x & 7;
  int d = dst[e];
  int p = atomicSub(&deg8[(size_t)c * N + d], 1) - 1;
  csr[rowptr[d] + offs8[(size_t)c * N + d] + p] = src[e];
}

// graph sizes from SORTED batch via binary search — zero atomics.
__global__ void k_gsize(const int* __restrict__ batch, float* __restrict__ cntg,
                        int N, int G) {
  int g = blockIdx.x * blockDim.x + threadIdx.x;
  if (g >= G) return;
  int lo = 0, hi = N;
  while (lo < hi) { int mid = (lo + hi) >> 1; if (batch[mid] < g) lo = mid + 1; else hi = mid; }
  int lb = lo;
  lo = 0; hi = N; int g1 = g + 1;
  while (lo < hi) { int mid = (lo + hi) >> 1; if (batch[mid] < g1) lo = mid + 1; else hi = mid; }
  cntg[g] = (float)(lo - lb);
}

// hb = proj(expmap0(b)) per layer; hb2 = ||hb||^2
__global__ void __launch_bounds__(192) k_prepb(const float* __restrict__ b1,
                                               const float* __restrict__ b2,
                                               const float* __restrict__ b3,
                                               float* __restrict__ hb_all,
                                               float* __restrict__ hb2_all) {
  int w = threadIdx.x >> 6, lane = threadIdx.x & 63;
  const float* b = (w == 0) ? b1 : (w == 1) ? b2 : b3;
  float bb = b[lane];
  float nb = fmaxf(fsqrt_(rsum64(bb * bb)), EPSF);
  float tb = tanh_fast(nb);
  float cb = fminf(tb, MAXNORM);
  float hb = cb * frcp(nb) * bb;
  hb_all[w * 64 + lane] = hb;
  if (lane == 0) hb2_all[w] = cb * cb;
}

// matvec for a node pair; W-row float4 reads shared by both nodes.
__device__ __forceinline__ void matvec_pair(const float* Wl, float* ts, int wid,
                                            int lane, float t2a, float t2b,
                                            float& acca, float& accb) {
  float* tsw = ts + wid * 128;
  tsw[lane] = t2a;
  tsw[64 + lane] = t2b;
  const float4* Wrow = reinterpret_cast<const float4*>(&Wl[lane * 68]);
  const float4* ta4 = reinterpret_cast<const float4*>(tsw);
  const float4* tb4 = reinterpret_cast<const float4*>(tsw + 64);
  float a = 0.f, b = 0.f;
#pragma unroll
  for (int q = 0; q < 16; ++q) {
    float4 w = Wrow[q];
    float4 ta = ta4[q];
    float4 tb = tb4[q];
    a = fmaf(w.x, ta.x, a); a = fmaf(w.y, ta.y, a);
    a = fmaf(w.z, ta.z, a); a = fmaf(w.w, ta.w, a);
    b = fmaf(w.x, tb.x, b); b = fmaf(w.y, tb.y, b);
    b = fmaf(w.z, tb.z, b); b = fmaf(w.w, tb.w, b);
  }
  acca = a; accb = b;
}

// mobius-bias + proj + logmap0 tail, dual-node, analytic result norm.
__device__ __forceinline__ void mobius_pair(float acca, float accb, float hbv,
                                            float hb2, float& oa, float& ob) {
  float p1a = acca * acca, p2a = acca * hbv;
  float p1b = accb * accb, p2b = accb * hbv;
#pragma unroll
  for (int m = 1; m <= 32; m <<= 1) {
    p1a += __shfl_xor(p1a, m, 64); p2a += __shfl_xor(p2a, m, 64);
    p1b += __shfl_xor(p1b, m, 64); p2b += __shfl_xor(p2b, m, 64);
  }
  float nya = fmaxf(fsqrt_(p1a), EPSF);
  float nyb = fmaxf(fsqrt_(p1b), EPSF);
  float cya = fminf(tanh_fast(nya), MAXNORM);
  float cyb = fminf(tanh_fast(nyb), MAXNORM);
  float ka = cya * frcp(nya);
  float kb = cyb * frcp(nyb);
  float xya = ka * p2a, xyb = kb * p2b;
  float x2a = cya * cya, x2b = cyb * cyb;
  float aa = 1.f + 2.f * xya + hb2, ab = 1.f + 2.f * xyb + hb2;
  float ca = 1.f - x2a, cb = 1.f - x2b;
  float dena = fmaxf(1.f + 2.f * xya + x2a * hb2, EPSF);
  float denb = fmaxf(1.f + 2.f * xyb + x2b * hb2, EPSF);
  float rda = frcp(dena), rdb = frcp(denb);
  float nr2a = (aa * aa * x2a + 2.f * aa * ca * xya + ca * ca * hb2) * rda * rda;
  float nr2b = (ab * ab * x2b + 2.f * ab * cb * xyb + cb * cb * hb2) * rdb * rdb;
  float nra = fmaxf(fsqrt_(nr2a), EPSF);
  float nrb = fmaxf(fsqrt_(nr2b), EPSF);
  float sa = atanh_fast(fminf(nra, MAXNORM)) * frcp(nra);
  float sb = atanh_fast(fminf(nrb, MAXNORM)) * frcp(nrb);
  oa = sa * rda * (aa * ka * acca + ca * hbv);
  ob = sb * rdb * (ab * kb * accb + cb * hbv);
}

// layer1 (node-pair): x(f32) -> xt1(fp16)
__global__ void __launch_bounds__(512) k_lin1(const float* __restrict__ x,
                                              const float* __restrict__ W,
                                              const float* __restrict__ hb,
                                              const float* __restrict__ hb2p,
                                              __half* __restrict__ xt, int N) {
  __shared__ __align__(16) float Wl[64 * 68];
  __shared__ __align__(16) float ts[8 * 128];
  int tid = threadIdx.x, wid = tid >> 6, lane = tid & 63;
  for (int i = tid; i < 4096; i += 512) Wl[(i >> 6) * 68 + (i & 63)] = W[i];
  __syncthreads();
  float hbv = hb[lane];
  float hb2 = hb2p[0];
  int pairs = (N + 1) >> 1;
  for (int p = blockIdx.x * 8 + wid; p < pairs; p += gridDim.x * 8) {
    int n0 = 2 * p, n1 = n0 + 1;
    bool v1 = n1 < N;
    float xa = x[(size_t)n0 * 64 + lane];
    float xb = v1 ? x[(size_t)n1 * 64 + lane] : 0.f;
    float pa = xa * xa, pb = xb * xb;
#pragma unroll
    for (int m = 1; m <= 32; m <<= 1) {
      pa += __shfl_xor(pa, m, 64); pb += __shfl_xor(pb, m, 64);
    }
    float na = fmaxf(fsqrt_(pa), EPSF);
    float nb = fmaxf(fsqrt_(pb), EPSF);
    float t2a = lp_exp_log_scale(na) * xa;
    float t2b = lp_exp_log_scale(nb) * xb;
    float acca, accb;
    matvec_pair(Wl, ts, wid, lane, t2a, t2b, acca, accb);
    float oa, ob;
    mobius_pair(acca, accb, hbv, hb2, oa, ob);
    xt[(size_t)n0 * 64 + lane] = __float2half(oa);
    if (v1) xt[(size_t)n1 * 64 + lane] = __float2half(ob);
  }
}

// layer boundary (node-pair): fp16 gather-mean -> hyp_agg -> act -> linear -> fp16
__global__ void __launch_bounds__(512) k_gatherlin(
    const int* __restrict__ rowptr, const int* __restrict__ csr,
    const __half* __restrict__ xtp, const float* __restrict__ W,
    const float* __restrict__ hb, const float* __restrict__ hb2p,
    __half* __restrict__ xt, int N) {
  __shared__ __align__(16) float Wl[64 * 68];
  __shared__ __align__(16) float ts[8 * 128];
  int tid = threadIdx.x, wid = tid >> 6, lane = tid & 63;
  for (int i = tid; i < 4096; i += 512) Wl[(i >> 6) * 68 + (i & 63)] = W[i];
  __syncthreads();
  float hbv = hb[lane];
  float hb2 = hb2p[0];
  int pairs = (N + 1) >> 1;
  for (int p = blockIdx.x * 8 + wid; p < pairs; p += gridDim.x * 8) {
    int n0 = 2 * p, n1 = n0 + 1;
    bool v1 = n1 < N;
    int r0a = rowptr[n0], r1a = rowptr[n0 + 1];
    int r0b = r1a, r1b = v1 ? rowptr[n1 + 1] : r1a;
    float4 Aa, Ba, Ab, Bb;
    gather_pair(csr, xtp, r0a, r1a, r0b, r1b, lane, Aa, Ba, Ab, Bb);
    float dia = frcp(fmaxf((float)(r1a - r0a), 1.f));
    float dib = frcp(fmaxf((float)(r1b - r0b), 1.f));
    Aa.x *= dia; Aa.y *= dia; Aa.z *= dia; Aa.w *= dia;
    Ba.x *= dia; Ba.y *= dia; Ba.z *= dia; Ba.w *= dia;
    Ab.x *= dib; Ab.y *= dib; Ab.z *= dib; Ab.w *= dib;
    Bb.x *= dib; Bb.y *= dib; Bb.z *= dib; Bb.w *= dib;
    // p = sum u^2, q = sum (leaky-weighted u)^2, per lane over 8 dims
    float pa = Aa.x * Aa.x + Aa.y * Aa.y + Aa.z * Aa.z + Aa.w * Aa.w +
               Ba.x * Ba.x + Ba.y * Ba.y + Ba.z * Ba.z + Ba.w * Ba.w;
    float qa = (Aa.x < 0.f ? 0.04f : 1.f) * Aa.x * Aa.x +
               (Aa.y < 0.f ? 0.04f : 1.f) * Aa.y * Aa.y +
               (Aa.z < 0.f ? 0.04f : 1.f) * Aa.z * Aa.z +
               (Aa.w < 0.f ? 0.04f : 1.f) * Aa.w * Aa.w +
               (Ba.x < 0.f ? 0.04f : 1.f) * Ba.x * Ba.x +
               (Ba.y < 0.f ? 0.04f : 1.f) * Ba.y * Ba.y +
               (Ba.z < 0.f ? 0.04f : 1.f) * Ba.z * Ba.z +
               (Ba.w < 0.f ? 0.04f : 1.f) * Ba.w * Ba.w;
    float pb = Ab.x * Ab.x + Ab.y * Ab.y + Ab.z * Ab.z + Ab.w * Ab.w +
               Bb.x * Bb.x + Bb.y * Bb.y + Bb.z * Bb.z + Bb.w * Bb.w;
    float qb = (Ab.x < 0.f ? 0.04f : 1.f) * Ab.x * Ab.x +
               (Ab.y < 0.f ? 0.04f : 1.f) * Ab.y * Ab.y +
               (Ab.z < 0.f ? 0.04f : 1.f) * Ab.z * Ab.z +
               (Ab.w < 0.f ? 0.04f : 1.f) * Ab.w * Ab.w +
               (Bb.x < 0.f ? 0.04f : 1.f) * Bb.x * Bb.x +
               (Bb.y < 0.f ? 0.04f : 1.f) * Bb.y * Bb.y +
               (Bb.z < 0.f ? 0.04f : 1.f) * Bb.z * Bb.z +
               (Bb.w < 0.f ? 0.04f : 1.f) * Bb.w * Bb.w;
#pragma unroll
    for (int m = 1; m <= 4; m <<= 1) {
      pa += __shfl_xor(pa, m, 64); qa += __shfl_xor(qa, m, 64);
      pb += __shfl_xor(pb, m, 64); qb += __shfl_xor(qb, m, 64);
    }
    float ua = redist8(Aa, Ba, lane);
    float ub = redist8(Ab, Bb, lane);
    float nua = fmaxf(fsqrt_(pa), EPSF);
    float nub = fmaxf(fsqrt_(pb), EPSF);
    float s1a = lp_exp_log_scale(nua);
    float s1b = lp_exp_log_scale(nub);
    float nta = fmaxf(s1a * fsqrt_(qa), EPSF);
    float ntb = fmaxf(s1b * fsqrt_(qb), EPSF);
    float fa = lp_exp_log_scale(nta) * s1a;
    float fb = lp_exp_log_scale(ntb) * s1b;
    float t2a = fa * ua * ((ua < 0.f) ? 0.2f : 1.f);
    float t2b = fb * ub * ((ub < 0.f) ? 0.2f : 1.f);
    float acca, accb;
    matvec_pair(Wl, ts, wid, lane, t2a, t2b, acca, accb);
    float oa, ob;
    mobius_pair(acca, accb, hbv, hb2, oa, ob);
    xt[(size_t)n0 * 64 + lane] = __float2half(oa);
    if (v1) xt[(size_t)n1 * 64 + lane] = __float2half(ob);
  }
}

// layer3 end (node-pair): fp16 gather-mean -> hyp_agg -> logmap -> pool atomics
__global__ void __launch_bounds__(256) k_gpool(const int* __restrict__ rowptr,
                                               const int* __restrict__ csr,
                                               const __half* __restrict__ xtp,
                                               const int* __restrict__ batch,
                                               float* __restrict__ pooled, int N) {
  int p = blockIdx.x * 4 + (threadIdx.x >> 6);
  int pairs = (N + 1) >> 1;
  if (p >= pairs) return;
  int lane = threadIdx.x & 63;
  int n0 = 2 * p, n1 = n0 + 1;
  bool v1 = n1 < N;
  int r0a = rowptr[n0], r1a = rowptr[n0 + 1];
  int r0b = r1a, r1b = v1 ? rowptr[n1 + 1] : r1a;
  float4 Aa, Ba, Ab, Bb;
  gather_pair(csr, xtp, r0a, r1a, r0b, r1b, lane, Aa, Ba, Ab, Bb);
  float dia = frcp(fmaxf((float)(r1a - r0a), 1.f));
  float dib = frcp(fmaxf((float)(r1b - r0b), 1.f));
  Aa.x *= dia; Aa.y *= dia; Aa.z *= dia; Aa.w *= dia;
  Ba.x *= dia; Ba.y *= dia; Ba.z *= dia; Ba.w *= dia;
  Ab.x *= dib; Ab.y *= dib; Ab.z *= dib; Ab.w *= dib;
  Bb.x *= dib; Bb.y *= dib; Bb.z *= dib; Bb.w *= dib;
  float pa = Aa.x * Aa.x + Aa.y * Aa.y + Aa.z * Aa.z + Aa.w * Aa.w +
             Ba.x * Ba.x + Ba.y * Ba.y + Ba.z * Ba.z + Ba.w * Ba.w;
  float pb = Ab.x * Ab.x + Ab.y * Ab.y + Ab.z * Ab.z + Ab.w * Ab.w +
             Bb.x * Bb.x + Bb.y * Bb.y + Bb.z * Bb.z + Bb.w * Bb.w;
#pragma unroll
  for (int m = 1; m <= 4; m <<= 1) {
    pa += __shfl_xor(pa, m, 64); pb += __shfl_xor(pb, m, 64);
  }
  float ua = redist8(Aa, Ba, lane);
  float ub = redist8(Ab, Bb, lane);
  float nua = fmaxf(fsqrt_(pa), EPSF);
  float nub = fmaxf(fsqrt_(pb), EPSF);
  float ta = lp_exp_log_scale(nua) * ua;
  float tb = lp_exp_log_scale(nub) * ub;
  atomicAdd(&pooled[(size_t)batch[n0] * 64 + lane], ta);
  if (v1) atomicAdd(&pooled[(size_t)batch[n1] * 64 + lane], tb);
}

// head: per graph, 1 wave (precise; negligible cost)
__global__ void __launch_bounds__(64) k_final(const float* __restrict__ pooled,
                                              const float* __restrict__ cntg,
                                              const float* __restrict__ W4,
                                              const float* __restrict__ b4,
                                              float* __restrict__ out, int G) {
  int g = blockIdx.x;
  int lane = threadIdx.x;
  float u = pooled[(size_t)g * 64 + lane] / fmaxf(cntg[g], 1.0f);
  float n = fmaxf(sqrtf(rsum64(u * u)), EPSF);
  float e = tanhf(n) * u / n;
  float ne = fmaxf(sqrtf(rsum64(e * e)), EPSF);
  if (ne > MAXNORM) e *= MAXNORM / ne;
  float nn = fmaxf(sqrtf(rsum64(e * e)), EPSF);
  float t = atanhf(fminf(nn, MAXNORM)) * e / nn;

  int row = lane & 15;
  float acc = 0.f;
#pragma unroll
  for (int k = 0; k < 64; ++k) {
    float tk = __shfl(t, k, 64);
    acc = fmaf(W4[row * 64 + k], tk, acc);
  }
  float ny = fmaxf(sqrtf(rsum16(acc * acc)), EPSF);
  float hy = tanhf(ny) * acc / ny;
  float nh = fmaxf(sqrtf(rsum16(hy * hy)), EPSF);
  if (nh > MAXNORM) hy *= MAXNORM / nh;
  float bb = b4[row];
  float nb = fmaxf(sqrtf(rsum16(bb * bb)), EPSF);
  float hb = tanhf(nb) * bb / nb;
  float nhb = fmaxf(sqrtf(rsum16(hb * hb)), EPSF);
  if (nhb > MAXNORM) hb *= MAXNORM / nhb;
  float x2 = rsum16(hy * hy);
  float y2 = rsum16(hb * hb);
  float xy = rsum16(hy * hb);
  float num = (1.f + 2.f * xy + y2) * hy + (1.f - x2) * hb;
  float den = fmaxf(1.f + 2.f * xy + x2 * y2, EPSF);
  float r = num / den;
  float nr = fmaxf(sqrtf(rsum16(r * r)), EPSF);
  if (nr > MAXNORM) r *= MAXNORM / nr;
  if (lane < 16) out[(size_t)g * 16 + lane] = r;
}

extern "C" void kernel_launch(void* const* d_in, const int* in_sizes, int n_in,
                              void* d_out, int out_size, void* d_ws, size_t ws_size,
                              hipStream_t stream) {
  const float* x  = (const float*)d_in[0];
  const float* W1 = (const float*)d_in[1];
  const float* b1 = (const float*)d_in[2];
  const float* W2 = (const float*)d_in[3];
  const float* b2 = (const float*)d_in[4];
  const float* W3 = (const float*)d_in[5];
  const float* b3 = (const float*)d_in[6];
  const float* W4 = (const float*)d_in[7];
  const float* b4 = (const float*)d_in[8];
  const int* ei   = (const int*)d_in[9];
  const int* batch = (const int*)d_in[10];

  int N = in_sizes[0] / 64;
  int E = in_sizes[9] / 2;
  int G = out_size / 16;
  const int* src = ei;
  const int* dst = ei + E;

  float* ws = (float*)d_ws;
  __half* xtA   = (__half*)ws;                 // N*64 halfs (N*32 floats)
  __half* xtB   = xtA + (size_t)N * 64;        // N*64 halfs
  float* pooled = ws + (size_t)N * 64;         // G*64 (after both half arrays)
  float* cntg   = pooled + (size_t)G * 64;     // G
  float* hb_all = cntg + G;                    // 192
  float* hb2_all = hb_all + 192;               // 4 (pad)
  int* ip       = (int*)(hb2_all + 4);
  int* deg      = ip;                          // N
  int* locscan  = deg + N;                     // N
  int* rowptr   = locscan + N;                 // N+1
  int* partial  = rowptr + N + 1;              // 256 (pad)
  int* deg8     = partial + 256;               // 8N
  int* offs8    = deg8 + (size_t)8 * N;        // 8N
  int* csr      = offs8 + (size_t)8 * N;       // E
  float* out = (float*)d_out;

  int nbN = (N + 255) / 256;
  int nbE = (E + 255) / 256;
  int pairs = (N + 1) / 2;
  int nbP = (pairs + 3) / 4;

  hipMemsetAsync(deg8, 0, (size_t)8 * N * sizeof(int), stream);
  hipMemsetAsync(pooled, 0, (size_t)G * 64 * sizeof(float), stream);

  k_hist8<<<nbE, 256, 0, stream>>>(dst, deg8, E, N);
  k_gsize<<<(G + 255) / 256, 256, 0, stream>>>(batch, cntg, N, G);
  k_red8<<<nbN, 256, 0, stream>>>(deg8, offs8, deg, N);
  k_scanA<<<nbN, 256, 0, stream>>>(deg, locscan, partial, N);
  k_scanB<<<1, 256, 0, stream>>>(partial, nbN);
  k_scanC<<<nbN, 256, 0, stream>>>(locscan, partial, rowptr, N, E);
  k_fill8<<<nbE, 256, 0, stream>>>(src, dst, rowptr, offs8, deg8, csr, E, N);

  k_prepb<<<1, 192, 0, stream>>>(b1, b2, b3, hb_all, hb2_all);

  k_lin1<<<2048, 512, 0, stream>>>(x, W1, hb_all, hb2_all, xtA, N);
  k_gatherlin<<<2048, 512, 0, stream>>>(rowptr, csr, xtA, W2, hb_all + 64,
                                        hb2_all + 1, xtB, N);
  k_gatherlin<<<2048, 512, 0, stream>>>(rowptr, csr, xtB, W3, hb_all + 128,
                                        hb2_all + 2, xtA, N);
  k_gpool<<<nbP, 256, 0, stream>>>(rowptr, csr, xtA, batch, pooled, N);
  k_final<<<G, 64, 0, stream>>>(pooled, cntg, W4, b4, out, G);
}

// Round 10
// 251.395 us; speedup vs baseline: 3.9158x; 1.0690x over previous
//
#include <hip/hip_runtime.h>

#define EPSF 1e-7f
#define MAXNORM (1.0f - 1e-5f)

__device__ __forceinline__ float rsum64(float v) {
#pragma unroll
  for (int m = 32; m; m >>= 1) v += __shfl_xor(v, m, 64);
  return v;
}
__device__ __forceinline__ float rsum16(float v) {
#pragma unroll
  for (int m = 8; m; m >>= 1) v += __shfl_xor(v, m, 64);
  return v;
}
// 8-lane group reduce (3 levels) — serves 8 nodes per wave at once
__device__ __forceinline__ float gr8(float v) {
  v += __shfl_xor(v, 1, 64);
  v += __shfl_xor(v, 2, 64);
  v += __shfl_xor(v, 4, 64);
  return v;
}

__device__ __forceinline__ float frcp(float x) { return __builtin_amdgcn_rcpf(x); }
__device__ __forceinline__ float fsqrt_(float x) { return __builtin_amdgcn_sqrtf(x); }
__device__ __forceinline__ float tanh_fast(float x) {
  x = fminf(x, 20.f);
  float e = __builtin_amdgcn_exp2f(x * 2.88539008178f);  // e^{2x}
  return (e - 1.f) * frcp(e + 1.f);
}
__device__ __forceinline__ float atanh_fast(float x) {
  return 0.34657359028f * __builtin_amdgcn_logf((1.f + x) * frcp(1.f - x));
}
// logmap0(proj(expmap0(u))) == f(nu) * u
__device__ __forceinline__ float lp_exp_log_scale(float nu) {
  float te = tanh_fast(nu);
  float tec = fminf(fmaxf(te, EPSF), MAXNORM);
  return atanh_fast(tec) * frcp(fmaxf(te, EPSF)) * te * frcp(nu);
}

__device__ __forceinline__ float4 ld4(const float* p) {
  return *reinterpret_cast<const float4*>(p);
}

// ---- 8-node gather: group g (8 lanes) gathers its own node's rows.
// Indices prefetched per-lane (coalesced), rows loaded f32 as 2x float4/lane,
// masked full-unroll (loads of clamped idx 0 are L1-hot, mask zeroes them).
__device__ __forceinline__ void gather8(const int* __restrict__ csr,
                                        const float* __restrict__ xtp,
                                        int r0, int deg, int g, int sub,
                                        float acc[8]) {
  for (int j0 = 0; j0 < deg; j0 += 8) {
    int myidx = 0;
    if (j0 + sub < deg) myidx = csr[r0 + j0 + sub];
#pragma unroll
    for (int m = 0; m < 8; ++m) {
      int idx = __shfl(myidx, (g << 3) | m, 64);
      float msk = (j0 + m < deg) ? 1.f : 0.f;
      const float* row = xtp + (size_t)idx * 64 + sub * 8;
      float4 v0 = ld4(row);
      float4 v1 = ld4(row + 4);
      acc[0] = fmaf(msk, v0.x, acc[0]); acc[1] = fmaf(msk, v0.y, acc[1]);
      acc[2] = fmaf(msk, v0.z, acc[2]); acc[3] = fmaf(msk, v0.w, acc[3]);
      acc[4] = fmaf(msk, v1.x, acc[4]); acc[5] = fmaf(msk, v1.y, acc[5]);
      acc[6] = fmaf(msk, v1.z, acc[6]); acc[7] = fmaf(msk, v1.w, acc[7]);
    }
  }
}

// ---- matvec + mobius-bias + proj + logmap0, 8 nodes/wave, 8-dim layout.
// sc = per-wave scratch [8*68] floats (stride 68 kills bank alignment).
__device__ __forceinline__ void linear_tail8(
    const float* __restrict__ Wl, float* __restrict__ sc, int g, int sub,
    int lane, const float t2[8], const float hb8[8], float hb2, float out8[8]) {
  // stage t2: group g's 64 values at sc[g*68 ...]
  float4* sw = reinterpret_cast<float4*>(sc + g * 68 + sub * 8);
  sw[0] = make_float4(t2[0], t2[1], t2[2], t2[3]);
  sw[1] = make_float4(t2[4], t2[5], t2[6], t2[7]);
  // matvec: lane computes dim=lane for all 8 nodes; W rows reused in regs.
  float y[8] = {0.f, 0.f, 0.f, 0.f, 0.f, 0.f, 0.f, 0.f};
  const float4* Wrow = reinterpret_cast<const float4*>(Wl + lane * 68);
#pragma unroll
  for (int q = 0; q < 16; ++q) {
    float4 w = Wrow[q];
#pragma unroll
    for (int g2 = 0; g2 < 8; ++g2) {
      float4 tq = *reinterpret_cast<const float4*>(sc + g2 * 68 + q * 4);
      y[g2] = fmaf(w.x, tq.x, fmaf(w.y, tq.y, fmaf(w.z, tq.z, fmaf(w.w, tq.w, y[g2]))));
    }
  }
  // redistribute y -> 8-dim layout (reuse sc; same-wave LDS ops are in-order)
#pragma unroll
  for (int g2 = 0; g2 < 8; ++g2) sc[g2 * 68 + lane] = y[g2];
  float4 r0 = *reinterpret_cast<const float4*>(sc + g * 68 + sub * 8);
  float4 r1 = *reinterpret_cast<const float4*>(sc + g * 68 + sub * 8 + 4);
  float yv[8] = {r0.x, r0.y, r0.z, r0.w, r1.x, r1.y, r1.z, r1.w};
  // mobius with analytic result norm; reductions are 3-level group reduces
  float p1 = 0.f, p2 = 0.f;
#pragma unroll
  for (int j = 0; j < 8; ++j) {
    p1 = fmaf(yv[j], yv[j], p1);
    p2 = fmaf(yv[j], hb8[j], p2);
  }
  p1 = gr8(p1); p2 = gr8(p2);
  float ny = fmaxf(fsqrt_(p1), EPSF);
  float cy = fminf(tanh_fast(ny), MAXNORM);
  float k = cy * frcp(ny);
  float xy = k * p2;
  float x2 = cy * cy;
  float aa = 1.f + 2.f * xy + hb2;
  float cc = 1.f - x2;
  float den = fmaxf(1.f + 2.f * xy + x2 * hb2, EPSF);
  float rd = frcp(den);
  float nr2 = (aa * aa * x2 + 2.f * aa * cc * xy + cc * cc * hb2) * rd * rd;
  float nr = fmaxf(fsqrt_(nr2), EPSF);
  float s = atanh_fast(fminf(nr, MAXNORM)) * frcp(nr);
  float sk = s * rd;
#pragma unroll
  for (int j = 0; j < 8; ++j) out8[j] = sk * (aa * k * yv[j] + cc * hb8[j]);
}

// ---------------- CSR build: XCD-privatized histogram (R8) ----------------
__global__ void k_hist8(const int* __restrict__ dst, int* __restrict__ deg8,
                        int E, int N) {
  int e = blockIdx.x * blockDim.x + threadIdx.x;
  if (e >= E) return;
  int c = blockIdx.x & 7;
  atomicAdd(&deg8[(size_t)c * N + dst[e]], 1);
}

__global__ void __launch_bounds__(256) k_red8(int* __restrict__ deg8,
                                              int* __restrict__ offs8,
                                              int* __restrict__ deg, int N) {
  int d = blockIdx.x * blockDim.x + threadIdx.x;
  if (d >= N) return;
  int s = 0;
#pragma unroll
  for (int k = 0; k < 8; ++k) {
    int v = deg8[(size_t)k * N + d];
    offs8[(size_t)k * N + d] = s;
    s += v;
  }
  deg[d] = s;
}

__global__ void __launch_bounds__(256) k_scanA(const int* __restrict__ deg,
                                               int* __restrict__ locscan,
                                               int* __restrict__ partial, int N) {
  __shared__ int buf[256];
  int i = blockIdx.x * 256 + threadIdx.x;
  int v = (i < N) ? deg[i] : 0;
  buf[threadIdx.x] = v;
  __syncthreads();
#pragma unroll
  for (int off = 1; off < 256; off <<= 1) {
    int t = (threadIdx.x >= off) ? buf[threadIdx.x - off] : 0;
    __syncthreads();
    buf[threadIdx.x] += t;
    __syncthreads();
  }
  if (i < N) locscan[i] = buf[threadIdx.x] - v;
  if (threadIdx.x == 255) partial[blockIdx.x] = buf[255];
}

__global__ void __launch_bounds__(256) k_scanB(int* __restrict__ partial, int nb) {
  __shared__ int buf[256];
  int v = (threadIdx.x < nb) ? partial[threadIdx.x] : 0;
  buf[threadIdx.x] = v;
  __syncthreads();
#pragma unroll
  for (int off = 1; off < 256; off <<= 1) {
    int t = (threadIdx.x >= off) ? buf[threadIdx.x - off] : 0;
    __syncthreads();
    buf[threadIdx.x] += t;
    __syncthreads();
  }
  if (threadIdx.x < nb) partial[threadIdx.x] = buf[threadIdx.x] - v;
}

__global__ void __launch_bounds__(256) k_scanC(const int* __restrict__ locscan,
                                               const int* __restrict__ partial,
                                               int* __restrict__ rowptr, int N, int E) {
  int i = blockIdx.x * 256 + threadIdx.x;
  if (i < N) rowptr[i] = locscan[i] + partial[blockIdx.x];
  if (i == 0) rowptr[N] = E;
}

__global__ void k_fill8(const int* __restrict__ src, const int* __restrict__ dst,
                        const int* __restrict__ rowptr,
                        const int* __restrict__ offs8, int* __restrict__ deg8,
                        int* __restrict__ csr, int E, int N) {
  int e = blockIdx.x * blockDim.x + threadIdx.x;
  if (e >= E) return;
  int c = blockIdx.x & 7;
  int d = dst[e];
  int p = atomicSub(&deg8[(size_t)c * N + d], 1) - 1;
  csr[rowptr[d] + offs8[(size_t)c * N + d] + p] = src[e];
}

// graph sizes from SORTED batch via binary search — zero atomics.
__global__ void k_gsize(const int* __restrict__ batch, float* __restrict__ cntg,
                        int N, int G) {
  int g = blockIdx.x * blockDim.x + threadIdx.x;
  if (g >= G) return;
  int lo = 0, hi = N;
  while (lo < hi) { int mid = (lo + hi) >> 1; if (batch[mid] < g) lo = mid + 1; else hi = mid; }
  int lb = lo;
  lo = 0; hi = N; int g1 = g + 1;
  while (lo < hi) { int mid = (lo + hi) >> 1; if (batch[mid] < g1) lo = mid + 1; else hi = mid; }
  cntg[g] = (float)(lo - lb);
}

// hb = proj(expmap0(b)) per layer; hb2 = ||hb||^2
__global__ void __launch_bounds__(192) k_prepb(const float* __restrict__ b1,
                                               const float* __restrict__ b2,
                                               const float* __restrict__ b3,
                                               float* __restrict__ hb_all,
                                               float* __restrict__ hb2_all) {
  int w = threadIdx.x >> 6, lane = threadIdx.x & 63;
  const float* b = (w == 0) ? b1 : (w == 1) ? b2 : b3;
  float bb = b[lane];
  float nb = fmaxf(fsqrt_(rsum64(bb * bb)), EPSF);
  float tb = tanh_fast(nb);
  float cb = fminf(tb, MAXNORM);
  float hb = cb * frcp(nb) * bb;
  hb_all[w * 64 + lane] = hb;
  if (lane == 0) hb2_all[w] = cb * cb;
}

// layer1: x -> xt1.  8 nodes/wave, 8 dims/lane.
__global__ void __launch_bounds__(512) k_lin1(const float* __restrict__ x,
                                              const float* __restrict__ W,
                                              const float* __restrict__ hb,
                                              const float* __restrict__ hb2p,
                                              float* __restrict__ xt, int N) {
  __shared__ __align__(16) float Wl[64 * 68];
  __shared__ __align__(16) float sc_all[8][8 * 68];
  int tid = threadIdx.x, wid = tid >> 6, lane = tid & 63;
  int g = lane >> 3, sub = lane & 7;
  for (int i = tid; i < 4096; i += 512) Wl[(i >> 6) * 68 + (i & 63)] = W[i];
  __syncthreads();
  float hb2 = hb2p[0];
  float4 h0 = ld4(hb + sub * 8), h1 = ld4(hb + sub * 8 + 4);
  float hb8[8] = {h0.x, h0.y, h0.z, h0.w, h1.x, h1.y, h1.z, h1.w};

  int slot = blockIdx.x * 64 + wid * 8 + g;
  bool valid = slot < N;
  int node = valid ? slot : 0;
  const float* row = x + (size_t)node * 64 + sub * 8;
  float4 v0 = ld4(row), v1 = ld4(row + 4);
  float xa[8] = {v0.x, v0.y, v0.z, v0.w, v1.x, v1.y, v1.z, v1.w};
  float p = 0.f;
#pragma unroll
  for (int j = 0; j < 8; ++j) p = fmaf(xa[j], xa[j], p);
  p = gr8(p);
  float na = fmaxf(fsqrt_(p), EPSF);
  float sc1 = lp_exp_log_scale(na);
  float t2[8];
#pragma unroll
  for (int j = 0; j < 8; ++j) t2[j] = sc1 * xa[j];
  float out8[8];
  linear_tail8(Wl, sc_all[wid], g, sub, lane, t2, hb8, hb2, out8);
  if (valid) {
    float4* o = reinterpret_cast<float4*>(xt + (size_t)node * 64 + sub * 8);
    o[0] = make_float4(out8[0], out8[1], out8[2], out8[3]);
    o[1] = make_float4(out8[4], out8[5], out8[6], out8[7]);
  }
}

// layer boundary: gather-mean -> hyp_agg -> act -> hyp_linear.  8 nodes/wave.
__global__ void __launch_bounds__(512) k_gatherlin(
    const int* __restrict__ rowptr, const int* __restrict__ csr,
    const float* __restrict__ xtp, const float* __restrict__ W,
    const float* __restrict__ hb, const float* __restrict__ hb2p,
    float* __restrict__ xt, int N) {
  __shared__ __align__(16) float Wl[64 * 68];
  __shared__ __align__(16) float sc_all[8][8 * 68];
  int tid = threadIdx.x, wid = tid >> 6, lane = tid & 63;
  int g = lane >> 3, sub = lane & 7;
  for (int i = tid; i < 4096; i += 512) Wl[(i >> 6) * 68 + (i & 63)] = W[i];
  __syncthreads();
  float hb2 = hb2p[0];
  float4 h0 = ld4(hb + sub * 8), h1 = ld4(hb + sub * 8 + 4);
  float hb8[8] = {h0.x, h0.y, h0.z, h0.w, h1.x, h1.y, h1.z, h1.w};

  int slot = blockIdx.x * 64 + wid * 8 + g;
  bool valid = slot < N;
  int node = valid ? slot : 0;
  int r0 = rowptr[node];
  int deg = valid ? (rowptr[node + 1] - r0) : 0;
  float acc[8] = {0.f, 0.f, 0.f, 0.f, 0.f, 0.f, 0.f, 0.f};
  gather8(csr, xtp, r0, deg, g, sub, acc);
  float rdeg = frcp(fmaxf((float)deg, 1.f));
  float u[8];
#pragma unroll
  for (int j = 0; j < 8; ++j) u[j] = acc[j] * rdeg;
  float p = 0.f, q = 0.f;
#pragma unroll
  for (int j = 0; j < 8; ++j) {
    float w = (u[j] < 0.f) ? 0.04f : 1.f;
    p = fmaf(u[j], u[j], p);
    q = fmaf(w * u[j], u[j], q);
  }
  p = gr8(p); q = gr8(q);
  float nu = fmaxf(fsqrt_(p), EPSF);
  float s1 = lp_exp_log_scale(nu);                 // agg expmap+proj+logmap
  float nt = fmaxf(s1 * fsqrt_(q), EPSF);          // ||leaky(t)|| analytically
  float f = lp_exp_log_scale(nt) * s1;             // act expmap+proj+next logmap
  float t2[8];
#pragma unroll
  for (int j = 0; j < 8; ++j) t2[j] = f * u[j] * ((u[j] < 0.f) ? 0.2f : 1.f);
  float out8[8];
  linear_tail8(Wl, sc_all[wid], g, sub, lane, t2, hb8, hb2, out8);
  if (valid) {
    float4* o = reinterpret_cast<float4*>(xt + (size_t)node * 64 + sub * 8);
    o[0] = make_float4(out8[0], out8[1], out8[2], out8[3]);
    o[1] = make_float4(out8[4], out8[5], out8[6], out8[7]);
  }
}

// layer3 end: gather-mean -> hyp_agg -> logmap -> pool.  8 nodes/wave.
// If the wave's 8 nodes share one graph (common: batch sorted, ~100 nodes/graph),
// cross-group reduce first -> 8x fewer pool atomics.
__global__ void __launch_bounds__(256) k_gpool(const int* __restrict__ rowptr,
                                               const int* __restrict__ csr,
                                               const float* __restrict__ xtp,
                                               const int* __restrict__ batch,
                                               float* __restrict__ pooled, int N) {
  int tid = threadIdx.x, wid = tid >> 6, lane = tid & 63;
  int g = lane >> 3, sub = lane & 7;
  int slot = blockIdx.x * 32 + wid * 8 + g;
  bool valid = slot < N;
  int node = valid ? slot : 0;
  int r0 = rowptr[node];
  int deg = valid ? (rowptr[node + 1] - r0) : 0;
  float acc[8] = {0.f, 0.f, 0.f, 0.f, 0.f, 0.f, 0.f, 0.f};
  gather8(csr, xtp, r0, deg, g, sub, acc);
  float rdeg = frcp(fmaxf((float)deg, 1.f));
  float u[8], p = 0.f;
#pragma unroll
  for (int j = 0; j < 8; ++j) {
    u[j] = acc[j] * rdeg;
    p = fmaf(u[j], u[j], p);
  }
  p = gr8(p);
  float nu = fmaxf(fsqrt_(p), EPSF);
  float s = lp_exp_log_scale(nu);
  float t8[8];
#pragma unroll
  for (int j = 0; j < 8; ++j) t8[j] = (valid ? s : 0.f) * u[j];
  int bs = batch[node];
  int b0 = __shfl(bs, 0, 64);
  bool uniform = __all(valid && bs == b0);
  if (uniform) {
#pragma unroll
    for (int j = 0; j < 8; ++j) {
      t8[j] += __shfl_xor(t8[j], 8, 64);
      t8[j] += __shfl_xor(t8[j], 16, 64);
      t8[j] += __shfl_xor(t8[j], 32, 64);
    }
    if (g == 0) {
#pragma unroll
      for (int j = 0; j < 8; ++j)
        atomicAdd(&pooled[(size_t)b0 * 64 + sub * 8 + j], t8[j]);
    }
  } else if (valid) {
#pragma unroll
    for (int j = 0; j < 8; ++j)
      atomicAdd(&pooled[(size_t)bs * 64 + sub * 8 + j], t8[j]);
  }
}

// head: per graph, 1 wave (precise; negligible cost)
__global__ void __launch_bounds__(64) k_final(const float* __restrict__ pooled,
                                              const float* __restrict__ cntg,
                                              const float* __restrict__ W4,
                                              const float* __restrict__ b4,
                                              float* __restrict__ out, int G) {
  int g = blockIdx.x;
  int lane = threadIdx.x;
  float u = pooled[(size_t)g * 64 + lane] / fmaxf(cntg[g], 1.0f);
  float n = fmaxf(sqrtf(rsum64(u * u)), EPSF);
  float e = tanhf(n) * u / n;
  float ne = fmaxf(sqrtf(rsum64(e * e)), EPSF);
  if (ne > MAXNORM) e *= MAXNORM / ne;
  float nn = fmaxf(sqrtf(rsum64(e * e)), EPSF);
  float t = atanhf(fminf(nn, MAXNORM)) * e / nn;

  int row = lane & 15;
  float acc = 0.f;
#pragma unroll
  for (int k = 0; k < 64; ++k) {
    float tk = __shfl(t, k, 64);
    acc = fmaf(W4[row * 64 + k], tk, acc);
  }
  float ny = fmaxf(sqrtf(rsum16(acc * acc)), EPSF);
  float hy = tanhf(ny) * acc / ny;
  float nh = fmaxf(sqrtf(rsum16(hy * hy)), EPSF);
  if (nh > MAXNORM) hy *= MAXNORM / nh;
  float bb = b4[row];
  float nb = fmaxf(sqrtf(rsum16(bb * bb)), EPSF);
  float hb = tanhf(nb) * bb / nb;
  float nhb = fmaxf(sqrtf(rsum16(hb * hb)), EPSF);
  if (nhb > MAXNORM) hb *= MAXNORM / nhb;
  float x2 = rsum16(hy * hy);
  float y2 = rsum16(hb * hb);
  float xy = rsum16(hy * hb);
  float num = (1.f + 2.f * xy + y2) * hy + (1.f - x2) * hb;
  float den = fmaxf(1.f + 2.f * xy + x2 * y2, EPSF);
  float r = num / den;
  float nr = fmaxf(sqrtf(rsum16(r * r)), EPSF);
  if (nr > MAXNORM) r *= MAXNORM / nr;
  if (lane < 16) out[(size_t)g * 16 + lane] = r;
}

extern "C" void kernel_launch(void* const* d_in, const int* in_sizes, int n_in,
                              void* d_out, int out_size, void* d_ws, size_t ws_size,
                              hipStream_t stream) {
  const float* x  = (const float*)d_in[0];
  const float* W1 = (const float*)d_in[1];
  const float* b1 = (const float*)d_in[2];
  const float* W2 = (const float*)d_in[3];
  const float* b2 = (const float*)d_in[4];
  const float* W3 = (const float*)d_in[5];
  const float* b3 = (const float*)d_in[6];
  const float* W4 = (const float*)d_in[7];
  const float* b4 = (const float*)d_in[8];
  const int* ei   = (const int*)d_in[9];
  const int* batch = (const int*)d_in[10];

  int N = in_sizes[0] / 64;
  int E = in_sizes[9] / 2;
  int G = out_size / 16;
  const int* src = ei;
  const int* dst = ei + E;

  float* ws = (float*)d_ws;
  float* xtA    = ws;                          // N*64
  float* xtB    = xtA + (size_t)N * 64;        // N*64
  float* pooled = xtB + (size_t)N * 64;        // G*64
  float* cntg   = pooled + (size_t)G * 64;     // G
  float* hb_all = cntg + G;                    // 192
  float* hb2_all = hb_all + 192;               // 4 (pad)
  int* ip       = (int*)(hb2_all + 4);
  int* deg      = ip;                          // N
  int* locscan  = deg + N;                     // N
  int* rowptr   = locscan + N;                 // N+1
  int* partial  = rowptr + N + 1;              // 256 (pad)
  int* deg8     = partial + 256;               // 8N
  int* offs8    = deg8 + (size_t)8 * N;        // 8N
  int* csr      = offs8 + (size_t)8 * N;       // E
  float* out = (float*)d_out;

  int nbN = (N + 255) / 256;
  int nbE = (E + 255) / 256;
  int nb64 = (N + 63) / 64;
  int nb32 = (N + 31) / 32;

  hipMemsetAsync(deg8, 0, (size_t)8 * N * sizeof(int), stream);
  hipMemsetAsync(pooled, 0, (size_t)G * 64 * sizeof(float), stream);

  k_hist8<<<nbE, 256, 0, stream>>>(dst, deg8, E, N);
  k_gsize<<<(G + 255) / 256, 256, 0, stream>>>(batch, cntg, N, G);
  k_red8<<<nbN, 256, 0, stream>>>(deg8, offs8, deg, N);
  k_scanA<<<nbN, 256, 0, stream>>>(deg, locscan, partial, N);
  k_scanB<<<1, 256, 0, stream>>>(partial, nbN);
  k_scanC<<<nbN, 256, 0, stream>>>(locscan, partial, rowptr, N, E);
  k_fill8<<<nbE, 256, 0, stream>>>(src, dst, rowptr, offs8, deg8, csr, E, N);

  k_prepb<<<1, 192, 0, stream>>>(b1, b2, b3, hb_all, hb2_all);

  k_lin1<<<nb64, 512, 0, stream>>>(x, W1, hb_all, hb2_all, xtA, N);
  k_gatherlin<<<nb64, 512, 0, stream>>>(rowptr, csr, xtA, W2, hb_all + 64,
                                        hb2_all + 1, xtB, N);
  k_gatherlin<<<nb64, 512, 0, stream>>>(rowptr, csr, xtB, W3, hb_all + 128,
                                        hb2_all + 2, xtA, N);
  k_gpool<<<nb32, 256, 0, stream>>>(rowptr, csr, xtA, batch, pooled, N);
  k_final<<<G, 64, 0, stream>>>(pooled, cntg, W4, b4, out, G);
}

// Round 11
// 210.191 us; speedup vs baseline: 4.6834x; 1.1960x over previous
//
#include <hip/hip_runtime.h>
#include <hip/hip_fp16.h>

#define EPSF 1e-7f
#define MAXNORM (1.0f - 1e-5f)

__device__ __forceinline__ float rsum64(float v) {
#pragma unroll
  for (int m = 32; m; m >>= 1) v += __shfl_xor(v, m, 64);
  return v;
}
__device__ __forceinline__ float rsum16(float v) {
#pragma unroll
  for (int m = 8; m; m >>= 1) v += __shfl_xor(v, m, 64);
  return v;
}
// 8-lane group reduce (3 levels) — serves 8 nodes per wave at once
__device__ __forceinline__ float gr8(float v) {
  v += __shfl_xor(v, 1, 64);
  v += __shfl_xor(v, 2, 64);
  v += __shfl_xor(v, 4, 64);
  return v;
}

__device__ __forceinline__ float frcp(float x) { return __builtin_amdgcn_rcpf(x); }
__device__ __forceinline__ float fsqrt_(float x) { return __builtin_amdgcn_sqrtf(x); }
__device__ __forceinline__ float tanh_fast(float x) {
  x = fminf(x, 20.f);
  float e = __builtin_amdgcn_exp2f(x * 2.88539008178f);  // e^{2x}
  return (e - 1.f) * frcp(e + 1.f);
}
__device__ __forceinline__ float atanh_fast(float x) {
  return 0.34657359028f * __builtin_amdgcn_logf((1.f + x) * frcp(1.f - x));
}
// logmap0(proj(expmap0(u))) == f(nu) * u
__device__ __forceinline__ float lp_exp_log_scale(float nu) {
  float te = tanh_fast(nu);
  float tec = fminf(fmaxf(te, EPSF), MAXNORM);
  return atanh_fast(tec) * frcp(fmaxf(te, EPSF)) * te * frcp(nu);
}

__device__ __forceinline__ float4 ld4(const float* p) {
  return *reinterpret_cast<const float4*>(p);
}

// ---- 8-node gather over fp16 rows (128B/row): group g (8 lanes) gathers its
// own node's rows; lane sub loads ONE uint4 (8 halves = dims sub*8..sub*8+7).
// f32 accumulate; unpack is cheap here (VALUBusy was 6% in the f32 variant).
__device__ __forceinline__ void gather8h(const int* __restrict__ csr,
                                         const __half* __restrict__ xtp,
                                         int r0, int deg, int g, int sub,
                                         float acc[8]) {
  const uint4* xt4 = reinterpret_cast<const uint4*>(xtp);
  for (int j0 = 0; j0 < deg; j0 += 8) {
    int myidx = 0;
    if (j0 + sub < deg) myidx = csr[r0 + j0 + sub];
#pragma unroll
    for (int m = 0; m < 8; ++m) {
      int idx = __shfl(myidx, (g << 3) | m, 64);
      float msk = (j0 + m < deg) ? 1.f : 0.f;
      union { uint4 u; __half2 h[4]; } U;
      U.u = xt4[(size_t)idx * 8 + sub];
      float2 f0 = __half22float2(U.h[0]);
      float2 f1 = __half22float2(U.h[1]);
      float2 f2 = __half22float2(U.h[2]);
      float2 f3 = __half22float2(U.h[3]);
      acc[0] = fmaf(msk, f0.x, acc[0]); acc[1] = fmaf(msk, f0.y, acc[1]);
      acc[2] = fmaf(msk, f1.x, acc[2]); acc[3] = fmaf(msk, f1.y, acc[3]);
      acc[4] = fmaf(msk, f2.x, acc[4]); acc[5] = fmaf(msk, f2.y, acc[5]);
      acc[6] = fmaf(msk, f3.x, acc[6]); acc[7] = fmaf(msk, f3.y, acc[7]);
    }
  }
}

// store 8 f32 dims as 8 fp16 (one uint4 per lane)
__device__ __forceinline__ void st8h(__half* __restrict__ xt, int node, int sub,
                                     const float o[8]) {
  union { uint4 u; __half2 h[4]; } U;
  U.h[0] = __floats2half2_rn(o[0], o[1]);
  U.h[1] = __floats2half2_rn(o[2], o[3]);
  U.h[2] = __floats2half2_rn(o[4], o[5]);
  U.h[3] = __floats2half2_rn(o[6], o[7]);
  reinterpret_cast<uint4*>(xt)[(size_t)node * 8 + sub] = U.u;
}

// ---- matvec + mobius-bias + proj + logmap0, 8 nodes/wave, 8-dim layout.
__device__ __forceinline__ void linear_tail8(
    const float* __restrict__ Wl, float* __restrict__ sc, int g, int sub,
    int lane, const float t2[8], const float hb8[8], float hb2, float out8[8]) {
  float4* sw = reinterpret_cast<float4*>(sc + g * 68 + sub * 8);
  sw[0] = make_float4(t2[0], t2[1], t2[2], t2[3]);
  sw[1] = make_float4(t2[4], t2[5], t2[6], t2[7]);
  float y[8] = {0.f, 0.f, 0.f, 0.f, 0.f, 0.f, 0.f, 0.f};
  const float4* Wrow = reinterpret_cast<const float4*>(Wl + lane * 68);
#pragma unroll
  for (int q = 0; q < 16; ++q) {
    float4 w = Wrow[q];
#pragma unroll
    for (int g2 = 0; g2 < 8; ++g2) {
      float4 tq = *reinterpret_cast<const float4*>(sc + g2 * 68 + q * 4);
      y[g2] = fmaf(w.x, tq.x, fmaf(w.y, tq.y, fmaf(w.z, tq.z, fmaf(w.w, tq.w, y[g2]))));
    }
  }
#pragma unroll
  for (int g2 = 0; g2 < 8; ++g2) sc[g2 * 68 + lane] = y[g2];
  float4 r0 = *reinterpret_cast<const float4*>(sc + g * 68 + sub * 8);
  float4 r1 = *reinterpret_cast<const float4*>(sc + g * 68 + sub * 8 + 4);
  float yv[8] = {r0.x, r0.y, r0.z, r0.w, r1.x, r1.y, r1.z, r1.w};
  float p1 = 0.f, p2 = 0.f;
#pragma unroll
  for (int j = 0; j < 8; ++j) {
    p1 = fmaf(yv[j], yv[j], p1);
    p2 = fmaf(yv[j], hb8[j], p2);
  }
  p1 = gr8(p1); p2 = gr8(p2);
  float ny = fmaxf(fsqrt_(p1), EPSF);
  float cy = fminf(tanh_fast(ny), MAXNORM);
  float k = cy * frcp(ny);
  float xy = k * p2;
  float x2 = cy * cy;
  float aa = 1.f + 2.f * xy + hb2;
  float cc = 1.f - x2;
  float den = fmaxf(1.f + 2.f * xy + x2 * hb2, EPSF);
  float rd = frcp(den);
  float nr2 = (aa * aa * x2 + 2.f * aa * cc * xy + cc * cc * hb2) * rd * rd;
  float nr = fmaxf(fsqrt_(nr2), EPSF);
  float s = atanh_fast(fminf(nr, MAXNORM)) * frcp(nr);
  float sk = s * rd;
#pragma unroll
  for (int j = 0; j < 8; ++j) out8[j] = sk * (aa * k * yv[j] + cc * hb8[j]);
}

// ---------------- CSR build: XCD-privatized histogram (R8) ----------------
__global__ void k_hist8(const int* __restrict__ dst, int* __restrict__ deg8,
                        int E, int N) {
  int e = blockIdx.x * blockDim.x + threadIdx.x;
  if (e >= E) return;
  int c = blockIdx.x & 7;
  atomicAdd(&deg8[(size_t)c * N + dst[e]], 1);
}

__global__ void __launch_bounds__(256) k_red8(int* __restrict__ deg8,
                                              int* __restrict__ offs8,
                                              int* __restrict__ deg, int N) {
  int d = blockIdx.x * blockDim.x + threadIdx.x;
  if (d >= N) return;
  int s = 0;
#pragma unroll
  for (int k = 0; k < 8; ++k) {
    int v = deg8[(size_t)k * N + d];
    offs8[(size_t)k * N + d] = s;
    s += v;
  }
  deg[d] = s;
}

__global__ void __launch_bounds__(256) k_scanA(const int* __restrict__ deg,
                                               int* __restrict__ locscan,
                                               int* __restrict__ partial, int N) {
  __shared__ int buf[256];
  int i = blockIdx.x * 256 + threadIdx.x;
  int v = (i < N) ? deg[i] : 0;
  buf[threadIdx.x] = v;
  __syncthreads();
#pragma unroll
  for (int off = 1; off < 256; off <<= 1) {
    int t = (threadIdx.x >= off) ? buf[threadIdx.x - off] : 0;
    __syncthreads();
    buf[threadIdx.x] += t;
    __syncthreads();
  }
  if (i < N) locscan[i] = buf[threadIdx.x] - v;
  if (threadIdx.x == 255) partial[blockIdx.x] = buf[255];
}

__global__ void __launch_bounds__(256) k_scanB(int* __restrict__ partial, int nb) {
  __shared__ int buf[256];
  int v = (threadIdx.x < nb) ? partial[threadIdx.x] : 0;
  buf[threadIdx.x] = v;
  __syncthreads();
#pragma unroll
  for (int off = 1; off < 256; off <<= 1) {
    int t = (threadIdx.x >= off) ? buf[threadIdx.x - off] : 0;
    __syncthreads();
    buf[threadIdx.x] += t;
    __syncthreads();
  }
  if (threadIdx.x < nb) partial[threadIdx.x] = buf[threadIdx.x] - v;
}

__global__ void __launch_bounds__(256) k_scanC(const int* __restrict__ locscan,
                                               const int* __restrict__ partial,
                                               int* __restrict__ rowptr, int N, int E) {
  int i = blockIdx.x * 256 + threadIdx.x;
  if (i < N) rowptr[i] = locscan[i] + partial[blockIdx.x];
  if (i == 0) rowptr[N] = E;
}

__global__ void k_fill8(const int* __restrict__ src, const int* __restrict__ dst,
                        const int* __restrict__ rowptr,
                        const int* __restrict__ offs8, int* __restrict__ deg8,
                        int* __restrict__ csr, int E, int N) {
  int e = blockIdx.x * blockDim.x + threadIdx.x;
  if (e >= E) return;
  int c = blockIdx.x & 7;
  int d = dst[e];
  int p = atomicSub(&deg8[(size_t)c * N + d], 1) - 1;
  csr[rowptr[d] + offs8[(size_t)c * N + d] + p] = src[e];
}

// graph sizes from SORTED batch via binary search — zero atomics.
__global__ void k_gsize(const int* __restrict__ batch, float* __restrict__ cntg,
                        int N, int G) {
  int g = blockIdx.x * blockDim.x + threadIdx.x;
  if (g >= G) return;
  int lo = 0, hi = N;
  while (lo < hi) { int mid = (lo + hi) >> 1; if (batch[mid] < g) lo = mid + 1; else hi = mid; }
  int lb = lo;
  lo = 0; hi = N; int g1 = g + 1;
  while (lo < hi) { int mid = (lo + hi) >> 1; if (batch[mid] < g1) lo = mid + 1; else hi = mid; }
  cntg[g] = (float)(lo - lb);
}

// hb = proj(expmap0(b)) per layer; hb2 = ||hb||^2
__global__ void __launch_bounds__(192) k_prepb(const float* __restrict__ b1,
                                               const float* __restrict__ b2,
                                               const float* __restrict__ b3,
                                               float* __restrict__ hb_all,
                                               float* __restrict__ hb2_all) {
  int w = threadIdx.x >> 6, lane = threadIdx.x & 63;
  const float* b = (w == 0) ? b1 : (w == 1) ? b2 : b3;
  float bb = b[lane];
  float nb = fmaxf(fsqrt_(rsum64(bb * bb)), EPSF);
  float tb = tanh_fast(nb);
  float cb = fminf(tb, MAXNORM);
  float hb = cb * frcp(nb) * bb;
  hb_all[w * 64 + lane] = hb;
  if (lane == 0) hb2_all[w] = cb * cb;
}

// layer1: x(f32) -> xt1(fp16).  8 nodes/wave, 8 dims/lane.
__global__ void __launch_bounds__(512) k_lin1(const float* __restrict__ x,
                                              const float* __restrict__ W,
                                              const float* __restrict__ hb,
                                              const float* __restrict__ hb2p,
                                              __half* __restrict__ xt, int N) {
  __shared__ __align__(16) float Wl[64 * 68];
  __shared__ __align__(16) float sc_all[8][8 * 68];
  int tid = threadIdx.x, wid = tid >> 6, lane = tid & 63;
  int g = lane >> 3, sub = lane & 7;
  for (int i = tid; i < 4096; i += 512) Wl[(i >> 6) * 68 + (i & 63)] = W[i];
  __syncthreads();
  float hb2 = hb2p[0];
  float4 h0 = ld4(hb + sub * 8), h1 = ld4(hb + sub * 8 + 4);
  float hb8[8] = {h0.x, h0.y, h0.z, h0.w, h1.x, h1.y, h1.z, h1.w};

  int slot = blockIdx.x * 64 + wid * 8 + g;
  bool valid = slot < N;
  int node = valid ? slot : 0;
  const float* row = x + (size_t)node * 64 + sub * 8;
  float4 v0 = ld4(row), v1 = ld4(row + 4);
  float xa[8] = {v0.x, v0.y, v0.z, v0.w, v1.x, v1.y, v1.z, v1.w};
  float p = 0.f;
#pragma unroll
  for (int j = 0; j < 8; ++j) p = fmaf(xa[j], xa[j], p);
  p = gr8(p);
  float na = fmaxf(fsqrt_(p), EPSF);
  float sc1 = lp_exp_log_scale(na);
  float t2[8];
#pragma unroll
  for (int j = 0; j < 8; ++j) t2[j] = sc1 * xa[j];
  float out8[8];
  linear_tail8(Wl, sc_all[wid], g, sub, lane, t2, hb8, hb2, out8);
  if (valid) st8h(xt, node, sub, out8);
}

// layer boundary: fp16 gather-mean -> hyp_agg -> act -> hyp_linear -> fp16.
__global__ void __launch_bounds__(512) k_gatherlin(
    const int* __restrict__ rowptr, const int* __restrict__ csr,
    const __half* __restrict__ xtp, const float* __restrict__ W,
    const float* __restrict__ hb, const float* __restrict__ hb2p,
    __half* __restrict__ xt, int N) {
  __shared__ __align__(16) float Wl[64 * 68];
  __shared__ __align__(16) float sc_all[8][8 * 68];
  int tid = threadIdx.x, wid = tid >> 6, lane = tid & 63;
  int g = lane >> 3, sub = lane & 7;
  for (int i = tid; i < 4096; i += 512) Wl[(i >> 6) * 68 + (i & 63)] = W[i];
  __syncthreads();
  float hb2 = hb2p[0];
  float4 h0 = ld4(hb + sub * 8), h1 = ld4(hb + sub * 8 + 4);
  float hb8[8] = {h0.x, h0.y, h0.z, h0.w, h1.x, h1.y, h1.z, h1.w};

  int slot = blockIdx.x * 64 + wid * 8 + g;
  bool valid = slot < N;
  int node = valid ? slot : 0;
  int r0 = rowptr[node];
  int deg = valid ? (rowptr[node + 1] - r0) : 0;
  float acc[8] = {0.f, 0.f, 0.f, 0.f, 0.f, 0.f, 0.f, 0.f};
  gather8h(csr, xtp, r0, deg, g, sub, acc);
  float rdeg = frcp(fmaxf((float)deg, 1.f));
  float u[8];
#pragma unroll
  for (int j = 0; j < 8; ++j) u[j] = acc[j] * rdeg;
  float p = 0.f, q = 0.f;
#pragma unroll
  for (int j = 0; j < 8; ++j) {
    float w = (u[j] < 0.f) ? 0.04f : 1.f;
    p = fmaf(u[j], u[j], p);
    q = fmaf(w * u[j], u[j], q);
  }
  p = gr8(p); q = gr8(q);
  float nu = fmaxf(fsqrt_(p), EPSF);
  float s1 = lp_exp_log_scale(nu);
  float nt = fmaxf(s1 * fsqrt_(q), EPSF);
  float f = lp_exp_log_scale(nt) * s1;
  float t2[8];
#pragma unroll
  for (int j = 0; j < 8; ++j) t2[j] = f * u[j] * ((u[j] < 0.f) ? 0.2f : 1.f);
  float out8[8];
  linear_tail8(Wl, sc_all[wid], g, sub, lane, t2, hb8, hb2, out8);
  if (valid) st8h(xt, node, sub, out8);
}

// layer3 end: fp16 gather-mean -> hyp_agg -> logmap -> pool.  8 nodes/wave.
__global__ void __launch_bounds__(512) k_gpool(const int* __restrict__ rowptr,
                                               const int* __restrict__ csr,
                                               const __half* __restrict__ xtp,
                                               const int* __restrict__ batch,
                                               float* __restrict__ pooled, int N) {
  int tid = threadIdx.x, wid = tid >> 6, lane = tid & 63;
  int g = lane >> 3, sub = lane & 7;
  int slot = blockIdx.x * 64 + wid * 8 + g;
  bool valid = slot < N;
  int node = valid ? slot : 0;
  int r0 = rowptr[node];
  int deg = valid ? (rowptr[node + 1] - r0) : 0;
  float acc[8] = {0.f, 0.f, 0.f, 0.f, 0.f, 0.f, 0.f, 0.f};
  gather8h(csr, xtp, r0, deg, g, sub, acc);
  float rdeg = frcp(fmaxf((float)deg, 1.f));
  float u[8], p = 0.f;
#pragma unroll
  for (int j = 0; j < 8; ++j) {
    u[j] = acc[j] * rdeg;
    p = fmaf(u[j], u[j], p);
  }
  p = gr8(p);
  float nu = fmaxf(fsqrt_(p), EPSF);
  float s = lp_exp_log_scale(nu);
  float t8[8];
#pragma unroll
  for (int j = 0; j < 8; ++j) t8[j] = (valid ? s : 0.f) * u[j];
  int bs = batch[node];
  int b0 = __shfl(bs, 0, 64);
  bool uniform = __all(valid && bs == b0);
  if (uniform) {
#pragma unroll
    for (int j = 0; j < 8; ++j) {
      t8[j] += __shfl_xor(t8[j], 8, 64);
      t8[j] += __shfl_xor(t8[j], 16, 64);
      t8[j] += __shfl_xor(t8[j], 32, 64);
    }
    if (g == 0) {
#pragma unroll
      for (int j = 0; j < 8; ++j)
        atomicAdd(&pooled[(size_t)b0 * 64 + sub * 8 + j], t8[j]);
    }
  } else if (valid) {
#pragma unroll
    for (int j = 0; j < 8; ++j)
      atomicAdd(&pooled[(size_t)bs * 64 + sub * 8 + j], t8[j]);
  }
}

// head: per graph, 1 wave (precise; negligible cost)
__global__ void __launch_bounds__(64) k_final(const float* __restrict__ pooled,
                                              const float* __restrict__ cntg,
                                              const float* __restrict__ W4,
                                              const float* __restrict__ b4,
                                              float* __restrict__ out, int G) {
  int g = blockIdx.x;
  int lane = threadIdx.x;
  float u = pooled[(size_t)g * 64 + lane] / fmaxf(cntg[g], 1.0f);
  float n = fmaxf(sqrtf(rsum64(u * u)), EPSF);
  float e = tanhf(n) * u / n;
  float ne = fmaxf(sqrtf(rsum64(e * e)), EPSF);
  if (ne > MAXNORM) e *= MAXNORM / ne;
  float nn = fmaxf(sqrtf(rsum64(e * e)), EPSF);
  float t = atanhf(fminf(nn, MAXNORM)) * e / nn;

  int row = lane & 15;
  float acc = 0.f;
#pragma unroll
  for (int k = 0; k < 64; ++k) {
    float tk = __shfl(t, k, 64);
    acc = fmaf(W4[row * 64 + k], tk, acc);
  }
  float ny = fmaxf(sqrtf(rsum16(acc * acc)), EPSF);
  float hy = tanhf(ny) * acc / ny;
  float nh = fmaxf(sqrtf(rsum16(hy * hy)), EPSF);
  if (nh > MAXNORM) hy *= MAXNORM / nh;
  float bb = b4[row];
  float nb = fmaxf(sqrtf(rsum16(bb * bb)), EPSF);
  float hb = tanhf(nb) * bb / nb;
  float nhb = fmaxf(sqrtf(rsum16(hb * hb)), EPSF);
  if (nhb > MAXNORM) hb *= MAXNORM / nhb;
  float x2 = rsum16(hy * hy);
  float y2 = rsum16(hb * hb);
  float xy = rsum16(hy * hb);
  float num = (1.f + 2.f * xy + y2) * hy + (1.f - x2) * hb;
  float den = fmaxf(1.f + 2.f * xy + x2 * y2, EPSF);
  float r = num / den;
  float nr = fmaxf(sqrtf(rsum16(r * r)), EPSF);
  if (nr > MAXNORM) r *= MAXNORM / nr;
  if (lane < 16) out[(size_t)g * 16 + lane] = r;
}

extern "C" void kernel_launch(void* const* d_in, const int* in_sizes, int n_in,
                              void* d_out, int out_size, void* d_ws, size_t ws_size,
                              hipStream_t stream) {
  const float* x  = (const float*)d_in[0];
  const float* W1 = (const float*)d_in[1];
  const float* b1 = (const float*)d_in[2];
  const float* W2 = (const float*)d_in[3];
  const float* b2 = (const float*)d_in[4];
  const float* W3 = (const float*)d_in[5];
  const float* b3 = (const float*)d_in[6];
  const float* W4 = (const float*)d_in[7];
  const float* b4 = (const float*)d_in[8];
  const int* ei   = (const int*)d_in[9];
  const int* batch = (const int*)d_in[10];

  int N = in_sizes[0] / 64;
  int E = in_sizes[9] / 2;
  int G = out_size / 16;
  const int* src = ei;
  const int* dst = ei + E;

  float* ws = (float*)d_ws;
  __half* xtA   = (__half*)ws;                 // N*64 halves = N*32 floats
  __half* xtB   = xtA + (size_t)N * 64;        // N*64 halves
  float* pooled = ws + (size_t)N * 64;         // G*64 (after the two half arrays)
  float* cntg   = pooled + (size_t)G * 64;     // G
  float* hb_all = cntg + G;                    // 192
  float* hb2_all = hb_all + 192;               // 4 (pad)
  int* ip       = (int*)(hb2_all + 4);
  int* deg      = ip;                          // N
  int* locscan  = deg + N;                     // N
  int* rowptr   = locscan + N;                 // N+1
  int* partial  = rowptr + N + 1;              // 256 (pad)
  int* deg8     = partial + 256;               // 8N
  int* offs8    = deg8 + (size_t)8 * N;        // 8N
  int* csr      = offs8 + (size_t)8 * N;       // E
  float* out = (float*)d_out;

  int nbN = (N + 255) / 256;
  int nbE = (E + 255) / 256;
  int nb64 = (N + 63) / 64;

  hipMemsetAsync(deg8, 0, (size_t)8 * N * sizeof(int), stream);
  hipMemsetAsync(pooled, 0, (size_t)G * 64 * sizeof(float), stream);

  k_hist8<<<nbE, 256, 0, stream>>>(dst, deg8, E, N);
  k_gsize<<<(G + 255) / 256, 256, 0, stream>>>(batch, cntg, N, G);
  k_red8<<<nbN, 256, 0, stream>>>(deg8, offs8, deg, N);
  k_scanA<<<nbN, 256, 0, stream>>>(deg, locscan, partial, N);
  k_scanB<<<1, 256, 0, stream>>>(partial, nbN);
  k_scanC<<<nbN, 256, 0, stream>>>(locscan, partial, rowptr, N, E);
  k_fill8<<<nbE, 256, 0, stream>>>(src, dst, rowptr, offs8, deg8, csr, E, N);

  k_prepb<<<1, 192, 0, stream>>>(b1, b2, b3, hb_all, hb2_all);

  k_lin1<<<nb64, 512, 0, stream>>>(x, W1, hb_all, hb2_all, xtA, N);
  k_gatherlin<<<nb64, 512, 0, stream>>>(rowptr, csr, xtA, W2, hb_all + 64,
                                        hb2_all + 1, xtB, N);
  k_gatherlin<<<nb64, 512, 0, stream>>>(rowptr, csr, xtB, W3, hb_all + 128,
                                        hb2_all + 2, xtA, N);
  k_gpool<<<nb64, 512, 0, stream>>>(rowptr, csr, xtA, batch, pooled, N);
  k_final<<<G, 64, 0, stream>>>(pooled, cntg, W4, b4, out, G);
}